// Round 1
// baseline (1580.378 us; speedup 1.0000x reference)
//
#include <hip/hip_runtime.h>
#include <hip/hip_bf16.h>

// DeepseekDecoderLayer on MI355X. Round 0: correctness-first.
// Pipeline: rmsnorm1 -> QKV (f32-split MFMA) -> RoPE (f64 table) -> causal
// flash attn (f32 VALU) -> O-proj+res (f32-split MFMA) -> rmsnorm2 ->
// router (f32, exact top-2) -> dense MoE dual-GEMM + shared dual-GEMM
// (bf16 MFMA) -> down GEMMs -> out = x + routed + shared.
// Precision: everything feeding the router is f32-accurate (split-bf16 3-MFMA
// trick, err ~2^-18) because top-2 selection flips at logit gaps ~2.5e-4.

#define DI __device__ __forceinline__

typedef __attribute__((ext_vector_type(8))) short short8;
typedef __attribute__((ext_vector_type(4))) float f32x4;
using u16 = unsigned short;

struct alignas(8) U16x4 { u16 x, y, z, w; };

DI u16 f2bf(float f) {
  unsigned u = __float_as_uint(f);
  u += 0x7fffu + ((u >> 16) & 1u);
  return (u16)(u >> 16);
}
DI float bf2f(u16 h) { return __uint_as_float(((unsigned)h) << 16); }

DI void gload16(const void* g, void* l) {
  __builtin_amdgcn_global_load_lds((const __attribute__((address_space(1))) void*)g,
                                   (__attribute__((address_space(3))) void*)l, 16, 0, 0);
}

// ---------------- small kernels ----------------

// RoPE cos/sin table in double precision (matches f64 numpy reference closely;
// f32 powf + large-arg trig would inject ~1e-4 into the router path).
__global__ __launch_bounds__(256) void k_ropetab(float* __restrict__ tab) {
  int idx = blockIdx.x * 256 + threadIdx.x;  // < 1024*64
  int s = idx >> 6, i = idx & 63;
  double inv = pow(10000.0, -(double)(2 * i) / 128.0);
  double ang = (double)s * inv;
  tab[idx * 2 + 0] = (float)cos(ang);
  tab[idx * 2 + 1] = (float)sin(ang);
}

// RMSNorm row kernel: optional f32 and bf16 outputs.
__global__ __launch_bounds__(256) void k_rmsnorm(const float* __restrict__ in,
                                                 const float* __restrict__ w,
                                                 float* __restrict__ outf,
                                                 u16* __restrict__ outb) {
  const int row = blockIdx.x, t = threadIdx.x;
  const float* x = in + (size_t)row * 2048;
  float4 a = *(const float4*)&x[t * 4];
  float4 b = *(const float4*)&x[1024 + t * 4];
  float ss = a.x * a.x + a.y * a.y + a.z * a.z + a.w * a.w +
             b.x * b.x + b.y * b.y + b.z * b.z + b.w * b.w;
#pragma unroll
  for (int off = 32; off; off >>= 1) ss += __shfl_xor(ss, off);
  __shared__ float red[4];
  if ((t & 63) == 0) red[t >> 6] = ss;
  __syncthreads();
  float total = red[0] + red[1] + red[2] + red[3];
  float r = 1.0f / sqrtf(total * (1.0f / 2048.0f) + 1e-6f);
  float4 wa = *(const float4*)&w[t * 4];
  float4 wb = *(const float4*)&w[1024 + t * 4];
  float4 oa, ob;
  oa.x = a.x * r * wa.x; oa.y = a.y * r * wa.y; oa.z = a.z * r * wa.z; oa.w = a.w * r * wa.w;
  ob.x = b.x * r * wb.x; ob.y = b.y * r * wb.y; ob.z = b.z * r * wb.z; ob.w = b.w * r * wb.w;
  if (outf) {
    *(float4*)&outf[(size_t)row * 2048 + t * 4] = oa;
    *(float4*)&outf[(size_t)row * 2048 + 1024 + t * 4] = ob;
  }
  if (outb) {
    U16x4 ua{f2bf(oa.x), f2bf(oa.y), f2bf(oa.z), f2bf(oa.w)};
    U16x4 ub{f2bf(ob.x), f2bf(ob.y), f2bf(ob.z), f2bf(ob.w)};
    *(U16x4*)&outb[(size_t)row * 2048 + t * 4] = ua;
    *(U16x4*)&outb[(size_t)row * 2048 + 1024 + t * 4] = ub;
  }
}

// Apply RoPE in-place to q (with 1/sqrt(128) folded in) and k. f32.
__global__ __launch_bounds__(256) void k_rope(float* __restrict__ q, float* __restrict__ k,
                                              const float* __restrict__ tab) {
  int idx = blockIdx.x * 256 + threadIdx.x;  // < 1024*16*64
  int s = idx >> 10, rem = idx & 1023;
  int h = rem >> 6, i = rem & 63;
  size_t base = (size_t)s * 2048 + h * 128 + i;
  float c = tab[(s * 64 + i) * 2 + 0];
  float sn = tab[(s * 64 + i) * 2 + 1];
  const float qs = 0.08838834764831845f;  // 1/sqrt(128)
  float q1 = q[base], q2 = q[base + 64];
  q[base] = (q1 * c - q2 * sn) * qs;
  q[base + 64] = (q2 * c + q1 * sn) * qs;
  float k1 = k[base], k2 = k[base + 64];
  k[base] = k1 * c - k2 * sn;
  k[base + 64] = k2 * c + k1 * sn;
}

// Router: f32 logits from f32 h2 (exact top-2 selection), combine weights out.
__global__ __launch_bounds__(256) void k_router(const float* __restrict__ h2f,
                                                const float* __restrict__ gw,
                                                float* __restrict__ comb) {
  const int tok = blockIdx.x;
  const float* hrow = h2f + (size_t)tok * 2048;
  float part[8];
#pragma unroll
  for (int e = 0; e < 8; ++e) part[e] = 0.f;
  for (int j = 0; j < 8; ++j) {
    int p = j * 256 + threadIdx.x;
    float hv = hrow[p];
#pragma unroll
    for (int e = 0; e < 8; ++e) part[e] += hv * gw[e * 2048 + p];
  }
#pragma unroll
  for (int e = 0; e < 8; ++e)
#pragma unroll
    for (int off = 32; off; off >>= 1) part[e] += __shfl_xor(part[e], off);
  __shared__ float red[4][8];
  int wv = threadIdx.x >> 6, lane = threadIdx.x & 63;
  if (lane == 0) {
#pragma unroll
    for (int e = 0; e < 8; ++e) red[wv][e] = part[e];
  }
  __syncthreads();
  if (threadIdx.x == 0) {
    float lg[8];
#pragma unroll
    for (int e = 0; e < 8; ++e) lg[e] = red[0][e] + red[1][e] + red[2][e] + red[3][e];
    float m = lg[0];
#pragma unroll
    for (int e = 1; e < 8; ++e) m = fmaxf(m, lg[e]);
    float ex[8], s = 0.f;
#pragma unroll
    for (int e = 0; e < 8; ++e) { ex[e] = expf(lg[e] - m); s += ex[e]; }
#pragma unroll
    for (int e = 0; e < 8; ++e) ex[e] /= s;
    int i1 = 0;
#pragma unroll
    for (int e = 1; e < 8; ++e) if (ex[e] > ex[i1]) i1 = e;
    int i2 = (i1 == 0) ? 1 : 0;
#pragma unroll
    for (int e = 0; e < 8; ++e) if (e != i1 && ex[e] > ex[i2]) i2 = e;
    float s2 = ex[i1] + ex[i2] + 1e-20f;
#pragma unroll
    for (int e = 0; e < 8; ++e)
      comb[tok * 8 + e] = (e == i1) ? ex[i1] / s2 : (e == i2) ? ex[i2] / s2 : 0.f;
  }
}

// Causal flash attention, f32 VALU. Block = (32 q rows, head). Thread owns a
// 16-wide d-slice of one q row; 8 threads/row cooperate via shfl.
__global__ __launch_bounds__(256) void k_attn(const float* __restrict__ q,
                                              const float* __restrict__ k,
                                              const float* __restrict__ v,
                                              float* __restrict__ o) {
  const int h = blockIdx.y;
  const int qb = blockIdx.x * 32;
  const int t = threadIdx.x;
  const int r = t >> 3;
  const int dl = (t & 7) * 16;
  const int qrow = qb + r;
  __shared__ float Ks[32][132];
  __shared__ float Vs[32][132];
  float qreg[16];
#pragma unroll
  for (int j = 0; j < 16; j += 4)
    *(float4*)&qreg[j] = *(const float4*)&q[(size_t)qrow * 2048 + h * 128 + dl + j];
  float oacc[16];
#pragma unroll
  for (int j = 0; j < 16; ++j) oacc[j] = 0.f;
  float m_run = -1e30f, l_run = 0.f;
  const int ntiles = blockIdx.x + 1;
  for (int kt = 0; kt < ntiles; ++kt) {
    const int kb = kt * 32;
    __syncthreads();
#pragma unroll
    for (int j = 0; j < 4; ++j) {
      int flat = (j * 256 + t) * 4;
      int rr = flat >> 7, dd = flat & 127;
      *(float4*)&Ks[rr][dd] = *(const float4*)&k[(size_t)(kb + rr) * 2048 + h * 128 + dd];
      *(float4*)&Vs[rr][dd] = *(const float4*)&v[(size_t)(kb + rr) * 2048 + h * 128 + dd];
    }
    __syncthreads();
    float s[32];
#pragma unroll
    for (int kk = 0; kk < 32; ++kk) {
      float p = 0.f;
#pragma unroll
      for (int j = 0; j < 16; ++j) p += qreg[j] * Ks[kk][dl + j];
      p += __shfl_xor(p, 1); p += __shfl_xor(p, 2); p += __shfl_xor(p, 4);
      s[kk] = (kb + kk <= qrow) ? p : -1e30f;
    }
    float tmax = s[0];
#pragma unroll
    for (int kk = 1; kk < 32; ++kk) tmax = fmaxf(tmax, s[kk]);
    float mnew = fmaxf(m_run, tmax);
    float scale = expf(m_run - mnew);
    l_run *= scale;
#pragma unroll
    for (int j = 0; j < 16; ++j) oacc[j] *= scale;
#pragma unroll
    for (int kk = 0; kk < 32; ++kk) {
      float pe = expf(s[kk] - mnew);
      l_run += pe;
#pragma unroll
      for (int j = 0; j < 16; ++j) oacc[j] += pe * Vs[kk][dl + j];
    }
    m_run = mnew;
  }
  float inv = 1.0f / l_run;
#pragma unroll
  for (int j = 0; j < 16; ++j)
    o[(size_t)qrow * 2048 + h * 128 + dl + j] = oacc[j] * inv;
}

// ---------------- GEMM kernels ----------------
// All GEMMs: C[M,N] = A[M,K] @ B[N,K]^T (inner dim contiguous both sides).
// MFMA 16x16x32 bf16; 128x128 block tile, 4 waves of 64x64 (4x4 frags).
// MFMA A/B fragment: lane holds row/col (lane&15), k-slots (lane>>4)*8+j —
// any consistent k-permutation is correct. C/D: col=lane&15, row=(lane>>4)*4+reg.

// Split-f32 GEMM (hi/lo bf16 decomposition, 3 MFMAs; drops lo*lo ~2^-18).
// z selects among up to 3 (B,C) pairs (QKV fusion). Optional residual add.
__global__ __launch_bounds__(256) void k_gemm_f32split(
    const float* __restrict__ A, const float* __restrict__ B0,
    const float* __restrict__ B1, const float* __restrict__ B2,
    float* __restrict__ C0, float* __restrict__ C1, float* __restrict__ C2,
    const float* __restrict__ resid) {
  __shared__ u16 lsAh[4096], lsAl[4096], lsBh[4096], lsBl[4096];
  const int z = blockIdx.z;
  const float* Bm = (z == 0) ? B0 : (z == 1) ? B1 : B2;
  float* Cm = (z == 0) ? C0 : (z == 1) ? C1 : C2;
  const int tid = threadIdx.x, lane = tid & 63, wv = tid >> 6;
  const int wr = (wv >> 1) * 64, wc = (wv & 1) * 64;
  const int fr = lane & 15, fg = lane >> 4;
  const int row0 = blockIdx.x * 128, col0 = blockIdx.y * 128;
  f32x4 acc[4][4];
#pragma unroll
  for (int i = 0; i < 4; ++i)
#pragma unroll
    for (int j = 0; j < 4; ++j) acc[i][j] = 0.f;

  for (int kt = 0; kt < 64; ++kt) {
    const int k0 = kt * 32;
#pragma unroll
    for (int j = 0; j < 4; ++j) {
      const int eo = (j * 256 + tid) * 4;
      const int rr = eo >> 5, cc = eo & 31;
      float4 av = *(const float4*)(A + (size_t)(row0 + rr) * 2048 + k0 + cc);
      float4 bv = *(const float4*)(Bm + (size_t)(col0 + rr) * 2048 + k0 + cc);
      U16x4 ahv{f2bf(av.x), f2bf(av.y), f2bf(av.z), f2bf(av.w)};
      U16x4 alv{f2bf(av.x - bf2f(ahv.x)), f2bf(av.y - bf2f(ahv.y)),
                f2bf(av.z - bf2f(ahv.z)), f2bf(av.w - bf2f(ahv.w))};
      U16x4 bhv{f2bf(bv.x), f2bf(bv.y), f2bf(bv.z), f2bf(bv.w)};
      U16x4 blv{f2bf(bv.x - bf2f(bhv.x)), f2bf(bv.y - bf2f(bhv.y)),
                f2bf(bv.z - bf2f(bhv.z)), f2bf(bv.w - bf2f(bhv.w))};
      *(U16x4*)&lsAh[eo] = ahv; *(U16x4*)&lsAl[eo] = alv;
      *(U16x4*)&lsBh[eo] = bhv; *(U16x4*)&lsBl[eo] = blv;
    }
    __syncthreads();
    short8 ah[4], al[4], bh[4], bl[4];
#pragma unroll
    for (int mi = 0; mi < 4; ++mi) {
      const int off = (wr + mi * 16 + fr) * 32 + fg * 8;
      ah[mi] = *(const short8*)&lsAh[off];
      al[mi] = *(const short8*)&lsAl[off];
    }
#pragma unroll
    for (int ni = 0; ni < 4; ++ni) {
      const int off = (wc + ni * 16 + fr) * 32 + fg * 8;
      bh[ni] = *(const short8*)&lsBh[off];
      bl[ni] = *(const short8*)&lsBl[off];
    }
#pragma unroll
    for (int mi = 0; mi < 4; ++mi)
#pragma unroll
      for (int ni = 0; ni < 4; ++ni) {
        f32x4 c = acc[mi][ni];
        c = __builtin_amdgcn_mfma_f32_16x16x32_bf16(al[mi], bh[ni], c, 0, 0, 0);
        c = __builtin_amdgcn_mfma_f32_16x16x32_bf16(ah[mi], bl[ni], c, 0, 0, 0);
        c = __builtin_amdgcn_mfma_f32_16x16x32_bf16(ah[mi], bh[ni], c, 0, 0, 0);
        acc[mi][ni] = c;
      }
    __syncthreads();
  }
  const bool hasres = (resid != nullptr);
#pragma unroll
  for (int mi = 0; mi < 4; ++mi)
#pragma unroll
    for (int ni = 0; ni < 4; ++ni)
#pragma unroll
      for (int qq = 0; qq < 4; ++qq) {
        const int row = row0 + wr + mi * 16 + fg * 4 + qq;
        const int col = col0 + wc + ni * 16 + fr;
        float val = acc[mi][ni][qq];
        if (hasres) val += resid[(size_t)row * 2048 + col];
        Cm[(size_t)row * 2048 + col] = val;
      }
}

// Staging helpers for bf16 GEMMs.
DI void stageA_bf16(const u16* __restrict__ A, size_t lda, int row0, int k0,
                    u16* lsA, int tid) {
  const int lane = tid & 63, wv = tid >> 6;
#pragma unroll
  for (int it = 0; it < 2; ++it) {
    const int ebase = it * 2048 + wv * 512;  // wave-uniform LDS base
    const int eo = ebase + lane * 8;
    const int rr = eo >> 5, cc = eo & 31;
    gload16(A + (size_t)(row0 + rr) * lda + k0 + cc, lsA + ebase);
  }
}
DI void stageB_f32(const float* __restrict__ B, size_t ldb, int row0, int k0,
                   u16* lsB, int tid) {
#pragma unroll
  for (int j = 0; j < 4; ++j) {
    const int eo = (j * 256 + tid) * 4;
    const int rr = eo >> 5, cc = eo & 31;
    float4 bv = *(const float4*)(B + (size_t)(row0 + rr) * ldb + k0 + cc);
    U16x4 hv{f2bf(bv.x), f2bf(bv.y), f2bf(bv.z), f2bf(bv.w)};
    *(U16x4*)&lsB[eo] = hv;
  }
}

// Dual GEMM + SiLU: act = silu(A@Bg^T) * (A@Bu^T) * weight. 128x64 tile.
// Experts: z = expert, weight = combine[row][e], out col offset e*1408.
// Shared: z = 0, weight = 1.
__global__ __launch_bounds__(256) void k_dual(
    const u16* __restrict__ A, const float* __restrict__ Bg_all,
    const float* __restrict__ Bu_all, size_t bstride,
    const float* __restrict__ comb, u16* __restrict__ outp, int ldc, int colstride) {
  __shared__ u16 lsA[4096], lsG[2048], lsU[2048];
  const int e = blockIdx.z;
  const float* Bg = Bg_all + (size_t)e * bstride;
  const float* Bu = Bu_all + (size_t)e * bstride;
  const int tid = threadIdx.x, lane = tid & 63, wv = tid >> 6;
  const int wr = (wv >> 1) * 64, wc = (wv & 1) * 32;
  const int fr = lane & 15, fg = lane >> 4;
  const int row0 = blockIdx.x * 128, n0 = blockIdx.y * 64;
  f32x4 ag[4][2], au[4][2];
#pragma unroll
  for (int i = 0; i < 4; ++i)
#pragma unroll
    for (int j = 0; j < 2; ++j) { ag[i][j] = 0.f; au[i][j] = 0.f; }

  for (int kt = 0; kt < 64; ++kt) {
    const int k0 = kt * 32;
    stageA_bf16(A, 2048, row0, k0, lsA, tid);
#pragma unroll
    for (int j = 0; j < 2; ++j) {
      const int eo = (j * 256 + tid) * 4;
      const int rr = eo >> 5, cc = eo & 31;
      float4 gv = *(const float4*)(Bg + (size_t)(n0 + rr) * 2048 + k0 + cc);
      float4 uv = *(const float4*)(Bu + (size_t)(n0 + rr) * 2048 + k0 + cc);
      U16x4 gh{f2bf(gv.x), f2bf(gv.y), f2bf(gv.z), f2bf(gv.w)};
      U16x4 uh{f2bf(uv.x), f2bf(uv.y), f2bf(uv.z), f2bf(uv.w)};
      *(U16x4*)&lsG[eo] = gh;
      *(U16x4*)&lsU[eo] = uh;
    }
    __syncthreads();
    short8 af[4], gf[2], uf[2];
#pragma unroll
    for (int mi = 0; mi < 4; ++mi)
      af[mi] = *(const short8*)&lsA[(wr + mi * 16 + fr) * 32 + fg * 8];
#pragma unroll
    for (int ni = 0; ni < 2; ++ni) {
      const int off = (wc + ni * 16 + fr) * 32 + fg * 8;
      gf[ni] = *(const short8*)&lsG[off];
      uf[ni] = *(const short8*)&lsU[off];
    }
#pragma unroll
    for (int mi = 0; mi < 4; ++mi)
#pragma unroll
      for (int ni = 0; ni < 2; ++ni) {
        ag[mi][ni] = __builtin_amdgcn_mfma_f32_16x16x32_bf16(af[mi], gf[ni], ag[mi][ni], 0, 0, 0);
        au[mi][ni] = __builtin_amdgcn_mfma_f32_16x16x32_bf16(af[mi], uf[ni], au[mi][ni], 0, 0, 0);
      }
    __syncthreads();
  }
#pragma unroll
  for (int mi = 0; mi < 4; ++mi)
#pragma unroll
    for (int ni = 0; ni < 2; ++ni)
#pragma unroll
      for (int qq = 0; qq < 4; ++qq) {
        const int row = row0 + wr + mi * 16 + fg * 4 + qq;
        const int col = n0 + wc + ni * 16 + fr;
        float g = ag[mi][ni][qq], u = au[mi][ni][qq];
        float act = g / (1.0f + expf(-g)) * u;
        float wgt = comb ? comb[row * 8 + e] : 1.0f;
        outp[(size_t)row * ldc + (size_t)e * colstride + col] = f2bf(act * wgt);
      }
}

// MoE down: routed[n,h] = sum_e sum_f actw[n, e*1408+f] * ed[e,h,f].
__global__ __launch_bounds__(256) void k_moedown(const u16* __restrict__ actw,
                                                 const float* __restrict__ ed,
                                                 float* __restrict__ routed) {
  __shared__ u16 lsA[4096], lsB[4096];
  const int tid = threadIdx.x, lane = tid & 63, wv = tid >> 6;
  const int wr = (wv >> 1) * 64, wc = (wv & 1) * 64;
  const int fr = lane & 15, fg = lane >> 4;
  const int row0 = blockIdx.x * 128, col0 = blockIdx.y * 128;
  f32x4 acc[4][4];
#pragma unroll
  for (int i = 0; i < 4; ++i)
#pragma unroll
    for (int j = 0; j < 4; ++j) acc[i][j] = 0.f;

  for (int e = 0; e < 8; ++e) {
    const u16* Ab = actw + (size_t)e * 1408;
    const float* Bb = ed + (size_t)e * 2048 * 1408;
    for (int kt = 0; kt < 44; ++kt) {
      const int k0 = kt * 32;
      stageA_bf16(Ab, 11264, row0, k0, lsA, tid);
      stageB_f32(Bb, 1408, col0, k0, lsB, tid);
      __syncthreads();
      short8 af[4], bf_[4];
#pragma unroll
      for (int mi = 0; mi < 4; ++mi)
        af[mi] = *(const short8*)&lsA[(wr + mi * 16 + fr) * 32 + fg * 8];
#pragma unroll
      for (int ni = 0; ni < 4; ++ni)
        bf_[ni] = *(const short8*)&lsB[(wc + ni * 16 + fr) * 32 + fg * 8];
#pragma unroll
      for (int mi = 0; mi < 4; ++mi)
#pragma unroll
        for (int ni = 0; ni < 4; ++ni)
          acc[mi][ni] = __builtin_amdgcn_mfma_f32_16x16x32_bf16(af[mi], bf_[ni], acc[mi][ni], 0, 0, 0);
      __syncthreads();
    }
  }
#pragma unroll
  for (int mi = 0; mi < 4; ++mi)
#pragma unroll
    for (int ni = 0; ni < 4; ++ni)
#pragma unroll
      for (int qq = 0; qq < 4; ++qq) {
        const int row = row0 + wr + mi * 16 + fg * 4 + qq;
        const int col = col0 + wc + ni * 16 + fr;
        routed[(size_t)row * 2048 + col] = acc[mi][ni][qq];
      }
}

// Shared down + final combine: out = x + routed + acts@sd^T.
__global__ __launch_bounds__(256) void k_shareddown(const u16* __restrict__ acts,
                                                    const float* __restrict__ sd,
                                                    const float* __restrict__ x,
                                                    const float* __restrict__ rtd,
                                                    float* __restrict__ outp) {
  __shared__ u16 lsA[4096], lsB[4096];
  const int tid = threadIdx.x, lane = tid & 63, wv = tid >> 6;
  const int wr = (wv >> 1) * 64, wc = (wv & 1) * 64;
  const int fr = lane & 15, fg = lane >> 4;
  const int row0 = blockIdx.x * 128, col0 = blockIdx.y * 128;
  f32x4 acc[4][4];
#pragma unroll
  for (int i = 0; i < 4; ++i)
#pragma unroll
    for (int j = 0; j < 4; ++j) acc[i][j] = 0.f;

  for (int kt = 0; kt < 88; ++kt) {
    const int k0 = kt * 32;
    stageA_bf16(acts, 2816, row0, k0, lsA, tid);
    stageB_f32(sd, 2816, col0, k0, lsB, tid);
    __syncthreads();
    short8 af[4], bf_[4];
#pragma unroll
    for (int mi = 0; mi < 4; ++mi)
      af[mi] = *(const short8*)&lsA[(wr + mi * 16 + fr) * 32 + fg * 8];
#pragma unroll
    for (int ni = 0; ni < 4; ++ni)
      bf_[ni] = *(const short8*)&lsB[(wc + ni * 16 + fr) * 32 + fg * 8];
#pragma unroll
    for (int mi = 0; mi < 4; ++mi)
#pragma unroll
      for (int ni = 0; ni < 4; ++ni)
        acc[mi][ni] = __builtin_amdgcn_mfma_f32_16x16x32_bf16(af[mi], bf_[ni], acc[mi][ni], 0, 0, 0);
    __syncthreads();
  }
#pragma unroll
  for (int mi = 0; mi < 4; ++mi)
#pragma unroll
    for (int ni = 0; ni < 4; ++ni)
#pragma unroll
      for (int qq = 0; qq < 4; ++qq) {
        const int row = row0 + wr + mi * 16 + fg * 4 + qq;
        const int col = col0 + wc + ni * 16 + fr;
        size_t idx = (size_t)row * 2048 + col;
        outp[idx] = acc[mi][ni][qq] + x[idx] + rtd[idx];
      }
}

// ---------------- host launch ----------------

extern "C" void kernel_launch(void* const* d_in, const int* in_sizes, int n_in,
                              void* d_out, int out_size, void* d_ws, size_t ws_size,
                              hipStream_t stream) {
  (void)in_sizes; (void)n_in; (void)out_size; (void)ws_size;
  const float* hidden = (const float*)d_in[0];
  const float* ln1 = (const float*)d_in[1];
  const float* ln2 = (const float*)d_in[2];
  const float* wq = (const float*)d_in[3];
  const float* wk = (const float*)d_in[4];
  const float* wvw = (const float*)d_in[5];
  const float* wo = (const float*)d_in[6];
  const float* gw = (const float*)d_in[7];
  const float* eg = (const float*)d_in[8];
  const float* eu = (const float*)d_in[9];
  const float* ed = (const float*)d_in[10];
  const float* sg = (const float*)d_in[11];
  const float* su = (const float*)d_in[12];
  const float* sd = (const float*)d_in[13];
  float* out = (float*)d_out;
  char* ws = (char*)d_ws;

  const size_t MB = 1ull << 20;
  float* hn = (float*)(ws + 0);           // 8MB  f32 rmsnorm1(hidden)
  float* qf = (float*)(ws + 8 * MB);      // 8MB
  float* kf = (float*)(ws + 16 * MB);     // 8MB
  float* vf = (float*)(ws + 24 * MB);     // 8MB
  float* att = (float*)(ws + 32 * MB);    // 8MB
  float* xf = (float*)(ws + 40 * MB);     // 8MB  residual2
  float* h2f = (float*)(ws + 48 * MB);    // 8MB
  u16* h2b = (u16*)(ws + 56 * MB);        // 4MB
  float* cmb = (float*)(ws + 60 * MB);    // 32KB
  float* tab = (float*)(ws + 61 * MB);    // 512KB
  u16* actw = (u16*)(ws + 62 * MB);       // 22MB  [1024][8*1408] bf16
  u16* acts = (u16*)(ws + 85 * MB);       // 5.5MB [1024][2816] bf16
  float* rtd = (float*)(ws + 91 * MB);    // 8MB   (total ~99MB)

  k_ropetab<<<256, 256, 0, stream>>>(tab);
  k_rmsnorm<<<1024, 256, 0, stream>>>(hidden, ln1, hn, nullptr);
  k_gemm_f32split<<<dim3(8, 16, 3), 256, 0, stream>>>(hn, wq, wk, wvw, qf, kf, vf, nullptr);
  k_rope<<<4096, 256, 0, stream>>>(qf, kf, tab);
  k_attn<<<dim3(32, 16), 256, 0, stream>>>(qf, kf, vf, att);
  k_gemm_f32split<<<dim3(8, 16, 1), 256, 0, stream>>>(att, wo, wo, wo, xf, xf, xf, hidden);
  k_rmsnorm<<<1024, 256, 0, stream>>>(xf, ln2, h2f, h2b);
  k_router<<<1024, 256, 0, stream>>>(h2f, gw, cmb);
  k_dual<<<dim3(8, 22, 8), 256, 0, stream>>>(h2b, eg, eu, (size_t)1408 * 2048, cmb, actw, 11264, 1408);
  k_dual<<<dim3(8, 44, 1), 256, 0, stream>>>(h2b, sg, su, 0, nullptr, acts, 2816, 0);
  k_moedown<<<dim3(8, 16), 256, 0, stream>>>(actw, ed, rtd);
  k_shareddown<<<dim3(8, 16), 256, 0, stream>>>(acts, sd, xf, rtd, out);
}

// Round 2
// 1320.819 us; speedup vs baseline: 1.1965x; 1.1965x over previous
//
#include <hip/hip_runtime.h>
#include <hip/hip_bf16.h>

// DeepseekDecoderLayer on MI355X. Round 1: MFMA split-precision attention.
// Pipeline: rmsnorm1 -> QKV (f32-split MFMA) -> RoPE (f64 table) -> split K/Q/V
// to bf16 hi/lo -> causal flash attn (split MFMA, lane-local softmax) ->
// O-proj+res (f32-split MFMA) -> rmsnorm2 -> router (f32, exact top-2) ->
// dense MoE dual-GEMM + shared dual-GEMM (bf16 MFMA) -> down GEMMs -> out.
// Precision: everything feeding the router is f32-accurate (split-bf16 3-MFMA
// trick, err ~2^-18) because top-2 selection flips at logit gaps ~2.5e-4.

#define DI __device__ __forceinline__

typedef __attribute__((ext_vector_type(8))) short short8;
typedef __attribute__((ext_vector_type(4))) float f32x4;
using u16 = unsigned short;

struct alignas(8) U16x4 { u16 x, y, z, w; };

DI u16 f2bf(float f) {
  unsigned u = __float_as_uint(f);
  u += 0x7fffu + ((u >> 16) & 1u);
  return (u16)(u >> 16);
}
DI float bf2f(u16 h) { return __uint_as_float(((unsigned)h) << 16); }

DI void gload16(const void* g, void* l) {
  __builtin_amdgcn_global_load_lds((const __attribute__((address_space(1))) void*)g,
                                   (__attribute__((address_space(3))) void*)l, 16, 0, 0);
}

// ---------------- small kernels ----------------

// RoPE cos/sin table in double precision (matches f64 numpy reference closely).
__global__ __launch_bounds__(256) void k_ropetab(float* __restrict__ tab) {
  int idx = blockIdx.x * 256 + threadIdx.x;  // < 1024*64
  int s = idx >> 6, i = idx & 63;
  double inv = pow(10000.0, -(double)(2 * i) / 128.0);
  double ang = (double)s * inv;
  tab[idx * 2 + 0] = (float)cos(ang);
  tab[idx * 2 + 1] = (float)sin(ang);
}

// RMSNorm row kernel: optional f32 and bf16 outputs.
__global__ __launch_bounds__(256) void k_rmsnorm(const float* __restrict__ in,
                                                 const float* __restrict__ w,
                                                 float* __restrict__ outf,
                                                 u16* __restrict__ outb) {
  const int row = blockIdx.x, t = threadIdx.x;
  const float* x = in + (size_t)row * 2048;
  float4 a = *(const float4*)&x[t * 4];
  float4 b = *(const float4*)&x[1024 + t * 4];
  float ss = a.x * a.x + a.y * a.y + a.z * a.z + a.w * a.w +
             b.x * b.x + b.y * b.y + b.z * b.z + b.w * b.w;
#pragma unroll
  for (int off = 32; off; off >>= 1) ss += __shfl_xor(ss, off);
  __shared__ float red[4];
  if ((t & 63) == 0) red[t >> 6] = ss;
  __syncthreads();
  float total = red[0] + red[1] + red[2] + red[3];
  float r = 1.0f / sqrtf(total * (1.0f / 2048.0f) + 1e-6f);
  float4 wa = *(const float4*)&w[t * 4];
  float4 wb = *(const float4*)&w[1024 + t * 4];
  float4 oa, ob;
  oa.x = a.x * r * wa.x; oa.y = a.y * r * wa.y; oa.z = a.z * r * wa.z; oa.w = a.w * r * wa.w;
  ob.x = b.x * r * wb.x; ob.y = b.y * r * wb.y; ob.z = b.z * r * wb.z; ob.w = b.w * r * wb.w;
  if (outf) {
    *(float4*)&outf[(size_t)row * 2048 + t * 4] = oa;
    *(float4*)&outf[(size_t)row * 2048 + 1024 + t * 4] = ob;
  }
  if (outb) {
    U16x4 ua{f2bf(oa.x), f2bf(oa.y), f2bf(oa.z), f2bf(oa.w)};
    U16x4 ub{f2bf(ob.x), f2bf(ob.y), f2bf(ob.z), f2bf(ob.w)};
    *(U16x4*)&outb[(size_t)row * 2048 + t * 4] = ua;
    *(U16x4*)&outb[(size_t)row * 2048 + 1024 + t * 4] = ub;
  }
}

// Apply RoPE in-place to q (with 1/sqrt(128) folded in) and k. f32.
__global__ __launch_bounds__(256) void k_rope(float* __restrict__ q, float* __restrict__ k,
                                              const float* __restrict__ tab) {
  int idx = blockIdx.x * 256 + threadIdx.x;  // < 1024*16*64
  int s = idx >> 10, rem = idx & 1023;
  int h = rem >> 6, i = rem & 63;
  size_t base = (size_t)s * 2048 + h * 128 + i;
  float c = tab[(s * 64 + i) * 2 + 0];
  float sn = tab[(s * 64 + i) * 2 + 1];
  const float qs = 0.08838834764831845f;  // 1/sqrt(128)
  float q1 = q[base], q2 = q[base + 64];
  q[base] = (q1 * c - q2 * sn) * qs;
  q[base + 64] = (q2 * c + q1 * sn) * qs;
  float k1 = k[base], k2 = k[base + 64];
  k[base] = k1 * c - k2 * sn;
  k[base + 64] = k2 * c + k1 * sn;
}

// Split f32 q/k/v into bf16 hi/lo. Q,K keep [s][2048] layout; V transposed to
// [h*128+d][s] (for direct MFMA A-operand loads in the PV step).
__global__ __launch_bounds__(256) void k_splitkv(
    const float* __restrict__ qf, const float* __restrict__ kf,
    const float* __restrict__ vf,
    u16* __restrict__ Qh, u16* __restrict__ Ql,
    u16* __restrict__ Kh, u16* __restrict__ Kl,
    u16* __restrict__ Vth, u16* __restrict__ Vtl) {
  int idx = (blockIdx.x * 256 + threadIdx.x) * 4;  // over 1024*2048 elements
  int s = idx >> 11, c = idx & 2047;
  float4 q4 = *(const float4*)&qf[idx];
  U16x4 qh{f2bf(q4.x), f2bf(q4.y), f2bf(q4.z), f2bf(q4.w)};
  U16x4 ql{f2bf(q4.x - bf2f(qh.x)), f2bf(q4.y - bf2f(qh.y)),
           f2bf(q4.z - bf2f(qh.z)), f2bf(q4.w - bf2f(qh.w))};
  *(U16x4*)&Qh[idx] = qh; *(U16x4*)&Ql[idx] = ql;
  float4 k4 = *(const float4*)&kf[idx];
  U16x4 kh{f2bf(k4.x), f2bf(k4.y), f2bf(k4.z), f2bf(k4.w)};
  U16x4 kl{f2bf(k4.x - bf2f(kh.x)), f2bf(k4.y - bf2f(kh.y)),
           f2bf(k4.z - bf2f(kh.z)), f2bf(k4.w - bf2f(kh.w))};
  *(U16x4*)&Kh[idx] = kh; *(U16x4*)&Kl[idx] = kl;
  float4 v4 = *(const float4*)&vf[idx];
  float vv[4] = {v4.x, v4.y, v4.z, v4.w};
#pragma unroll
  for (int i = 0; i < 4; ++i) {
    u16 hv = f2bf(vv[i]);
    u16 lv = f2bf(vv[i] - bf2f(hv));
    Vth[(size_t)(c + i) * 1024 + s] = hv;
    Vtl[(size_t)(c + i) * 1024 + s] = lv;
  }
}

// Causal flash attention via split-bf16 MFMA (3-term: h*h + l*h + h*l).
// Block = 2 independent waves; each wave owns a 16-row q strip of one head.
// S^T = K·Q^T  -> D col = lane&15 = q  -> softmax is lane-local (+2 shfl).
// O^T = V^T·P^T -> D col = lane&15 = q -> rescale lane-local. P round-trips
// through wave-private LDS (padded [16][40] u16, conflict-free-ish).
__global__ __launch_bounds__(128) void k_attn_mfma(
    const u16* __restrict__ Qh, const u16* __restrict__ Ql,
    const u16* __restrict__ Kh, const u16* __restrict__ Kl,
    const u16* __restrict__ Vth, const u16* __restrict__ Vtl,
    float* __restrict__ o) {
  const int h = blockIdx.y;
  const int wave = threadIdx.x >> 6, lane = threadIdx.x & 63;
  const int strip = blockIdx.x * 32 + wave * 16;
  const int l15 = lane & 15, grp = lane >> 4;
  __shared__ u16 Plh[2][16][40], Pll[2][16][40];
  u16(*plh)[40] = Plh[wave];
  u16(*pll)[40] = Pll[wave];

  short8 qfh[4], qfl[4];
  const size_t qbase = (size_t)(strip + l15) * 2048 + h * 128;
#pragma unroll
  for (int c = 0; c < 4; ++c) {
    qfh[c] = *(const short8*)&Qh[qbase + c * 32 + grp * 8];
    qfl[c] = *(const short8*)&Ql[qbase + c * 32 + grp * 8];
  }
  f32x4 oacc[8];
#pragma unroll
  for (int dc = 0; dc < 8; ++dc) oacc[dc] = 0.f;
  float m_run = -1e30f, l_run = 0.f;
  const int q_glob = strip + l15;
  const int tend = (strip >> 5) + 1;

  for (int t = 0; t < tend; ++t) {
    const int kvb = t * 32;
    f32x4 s[2];
#pragma unroll
    for (int sub = 0; sub < 2; ++sub) {
      f32x4 a = {0.f, 0.f, 0.f, 0.f};
      const size_t kbase = (size_t)(kvb + sub * 16 + l15) * 2048 + h * 128;
#pragma unroll
      for (int c = 0; c < 4; ++c) {
        short8 khf = *(const short8*)&Kh[kbase + c * 32 + grp * 8];
        short8 klf = *(const short8*)&Kl[kbase + c * 32 + grp * 8];
        a = __builtin_amdgcn_mfma_f32_16x16x32_bf16(khf, qfh[c], a, 0, 0, 0);
        a = __builtin_amdgcn_mfma_f32_16x16x32_bf16(klf, qfh[c], a, 0, 0, 0);
        a = __builtin_amdgcn_mfma_f32_16x16x32_bf16(khf, qfl[c], a, 0, 0, 0);
      }
      s[sub] = a;
    }
    if (t == tend - 1) {
#pragma unroll
      for (int sub = 0; sub < 2; ++sub)
#pragma unroll
        for (int r = 0; r < 4; ++r) {
          int kv = kvb + sub * 16 + grp * 4 + r;
          if (kv > q_glob) s[sub][r] = -1e30f;
        }
    }
    float tmax = s[0][0];
#pragma unroll
    for (int sub = 0; sub < 2; ++sub)
#pragma unroll
      for (int r = 0; r < 4; ++r) tmax = fmaxf(tmax, s[sub][r]);
    tmax = fmaxf(tmax, __shfl_xor(tmax, 16));
    tmax = fmaxf(tmax, __shfl_xor(tmax, 32));
    float mnew = fmaxf(m_run, tmax);
    float scale = expf(m_run - mnew);
    float p[8], lsum = 0.f;
#pragma unroll
    for (int sub = 0; sub < 2; ++sub)
#pragma unroll
      for (int r = 0; r < 4; ++r) {
        float pe = expf(s[sub][r] - mnew);
        p[sub * 4 + r] = pe;
        lsum += pe;
      }
    lsum += __shfl_xor(lsum, 16);
    lsum += __shfl_xor(lsum, 32);
    l_run = l_run * scale + lsum;
    m_run = mnew;
#pragma unroll
    for (int dc = 0; dc < 8; ++dc) oacc[dc] *= scale;
    // P split -> wave-private LDS (packed pair writes).
#pragma unroll
    for (int sub = 0; sub < 2; ++sub)
#pragma unroll
      for (int rp = 0; rp < 2; ++rp) {
        int i0 = sub * 4 + rp * 2;
        u16 h0 = f2bf(p[i0]), h1 = f2bf(p[i0 + 1]);
        u16 lo0 = f2bf(p[i0] - bf2f(h0)), lo1 = f2bf(p[i0 + 1] - bf2f(h1));
        int kvoff = sub * 16 + grp * 4 + rp * 2;
        *(unsigned*)&plh[l15][kvoff] = (unsigned)h0 | ((unsigned)h1 << 16);
        *(unsigned*)&pll[l15][kvoff] = (unsigned)lo0 | ((unsigned)lo1 << 16);
      }
    short8 phf = *(const short8*)&plh[l15][grp * 8];
    short8 plf = *(const short8*)&pll[l15][grp * 8];
#pragma unroll
    for (int dc = 0; dc < 8; ++dc) {
      const size_t vbase = (size_t)(h * 128 + dc * 16 + l15) * 1024 + kvb + grp * 8;
      short8 vh = *(const short8*)&Vth[vbase];
      short8 vl = *(const short8*)&Vtl[vbase];
      f32x4 acc = oacc[dc];
      acc = __builtin_amdgcn_mfma_f32_16x16x32_bf16(vh, phf, acc, 0, 0, 0);
      acc = __builtin_amdgcn_mfma_f32_16x16x32_bf16(vl, phf, acc, 0, 0, 0);
      acc = __builtin_amdgcn_mfma_f32_16x16x32_bf16(vh, plf, acc, 0, 0, 0);
      oacc[dc] = acc;
    }
  }
  float inv = 1.0f / l_run;
#pragma unroll
  for (int dc = 0; dc < 8; ++dc)
#pragma unroll
    for (int r = 0; r < 4; ++r)
      o[(size_t)q_glob * 2048 + h * 128 + dc * 16 + grp * 4 + r] = oacc[dc][r] * inv;
}

// Router: f32 logits from f32 h2 (exact top-2 selection), combine weights out.
__global__ __launch_bounds__(256) void k_router(const float* __restrict__ h2f,
                                                const float* __restrict__ gw,
                                                float* __restrict__ comb) {
  const int tok = blockIdx.x;
  const float* hrow = h2f + (size_t)tok * 2048;
  float part[8];
#pragma unroll
  for (int e = 0; e < 8; ++e) part[e] = 0.f;
  for (int j = 0; j < 8; ++j) {
    int p = j * 256 + threadIdx.x;
    float hv = hrow[p];
#pragma unroll
    for (int e = 0; e < 8; ++e) part[e] += hv * gw[e * 2048 + p];
  }
#pragma unroll
  for (int e = 0; e < 8; ++e)
#pragma unroll
    for (int off = 32; off; off >>= 1) part[e] += __shfl_xor(part[e], off);
  __shared__ float red[4][8];
  int wv = threadIdx.x >> 6, lane = threadIdx.x & 63;
  if (lane == 0) {
#pragma unroll
    for (int e = 0; e < 8; ++e) red[wv][e] = part[e];
  }
  __syncthreads();
  if (threadIdx.x == 0) {
    float lg[8];
#pragma unroll
    for (int e = 0; e < 8; ++e) lg[e] = red[0][e] + red[1][e] + red[2][e] + red[3][e];
    float m = lg[0];
#pragma unroll
    for (int e = 1; e < 8; ++e) m = fmaxf(m, lg[e]);
    float ex[8], s = 0.f;
#pragma unroll
    for (int e = 0; e < 8; ++e) { ex[e] = expf(lg[e] - m); s += ex[e]; }
#pragma unroll
    for (int e = 0; e < 8; ++e) ex[e] /= s;
    int i1 = 0;
#pragma unroll
    for (int e = 1; e < 8; ++e) if (ex[e] > ex[i1]) i1 = e;
    int i2 = (i1 == 0) ? 1 : 0;
#pragma unroll
    for (int e = 0; e < 8; ++e) if (e != i1 && ex[e] > ex[i2]) i2 = e;
    float s2 = ex[i1] + ex[i2] + 1e-20f;
#pragma unroll
    for (int e = 0; e < 8; ++e)
      comb[tok * 8 + e] = (e == i1) ? ex[i1] / s2 : (e == i2) ? ex[i2] / s2 : 0.f;
  }
}

// ---------------- GEMM kernels ----------------
// All GEMMs: C[M,N] = A[M,K] @ B[N,K]^T. MFMA 16x16x32 bf16; 128x128 block
// tile, 4 waves of 64x64 (4x4 frags). C/D: col=lane&15, row=(lane>>4)*4+reg.

__global__ __launch_bounds__(256) void k_gemm_f32split(
    const float* __restrict__ A, const float* __restrict__ B0,
    const float* __restrict__ B1, const float* __restrict__ B2,
    float* __restrict__ C0, float* __restrict__ C1, float* __restrict__ C2,
    const float* __restrict__ resid) {
  __shared__ u16 lsAh[4096], lsAl[4096], lsBh[4096], lsBl[4096];
  const int z = blockIdx.z;
  const float* Bm = (z == 0) ? B0 : (z == 1) ? B1 : B2;
  float* Cm = (z == 0) ? C0 : (z == 1) ? C1 : C2;
  const int tid = threadIdx.x, lane = tid & 63, wv = tid >> 6;
  const int wr = (wv >> 1) * 64, wc = (wv & 1) * 64;
  const int fr = lane & 15, fg = lane >> 4;
  const int row0 = blockIdx.x * 128, col0 = blockIdx.y * 128;
  f32x4 acc[4][4];
#pragma unroll
  for (int i = 0; i < 4; ++i)
#pragma unroll
    for (int j = 0; j < 4; ++j) acc[i][j] = 0.f;

  for (int kt = 0; kt < 64; ++kt) {
    const int k0 = kt * 32;
#pragma unroll
    for (int j = 0; j < 4; ++j) {
      const int eo = (j * 256 + tid) * 4;
      const int rr = eo >> 5, cc = eo & 31;
      float4 av = *(const float4*)(A + (size_t)(row0 + rr) * 2048 + k0 + cc);
      float4 bv = *(const float4*)(Bm + (size_t)(col0 + rr) * 2048 + k0 + cc);
      U16x4 ahv{f2bf(av.x), f2bf(av.y), f2bf(av.z), f2bf(av.w)};
      U16x4 alv{f2bf(av.x - bf2f(ahv.x)), f2bf(av.y - bf2f(ahv.y)),
                f2bf(av.z - bf2f(ahv.z)), f2bf(av.w - bf2f(ahv.w))};
      U16x4 bhv{f2bf(bv.x), f2bf(bv.y), f2bf(bv.z), f2bf(bv.w)};
      U16x4 blv{f2bf(bv.x - bf2f(bhv.x)), f2bf(bv.y - bf2f(bhv.y)),
                f2bf(bv.z - bf2f(bhv.z)), f2bf(bv.w - bf2f(bhv.w))};
      *(U16x4*)&lsAh[eo] = ahv; *(U16x4*)&lsAl[eo] = alv;
      *(U16x4*)&lsBh[eo] = bhv; *(U16x4*)&lsBl[eo] = blv;
    }
    __syncthreads();
    short8 ah[4], al[4], bh[4], bl[4];
#pragma unroll
    for (int mi = 0; mi < 4; ++mi) {
      const int off = (wr + mi * 16 + fr) * 32 + fg * 8;
      ah[mi] = *(const short8*)&lsAh[off];
      al[mi] = *(const short8*)&lsAl[off];
    }
#pragma unroll
    for (int ni = 0; ni < 4; ++ni) {
      const int off = (wc + ni * 16 + fr) * 32 + fg * 8;
      bh[ni] = *(const short8*)&lsBh[off];
      bl[ni] = *(const short8*)&lsBl[off];
    }
#pragma unroll
    for (int mi = 0; mi < 4; ++mi)
#pragma unroll
      for (int ni = 0; ni < 4; ++ni) {
        f32x4 c = acc[mi][ni];
        c = __builtin_amdgcn_mfma_f32_16x16x32_bf16(al[mi], bh[ni], c, 0, 0, 0);
        c = __builtin_amdgcn_mfma_f32_16x16x32_bf16(ah[mi], bl[ni], c, 0, 0, 0);
        c = __builtin_amdgcn_mfma_f32_16x16x32_bf16(ah[mi], bh[ni], c, 0, 0, 0);
        acc[mi][ni] = c;
      }
    __syncthreads();
  }
  const bool hasres = (resid != nullptr);
#pragma unroll
  for (int mi = 0; mi < 4; ++mi)
#pragma unroll
    for (int ni = 0; ni < 4; ++ni)
#pragma unroll
      for (int qq = 0; qq < 4; ++qq) {
        const int row = row0 + wr + mi * 16 + fg * 4 + qq;
        const int col = col0 + wc + ni * 16 + fr;
        float val = acc[mi][ni][qq];
        if (hasres) val += resid[(size_t)row * 2048 + col];
        Cm[(size_t)row * 2048 + col] = val;
      }
}

// Staging helpers for bf16 GEMMs.
DI void stageA_bf16(const u16* __restrict__ A, size_t lda, int row0, int k0,
                    u16* lsA, int tid) {
  const int lane = tid & 63, wv = tid >> 6;
#pragma unroll
  for (int it = 0; it < 2; ++it) {
    const int ebase = it * 2048 + wv * 512;  // wave-uniform LDS base
    const int eo = ebase + lane * 8;
    const int rr = eo >> 5, cc = eo & 31;
    gload16(A + (size_t)(row0 + rr) * lda + k0 + cc, lsA + ebase);
  }
}
DI void stageB_f32(const float* __restrict__ B, size_t ldb, int row0, int k0,
                   u16* lsB, int tid) {
#pragma unroll
  for (int j = 0; j < 4; ++j) {
    const int eo = (j * 256 + tid) * 4;
    const int rr = eo >> 5, cc = eo & 31;
    float4 bv = *(const float4*)(B + (size_t)(row0 + rr) * ldb + k0 + cc);
    U16x4 hv{f2bf(bv.x), f2bf(bv.y), f2bf(bv.z), f2bf(bv.w)};
    *(U16x4*)&lsB[eo] = hv;
  }
}

// Dual GEMM + SiLU: act = silu(A@Bg^T) * (A@Bu^T) * weight. 128x64 tile.
__global__ __launch_bounds__(256) void k_dual(
    const u16* __restrict__ A, const float* __restrict__ Bg_all,
    const float* __restrict__ Bu_all, size_t bstride,
    const float* __restrict__ comb, u16* __restrict__ outp, int ldc, int colstride) {
  __shared__ u16 lsA[4096], lsG[2048], lsU[2048];
  const int e = blockIdx.z;
  const float* Bg = Bg_all + (size_t)e * bstride;
  const float* Bu = Bu_all + (size_t)e * bstride;
  const int tid = threadIdx.x, lane = tid & 63, wv = tid >> 6;
  const int wr = (wv >> 1) * 64, wc = (wv & 1) * 32;
  const int fr = lane & 15, fg = lane >> 4;
  const int row0 = blockIdx.x * 128, n0 = blockIdx.y * 64;
  f32x4 ag[4][2], au[4][2];
#pragma unroll
  for (int i = 0; i < 4; ++i)
#pragma unroll
    for (int j = 0; j < 2; ++j) { ag[i][j] = 0.f; au[i][j] = 0.f; }

  for (int kt = 0; kt < 64; ++kt) {
    const int k0 = kt * 32;
    stageA_bf16(A, 2048, row0, k0, lsA, tid);
#pragma unroll
    for (int j = 0; j < 2; ++j) {
      const int eo = (j * 256 + tid) * 4;
      const int rr = eo >> 5, cc = eo & 31;
      float4 gv = *(const float4*)(Bg + (size_t)(n0 + rr) * 2048 + k0 + cc);
      float4 uv = *(const float4*)(Bu + (size_t)(n0 + rr) * 2048 + k0 + cc);
      U16x4 gh{f2bf(gv.x), f2bf(gv.y), f2bf(gv.z), f2bf(gv.w)};
      U16x4 uh{f2bf(uv.x), f2bf(uv.y), f2bf(uv.z), f2bf(uv.w)};
      *(U16x4*)&lsG[eo] = gh;
      *(U16x4*)&lsU[eo] = uh;
    }
    __syncthreads();
    short8 af[4], gf[2], uf[2];
#pragma unroll
    for (int mi = 0; mi < 4; ++mi)
      af[mi] = *(const short8*)&lsA[(wr + mi * 16 + fr) * 32 + fg * 8];
#pragma unroll
    for (int ni = 0; ni < 2; ++ni) {
      const int off = (wc + ni * 16 + fr) * 32 + fg * 8;
      gf[ni] = *(const short8*)&lsG[off];
      uf[ni] = *(const short8*)&lsU[off];
    }
#pragma unroll
    for (int mi = 0; mi < 4; ++mi)
#pragma unroll
      for (int ni = 0; ni < 2; ++ni) {
        ag[mi][ni] = __builtin_amdgcn_mfma_f32_16x16x32_bf16(af[mi], gf[ni], ag[mi][ni], 0, 0, 0);
        au[mi][ni] = __builtin_amdgcn_mfma_f32_16x16x32_bf16(af[mi], uf[ni], au[mi][ni], 0, 0, 0);
      }
    __syncthreads();
  }
#pragma unroll
  for (int mi = 0; mi < 4; ++mi)
#pragma unroll
    for (int ni = 0; ni < 2; ++ni)
#pragma unroll
      for (int qq = 0; qq < 4; ++qq) {
        const int row = row0 + wr + mi * 16 + fg * 4 + qq;
        const int col = n0 + wc + ni * 16 + fr;
        float g = ag[mi][ni][qq], u = au[mi][ni][qq];
        float act = g / (1.0f + expf(-g)) * u;
        float wgt = comb ? comb[row * 8 + e] : 1.0f;
        outp[(size_t)row * ldc + (size_t)e * colstride + col] = f2bf(act * wgt);
      }
}

// MoE down: routed[n,h] = sum_e sum_f actw[n, e*1408+f] * ed[e,h,f].
__global__ __launch_bounds__(256) void k_moedown(const u16* __restrict__ actw,
                                                 const float* __restrict__ ed,
                                                 float* __restrict__ routed) {
  __shared__ u16 lsA[4096], lsB[4096];
  const int tid = threadIdx.x, lane = tid & 63, wv = tid >> 6;
  const int wr = (wv >> 1) * 64, wc = (wv & 1) * 64;
  const int fr = lane & 15, fg = lane >> 4;
  const int row0 = blockIdx.x * 128, col0 = blockIdx.y * 128;
  f32x4 acc[4][4];
#pragma unroll
  for (int i = 0; i < 4; ++i)
#pragma unroll
    for (int j = 0; j < 4; ++j) acc[i][j] = 0.f;

  for (int e = 0; e < 8; ++e) {
    const u16* Ab = actw + (size_t)e * 1408;
    const float* Bb = ed + (size_t)e * 2048 * 1408;
    for (int kt = 0; kt < 44; ++kt) {
      const int k0 = kt * 32;
      stageA_bf16(Ab, 11264, row0, k0, lsA, tid);
      stageB_f32(Bb, 1408, col0, k0, lsB, tid);
      __syncthreads();
      short8 af[4], bf_[4];
#pragma unroll
      for (int mi = 0; mi < 4; ++mi)
        af[mi] = *(const short8*)&lsA[(wr + mi * 16 + fr) * 32 + fg * 8];
#pragma unroll
      for (int ni = 0; ni < 4; ++ni)
        bf_[ni] = *(const short8*)&lsB[(wc + ni * 16 + fr) * 32 + fg * 8];
#pragma unroll
      for (int mi = 0; mi < 4; ++mi)
#pragma unroll
        for (int ni = 0; ni < 4; ++ni)
          acc[mi][ni] = __builtin_amdgcn_mfma_f32_16x16x32_bf16(af[mi], bf_[ni], acc[mi][ni], 0, 0, 0);
      __syncthreads();
    }
  }
#pragma unroll
  for (int mi = 0; mi < 4; ++mi)
#pragma unroll
    for (int ni = 0; ni < 4; ++ni)
#pragma unroll
      for (int qq = 0; qq < 4; ++qq) {
        const int row = row0 + wr + mi * 16 + fg * 4 + qq;
        const int col = col0 + wc + ni * 16 + fr;
        routed[(size_t)row * 2048 + col] = acc[mi][ni][qq];
      }
}

// Shared down + final combine: out = x + routed + acts@sd^T.
__global__ __launch_bounds__(256) void k_shareddown(const u16* __restrict__ acts,
                                                    const float* __restrict__ sd,
                                                    const float* __restrict__ x,
                                                    const float* __restrict__ rtd,
                                                    float* __restrict__ outp) {
  __shared__ u16 lsA[4096], lsB[4096];
  const int tid = threadIdx.x, lane = tid & 63, wv = tid >> 6;
  const int wr = (wv >> 1) * 64, wc = (wv & 1) * 64;
  const int fr = lane & 15, fg = lane >> 4;
  const int row0 = blockIdx.x * 128, col0 = blockIdx.y * 128;
  f32x4 acc[4][4];
#pragma unroll
  for (int i = 0; i < 4; ++i)
#pragma unroll
    for (int j = 0; j < 4; ++j) acc[i][j] = 0.f;

  for (int kt = 0; kt < 88; ++kt) {
    const int k0 = kt * 32;
    stageA_bf16(acts, 2816, row0, k0, lsA, tid);
    stageB_f32(sd, 2816, col0, k0, lsB, tid);
    __syncthreads();
    short8 af[4], bf_[4];
#pragma unroll
    for (int mi = 0; mi < 4; ++mi)
      af[mi] = *(const short8*)&lsA[(wr + mi * 16 + fr) * 32 + fg * 8];
#pragma unroll
    for (int ni = 0; ni < 4; ++ni)
      bf_[ni] = *(const short8*)&lsB[(wc + ni * 16 + fr) * 32 + fg * 8];
#pragma unroll
    for (int mi = 0; mi < 4; ++mi)
#pragma unroll
      for (int ni = 0; ni < 4; ++ni)
        acc[mi][ni] = __builtin_amdgcn_mfma_f32_16x16x32_bf16(af[mi], bf_[ni], acc[mi][ni], 0, 0, 0);
    __syncthreads();
  }
#pragma unroll
  for (int mi = 0; mi < 4; ++mi)
#pragma unroll
    for (int ni = 0; ni < 4; ++ni)
#pragma unroll
      for (int qq = 0; qq < 4; ++qq) {
        const int row = row0 + wr + mi * 16 + fg * 4 + qq;
        const int col = col0 + wc + ni * 16 + fr;
        size_t idx = (size_t)row * 2048 + col;
        outp[idx] = acc[mi][ni][qq] + x[idx] + rtd[idx];
      }
}

// ---------------- host launch ----------------

extern "C" void kernel_launch(void* const* d_in, const int* in_sizes, int n_in,
                              void* d_out, int out_size, void* d_ws, size_t ws_size,
                              hipStream_t stream) {
  (void)in_sizes; (void)n_in; (void)out_size; (void)ws_size;
  const float* hidden = (const float*)d_in[0];
  const float* ln1 = (const float*)d_in[1];
  const float* ln2 = (const float*)d_in[2];
  const float* wq = (const float*)d_in[3];
  const float* wk = (const float*)d_in[4];
  const float* wvw = (const float*)d_in[5];
  const float* wo = (const float*)d_in[6];
  const float* gw = (const float*)d_in[7];
  const float* eg = (const float*)d_in[8];
  const float* eu = (const float*)d_in[9];
  const float* ed = (const float*)d_in[10];
  const float* sg = (const float*)d_in[11];
  const float* su = (const float*)d_in[12];
  const float* sd = (const float*)d_in[13];
  float* out = (float*)d_out;
  char* ws = (char*)d_ws;

  const size_t KB = 1ull << 10, MB = 1ull << 20;
  float* tab = (float*)(ws + 0);            // [0, 0.5MB)
  float* cmb = (float*)(ws + 512 * KB);     // 32KB
  float* hn = (float*)(ws + 1 * MB);        // [1, 9)
  float* qf = (float*)(ws + 9 * MB);        // [9, 17)
  float* kf = (float*)(ws + 17 * MB);       // [17, 25)
  float* vf = (float*)(ws + 25 * MB);       // [25, 33)
  u16* Qh = (u16*)(ws + 33 * MB);           // [33, 37)
  u16* Ql = (u16*)(ws + 37 * MB);           // [37, 41)
  u16* Kh = (u16*)(ws + 41 * MB);           // [41, 45)
  u16* Kl = (u16*)(ws + 45 * MB);           // [45, 49)
  u16* Vth = (u16*)(ws + 49 * MB);          // [49, 53)
  u16* Vtl = (u16*)(ws + 53 * MB);          // [53, 57)
  float* att = (float*)(ws + 57 * MB);      // [57, 65)
  float* xf = (float*)(ws + 65 * MB);       // [65, 73)
  float* h2f = (float*)(ws + 73 * MB);      // [73, 81)
  u16* h2b = (u16*)(ws + 81 * MB);          // [81, 85)
  // Reuse of dead regions (all pre-attention buffers are dead post-attention):
  u16* actw = (u16*)(ws + 1 * MB);          // [1, 23)   22MB
  u16* acts = (u16*)(ws + 23 * MB);         // [23, 28.5) 5.5MB
  float* rtd = (float*)(ws + 29 * MB);      // [29, 37)  8MB

  k_ropetab<<<256, 256, 0, stream>>>(tab);
  k_rmsnorm<<<1024, 256, 0, stream>>>(hidden, ln1, hn, nullptr);
  k_gemm_f32split<<<dim3(8, 16, 3), 256, 0, stream>>>(hn, wq, wk, wvw, qf, kf, vf, nullptr);
  k_rope<<<4096, 256, 0, stream>>>(qf, kf, tab);
  k_splitkv<<<2048, 256, 0, stream>>>(qf, kf, vf, Qh, Ql, Kh, Kl, Vth, Vtl);
  k_attn_mfma<<<dim3(32, 16), 128, 0, stream>>>(Qh, Ql, Kh, Kl, Vth, Vtl, att);
  k_gemm_f32split<<<dim3(8, 16, 1), 256, 0, stream>>>(att, wo, wo, wo, xf, xf, xf, hidden);
  k_rmsnorm<<<1024, 256, 0, stream>>>(xf, ln2, h2f, h2b);
  k_router<<<1024, 256, 0, stream>>>(h2f, gw, cmb);
  k_dual<<<dim3(8, 22, 8), 256, 0, stream>>>(h2b, eg, eu, (size_t)1408 * 2048, cmb, actw, 11264, 1408);
  k_dual<<<dim3(8, 44, 1), 256, 0, stream>>>(h2b, sg, su, 0, nullptr, acts, 2816, 0);
  k_moedown<<<dim3(8, 16), 256, 0, stream>>>(actw, ed, rtd);
  k_shareddown<<<dim3(8, 16), 256, 0, stream>>>(acts, sd, xf, rtd, out);
}

// Round 4
// 893.761 us; speedup vs baseline: 1.7682x; 1.4778x over previous
//
#include <hip/hip_runtime.h>
#include <hip/hip_bf16.h>

// DeepseekDecoderLayer on MI355X. Round 3: fix sparse-MoE gather crash.
// (r2 bug: intra-expert padding slots of toklist were uninitialized -> gather
// addresses from garbage -> OOB fault; plus a base_s race in the 1024-thread
// scan. Fixed with a single-wave ballot scan + explicit padding zero-fill.)
// Pipeline: rmsnorm1 -> QKV (f32-split MFMA) -> RoPE (f64 table) -> split K/Q/V
// to bf16 hi/lo -> causal flash attn (split MFMA, lane-local softmax) ->
// O-proj+res (f32-split MFMA) -> rmsnorm2 -> router (f32, exact top-2) ->
// deterministic ballot-scan token gather -> SPARSE expert dual-GEMM + down ->
// shared dual-GEMM + down -> out = x + routed(2 slots) + shared.

#define DI __device__ __forceinline__

typedef __attribute__((ext_vector_type(8))) short short8;
typedef __attribute__((ext_vector_type(4))) float f32x4;
using u16 = unsigned short;

struct alignas(8) U16x4 { u16 x, y, z, w; };

DI u16 f2bf(float f) {
  unsigned u = __float_as_uint(f);
  u += 0x7fffu + ((u >> 16) & 1u);
  return (u16)(u >> 16);
}
DI float bf2f(u16 h) { return __uint_as_float(((unsigned)h) << 16); }

DI void gload16(const void* g, void* l) {
  __builtin_amdgcn_global_load_lds((const __attribute__((address_space(1))) void*)g,
                                   (__attribute__((address_space(3))) void*)l, 16, 0, 0);
}

// ---------------- small kernels ----------------

// RoPE cos/sin table in double precision (matches f64 numpy reference closely).
__global__ __launch_bounds__(256) void k_ropetab(float* __restrict__ tab) {
  int idx = blockIdx.x * 256 + threadIdx.x;  // < 1024*64
  int s = idx >> 6, i = idx & 63;
  double inv = pow(10000.0, -(double)(2 * i) / 128.0);
  double ang = (double)s * inv;
  tab[idx * 2 + 0] = (float)cos(ang);
  tab[idx * 2 + 1] = (float)sin(ang);
}

// RMSNorm row kernel: optional f32 and bf16 outputs.
__global__ __launch_bounds__(256) void k_rmsnorm(const float* __restrict__ in,
                                                 const float* __restrict__ w,
                                                 float* __restrict__ outf,
                                                 u16* __restrict__ outb) {
  const int row = blockIdx.x, t = threadIdx.x;
  const float* x = in + (size_t)row * 2048;
  float4 a = *(const float4*)&x[t * 4];
  float4 b = *(const float4*)&x[1024 + t * 4];
  float ss = a.x * a.x + a.y * a.y + a.z * a.z + a.w * a.w +
             b.x * b.x + b.y * b.y + b.z * b.z + b.w * b.w;
#pragma unroll
  for (int off = 32; off; off >>= 1) ss += __shfl_xor(ss, off);
  __shared__ float red[4];
  if ((t & 63) == 0) red[t >> 6] = ss;
  __syncthreads();
  float total = red[0] + red[1] + red[2] + red[3];
  float r = 1.0f / sqrtf(total * (1.0f / 2048.0f) + 1e-6f);
  float4 wa = *(const float4*)&w[t * 4];
  float4 wb = *(const float4*)&w[1024 + t * 4];
  float4 oa, ob;
  oa.x = a.x * r * wa.x; oa.y = a.y * r * wa.y; oa.z = a.z * r * wa.z; oa.w = a.w * r * wa.w;
  ob.x = b.x * r * wb.x; ob.y = b.y * r * wb.y; ob.z = b.z * r * wb.z; ob.w = b.w * r * wb.w;
  if (outf) {
    *(float4*)&outf[(size_t)row * 2048 + t * 4] = oa;
    *(float4*)&outf[(size_t)row * 2048 + 1024 + t * 4] = ob;
  }
  if (outb) {
    U16x4 ua{f2bf(oa.x), f2bf(oa.y), f2bf(oa.z), f2bf(oa.w)};
    U16x4 ub{f2bf(ob.x), f2bf(ob.y), f2bf(ob.z), f2bf(ob.w)};
    *(U16x4*)&outb[(size_t)row * 2048 + t * 4] = ua;
    *(U16x4*)&outb[(size_t)row * 2048 + 1024 + t * 4] = ub;
  }
}

// Apply RoPE in-place to q (with 1/sqrt(128) folded in) and k. f32.
__global__ __launch_bounds__(256) void k_rope(float* __restrict__ q, float* __restrict__ k,
                                              const float* __restrict__ tab) {
  int idx = blockIdx.x * 256 + threadIdx.x;  // < 1024*16*64
  int s = idx >> 10, rem = idx & 1023;
  int h = rem >> 6, i = rem & 63;
  size_t base = (size_t)s * 2048 + h * 128 + i;
  float c = tab[(s * 64 + i) * 2 + 0];
  float sn = tab[(s * 64 + i) * 2 + 1];
  const float qs = 0.08838834764831845f;  // 1/sqrt(128)
  float q1 = q[base], q2 = q[base + 64];
  q[base] = (q1 * c - q2 * sn) * qs;
  q[base + 64] = (q2 * c + q1 * sn) * qs;
  float k1 = k[base], k2 = k[base + 64];
  k[base] = k1 * c - k2 * sn;
  k[base + 64] = k2 * c + k1 * sn;
}

// Split f32 q/k/v into bf16 hi/lo. Q,K keep [s][2048] layout; V transposed to
// [h*128+d][s] (for direct MFMA A-operand loads in the PV step).
__global__ __launch_bounds__(256) void k_splitkv(
    const float* __restrict__ qf, const float* __restrict__ kf,
    const float* __restrict__ vf,
    u16* __restrict__ Qh, u16* __restrict__ Ql,
    u16* __restrict__ Kh, u16* __restrict__ Kl,
    u16* __restrict__ Vth, u16* __restrict__ Vtl) {
  int idx = (blockIdx.x * 256 + threadIdx.x) * 4;  // over 1024*2048 elements
  int s = idx >> 11, c = idx & 2047;
  float4 q4 = *(const float4*)&qf[idx];
  U16x4 qh{f2bf(q4.x), f2bf(q4.y), f2bf(q4.z), f2bf(q4.w)};
  U16x4 ql{f2bf(q4.x - bf2f(qh.x)), f2bf(q4.y - bf2f(qh.y)),
           f2bf(q4.z - bf2f(qh.z)), f2bf(q4.w - bf2f(qh.w))};
  *(U16x4*)&Qh[idx] = qh; *(U16x4*)&Ql[idx] = ql;
  float4 k4 = *(const float4*)&kf[idx];
  U16x4 kh{f2bf(k4.x), f2bf(k4.y), f2bf(k4.z), f2bf(k4.w)};
  U16x4 kl{f2bf(k4.x - bf2f(kh.x)), f2bf(k4.y - bf2f(kh.y)),
           f2bf(k4.z - bf2f(kh.z)), f2bf(k4.w - bf2f(kh.w))};
  *(U16x4*)&Kh[idx] = kh; *(U16x4*)&Kl[idx] = kl;
  float4 v4 = *(const float4*)&vf[idx];
  float vv[4] = {v4.x, v4.y, v4.z, v4.w};
#pragma unroll
  for (int i = 0; i < 4; ++i) {
    u16 hv = f2bf(vv[i]);
    u16 lv = f2bf(vv[i] - bf2f(hv));
    Vth[(size_t)(c + i) * 1024 + s] = hv;
    Vtl[(size_t)(c + i) * 1024 + s] = lv;
  }
}

// Causal flash attention via split-bf16 MFMA (3-term: h*h + l*h + h*l).
__global__ __launch_bounds__(128) void k_attn_mfma(
    const u16* __restrict__ Qh, const u16* __restrict__ Ql,
    const u16* __restrict__ Kh, const u16* __restrict__ Kl,
    const u16* __restrict__ Vth, const u16* __restrict__ Vtl,
    float* __restrict__ o) {
  const int h = blockIdx.y;
  const int wave = threadIdx.x >> 6, lane = threadIdx.x & 63;
  const int strip = blockIdx.x * 32 + wave * 16;
  const int l15 = lane & 15, grp = lane >> 4;
  __shared__ u16 Plh[2][16][40], Pll[2][16][40];
  u16(*plh)[40] = Plh[wave];
  u16(*pll)[40] = Pll[wave];

  short8 qfh[4], qfl[4];
  const size_t qbase = (size_t)(strip + l15) * 2048 + h * 128;
#pragma unroll
  for (int c = 0; c < 4; ++c) {
    qfh[c] = *(const short8*)&Qh[qbase + c * 32 + grp * 8];
    qfl[c] = *(const short8*)&Ql[qbase + c * 32 + grp * 8];
  }
  f32x4 oacc[8];
#pragma unroll
  for (int dc = 0; dc < 8; ++dc) oacc[dc] = 0.f;
  float m_run = -1e30f, l_run = 0.f;
  const int q_glob = strip + l15;
  const int tend = (strip >> 5) + 1;

  for (int t = 0; t < tend; ++t) {
    const int kvb = t * 32;
    f32x4 s[2];
#pragma unroll
    for (int sub = 0; sub < 2; ++sub) {
      f32x4 a = {0.f, 0.f, 0.f, 0.f};
      const size_t kbase = (size_t)(kvb + sub * 16 + l15) * 2048 + h * 128;
#pragma unroll
      for (int c = 0; c < 4; ++c) {
        short8 khf = *(const short8*)&Kh[kbase + c * 32 + grp * 8];
        short8 klf = *(const short8*)&Kl[kbase + c * 32 + grp * 8];
        a = __builtin_amdgcn_mfma_f32_16x16x32_bf16(khf, qfh[c], a, 0, 0, 0);
        a = __builtin_amdgcn_mfma_f32_16x16x32_bf16(klf, qfh[c], a, 0, 0, 0);
        a = __builtin_amdgcn_mfma_f32_16x16x32_bf16(khf, qfl[c], a, 0, 0, 0);
      }
      s[sub] = a;
    }
    if (t == tend - 1) {
#pragma unroll
      for (int sub = 0; sub < 2; ++sub)
#pragma unroll
        for (int r = 0; r < 4; ++r) {
          int kv = kvb + sub * 16 + grp * 4 + r;
          if (kv > q_glob) s[sub][r] = -1e30f;
        }
    }
    float tmax = s[0][0];
#pragma unroll
    for (int sub = 0; sub < 2; ++sub)
#pragma unroll
      for (int r = 0; r < 4; ++r) tmax = fmaxf(tmax, s[sub][r]);
    tmax = fmaxf(tmax, __shfl_xor(tmax, 16));
    tmax = fmaxf(tmax, __shfl_xor(tmax, 32));
    float mnew = fmaxf(m_run, tmax);
    float scale = expf(m_run - mnew);
    float p[8], lsum = 0.f;
#pragma unroll
    for (int sub = 0; sub < 2; ++sub)
#pragma unroll
      for (int r = 0; r < 4; ++r) {
        float pe = expf(s[sub][r] - mnew);
        p[sub * 4 + r] = pe;
        lsum += pe;
      }
    lsum += __shfl_xor(lsum, 16);
    lsum += __shfl_xor(lsum, 32);
    l_run = l_run * scale + lsum;
    m_run = mnew;
#pragma unroll
    for (int dc = 0; dc < 8; ++dc) oacc[dc] *= scale;
#pragma unroll
    for (int sub = 0; sub < 2; ++sub)
#pragma unroll
      for (int rp = 0; rp < 2; ++rp) {
        int i0 = sub * 4 + rp * 2;
        u16 h0 = f2bf(p[i0]), h1 = f2bf(p[i0 + 1]);
        u16 lo0 = f2bf(p[i0] - bf2f(h0)), lo1 = f2bf(p[i0 + 1] - bf2f(h1));
        int kvoff = sub * 16 + grp * 4 + rp * 2;
        *(unsigned*)&plh[l15][kvoff] = (unsigned)h0 | ((unsigned)h1 << 16);
        *(unsigned*)&pll[l15][kvoff] = (unsigned)lo0 | ((unsigned)lo1 << 16);
      }
    short8 phf = *(const short8*)&plh[l15][grp * 8];
    short8 plf = *(const short8*)&pll[l15][grp * 8];
#pragma unroll
    for (int dc = 0; dc < 8; ++dc) {
      const size_t vbase = (size_t)(h * 128 + dc * 16 + l15) * 1024 + kvb + grp * 8;
      short8 vh = *(const short8*)&Vth[vbase];
      short8 vl = *(const short8*)&Vtl[vbase];
      f32x4 acc = oacc[dc];
      acc = __builtin_amdgcn_mfma_f32_16x16x32_bf16(vh, phf, acc, 0, 0, 0);
      acc = __builtin_amdgcn_mfma_f32_16x16x32_bf16(vl, phf, acc, 0, 0, 0);
      acc = __builtin_amdgcn_mfma_f32_16x16x32_bf16(vh, plf, acc, 0, 0, 0);
      oacc[dc] = acc;
    }
  }
  float inv = 1.0f / l_run;
#pragma unroll
  for (int dc = 0; dc < 8; ++dc)
#pragma unroll
    for (int r = 0; r < 4; ++r)
      o[(size_t)q_glob * 2048 + h * 128 + dc * 16 + grp * 4 + r] = oacc[dc][r] * inv;
}

// Router: f32 logits (exact top-2 selection); emits top-2 idx + normed weights.
__global__ __launch_bounds__(256) void k_router(const float* __restrict__ h2f,
                                                const float* __restrict__ gw,
                                                int2* __restrict__ tidx,
                                                float2* __restrict__ twgt) {
  const int tok = blockIdx.x;
  const float* hrow = h2f + (size_t)tok * 2048;
  float part[8];
#pragma unroll
  for (int e = 0; e < 8; ++e) part[e] = 0.f;
  for (int j = 0; j < 8; ++j) {
    int p = j * 256 + threadIdx.x;
    float hv = hrow[p];
#pragma unroll
    for (int e = 0; e < 8; ++e) part[e] += hv * gw[e * 2048 + p];
  }
#pragma unroll
  for (int e = 0; e < 8; ++e)
#pragma unroll
    for (int off = 32; off; off >>= 1) part[e] += __shfl_xor(part[e], off);
  __shared__ float red[4][8];
  int wv = threadIdx.x >> 6, lane = threadIdx.x & 63;
  if (lane == 0) {
#pragma unroll
    for (int e = 0; e < 8; ++e) red[wv][e] = part[e];
  }
  __syncthreads();
  if (threadIdx.x == 0) {
    float lg[8];
#pragma unroll
    for (int e = 0; e < 8; ++e) lg[e] = red[0][e] + red[1][e] + red[2][e] + red[3][e];
    float m = lg[0];
#pragma unroll
    for (int e = 1; e < 8; ++e) m = fmaxf(m, lg[e]);
    float ex[8], s = 0.f;
#pragma unroll
    for (int e = 0; e < 8; ++e) { ex[e] = expf(lg[e] - m); s += ex[e]; }
#pragma unroll
    for (int e = 0; e < 8; ++e) ex[e] /= s;
    int i1 = 0;
#pragma unroll
    for (int e = 1; e < 8; ++e) if (ex[e] > ex[i1]) i1 = e;
    int i2 = (i1 == 0) ? 1 : 0;
#pragma unroll
    for (int e = 0; e < 8; ++e) if (e != i1 && ex[e] > ex[i2]) i2 = e;
    float s2 = ex[i1] + ex[i2] + 1e-20f;
    tidx[tok] = make_int2(i1, i2);
    twgt[tok] = make_float2(ex[i1] / s2, ex[i2] / s2);
  }
}

// Deterministic token gather, SINGLE WAVE (race-free): per-expert lists padded
// to 128-row tiles. meta[0..8] = padded offsets (meta[8]=total), meta[9..16] =
// counts. toklist[slot] = token id (padding slots = 0), slotw[slot] = combine
// weight (padding = 0), slots[tok*2+j] = slot of token's j-th expert.
// base/cnt are wave-uniform registers; ranks via ballot+popc. ~5us.
__global__ __launch_bounds__(64) void k_scan(const int2* __restrict__ tidx,
                                             const float2* __restrict__ twgt,
                                             int* __restrict__ meta,
                                             int* __restrict__ toklist,
                                             float* __restrict__ slotw,
                                             int* __restrict__ slots) {
  const int lane = threadIdx.x;
  int base = 0;
  for (int e = 0; e < 8; ++e) {
    int cnt = 0;
    for (int c = 0; c < 16; ++c) {
      const int tok = c * 64 + lane;
      int2 my = tidx[tok];
      int f1 = (my.x == e), f2 = (my.y == e);
      int flag = f1 | f2;
      unsigned long long m = __ballot(flag);
      if (flag) {
        float2 w = twgt[tok];
        int rank = (int)__popcll(m & ((1ull << lane) - 1ull));
        int s = base + cnt + rank;
        toklist[s] = tok;
        slotw[s] = f1 ? w.x : w.y;
        slots[tok * 2 + (f1 ? 0 : 1)] = s;
      }
      cnt += (int)__popcll(m);
    }
    if (lane == 0) { meta[e] = base; meta[9 + e] = cnt; }
    const int padded = ((cnt + 127) >> 7) << 7;
    // zero the padding slots (disjoint from filled slots; safe gather targets)
    for (int s = cnt + lane; s < padded; s += 64) {
      toklist[base + s] = 0;
      slotw[base + s] = 0.f;
    }
    base += padded;
  }
  if (lane == 0) meta[8] = base;
}

// ---------------- GEMM kernels ----------------
// All GEMMs: C[M,N] = A[M,K] @ B[N,K]^T. MFMA 16x16x32 bf16; C/D layout:
// col=lane&15, row=(lane>>4)*4+reg.

__global__ __launch_bounds__(256) void k_gemm_f32split(
    const float* __restrict__ A, const float* __restrict__ B0,
    const float* __restrict__ B1, const float* __restrict__ B2,
    float* __restrict__ C0, float* __restrict__ C1, float* __restrict__ C2,
    const float* __restrict__ resid) {
  __shared__ u16 lsAh[4096], lsAl[4096], lsBh[4096], lsBl[4096];
  const int z = blockIdx.z;
  const float* Bm = (z == 0) ? B0 : (z == 1) ? B1 : B2;
  float* Cm = (z == 0) ? C0 : (z == 1) ? C1 : C2;
  const int tid = threadIdx.x, lane = tid & 63, wv = tid >> 6;
  const int wr = (wv >> 1) * 64, wc = (wv & 1) * 64;
  const int fr = lane & 15, fg = lane >> 4;
  const int row0 = blockIdx.x * 128, col0 = blockIdx.y * 128;
  f32x4 acc[4][4];
#pragma unroll
  for (int i = 0; i < 4; ++i)
#pragma unroll
    for (int j = 0; j < 4; ++j) acc[i][j] = 0.f;

  for (int kt = 0; kt < 64; ++kt) {
    const int k0 = kt * 32;
#pragma unroll
    for (int j = 0; j < 4; ++j) {
      const int eo = (j * 256 + tid) * 4;
      const int rr = eo >> 5, cc = eo & 31;
      float4 av = *(const float4*)(A + (size_t)(row0 + rr) * 2048 + k0 + cc);
      float4 bv = *(const float4*)(Bm + (size_t)(col0 + rr) * 2048 + k0 + cc);
      U16x4 ahv{f2bf(av.x), f2bf(av.y), f2bf(av.z), f2bf(av.w)};
      U16x4 alv{f2bf(av.x - bf2f(ahv.x)), f2bf(av.y - bf2f(ahv.y)),
                f2bf(av.z - bf2f(ahv.z)), f2bf(av.w - bf2f(ahv.w))};
      U16x4 bhv{f2bf(bv.x), f2bf(bv.y), f2bf(bv.z), f2bf(bv.w)};
      U16x4 blv{f2bf(bv.x - bf2f(bhv.x)), f2bf(bv.y - bf2f(bhv.y)),
                f2bf(bv.z - bf2f(bhv.z)), f2bf(bv.w - bf2f(bhv.w))};
      *(U16x4*)&lsAh[eo] = ahv; *(U16x4*)&lsAl[eo] = alv;
      *(U16x4*)&lsBh[eo] = bhv; *(U16x4*)&lsBl[eo] = blv;
    }
    __syncthreads();
    short8 ah[4], al[4], bh[4], bl[4];
#pragma unroll
    for (int mi = 0; mi < 4; ++mi) {
      const int off = (wr + mi * 16 + fr) * 32 + fg * 8;
      ah[mi] = *(const short8*)&lsAh[off];
      al[mi] = *(const short8*)&lsAl[off];
    }
#pragma unroll
    for (int ni = 0; ni < 4; ++ni) {
      const int off = (wc + ni * 16 + fr) * 32 + fg * 8;
      bh[ni] = *(const short8*)&lsBh[off];
      bl[ni] = *(const short8*)&lsBl[off];
    }
#pragma unroll
    for (int mi = 0; mi < 4; ++mi)
#pragma unroll
      for (int ni = 0; ni < 4; ++ni) {
        f32x4 c = acc[mi][ni];
        c = __builtin_amdgcn_mfma_f32_16x16x32_bf16(al[mi], bh[ni], c, 0, 0, 0);
        c = __builtin_amdgcn_mfma_f32_16x16x32_bf16(ah[mi], bl[ni], c, 0, 0, 0);
        c = __builtin_amdgcn_mfma_f32_16x16x32_bf16(ah[mi], bh[ni], c, 0, 0, 0);
        acc[mi][ni] = c;
      }
    __syncthreads();
  }
  const bool hasres = (resid != nullptr);
#pragma unroll
  for (int mi = 0; mi < 4; ++mi)
#pragma unroll
    for (int ni = 0; ni < 4; ++ni)
#pragma unroll
      for (int qq = 0; qq < 4; ++qq) {
        const int row = row0 + wr + mi * 16 + fg * 4 + qq;
        const int col = col0 + wc + ni * 16 + fr;
        float val = acc[mi][ni][qq];
        if (hasres) val += resid[(size_t)row * 2048 + col];
        Cm[(size_t)row * 2048 + col] = val;
      }
}

// Staging helpers for bf16 GEMMs.
DI void stageA_bf16(const u16* __restrict__ A, size_t lda, int row0, int k0,
                    u16* lsA, int tid) {
  const int lane = tid & 63, wv = tid >> 6;
#pragma unroll
  for (int it = 0; it < 2; ++it) {
    const int ebase = it * 2048 + wv * 512;  // wave-uniform LDS base
    const int eo = ebase + lane * 8;
    const int rr = eo >> 5, cc = eo & 31;
    gload16(A + (size_t)(row0 + rr) * lda + k0 + cc, lsA + ebase);
  }
}
DI void stageB_f32(const float* __restrict__ B, size_t ldb, int row0, int k0,
                   u16* lsB, int tid) {
#pragma unroll
  for (int j = 0; j < 4; ++j) {
    const int eo = (j * 256 + tid) * 4;
    const int rr = eo >> 5, cc = eo & 31;
    float4 bv = *(const float4*)(B + (size_t)(row0 + rr) * ldb + k0 + cc);
    U16x4 hv{f2bf(bv.x), f2bf(bv.y), f2bf(bv.z), f2bf(bv.w)};
    *(U16x4*)&lsB[eo] = hv;
  }
}

// Find expert for a padded row-tile index. meta[0..8] = offsets (mult of 128).
DI int tile_to_expert(const int* meta, int t) {
  int e = 0;
  while (e < 7 && t >= (meta[e + 1] >> 7)) ++e;
  return e;
}

// Dense dual GEMM + SiLU for the shared expert: acts = silu(A@Bg^T)*(A@Bu^T).
__global__ __launch_bounds__(256) void k_dual_shared(
    const u16* __restrict__ A, const float* __restrict__ Bg,
    const float* __restrict__ Bu, u16* __restrict__ outp, int ldc) {
  __shared__ u16 lsA[4096], lsG[2048], lsU[2048];
  const int tid = threadIdx.x, lane = tid & 63, wv = tid >> 6;
  const int wr = (wv >> 1) * 64, wc = (wv & 1) * 32;
  const int fr = lane & 15, fg = lane >> 4;
  const int row0 = blockIdx.x * 128, n0 = blockIdx.y * 64;
  f32x4 ag[4][2], au[4][2];
#pragma unroll
  for (int i = 0; i < 4; ++i)
#pragma unroll
    for (int j = 0; j < 2; ++j) { ag[i][j] = 0.f; au[i][j] = 0.f; }

  for (int kt = 0; kt < 64; ++kt) {
    const int k0 = kt * 32;
    stageA_bf16(A, 2048, row0, k0, lsA, tid);
#pragma unroll
    for (int j = 0; j < 2; ++j) {
      const int eo = (j * 256 + tid) * 4;
      const int rr = eo >> 5, cc = eo & 31;
      float4 gv = *(const float4*)(Bg + (size_t)(n0 + rr) * 2048 + k0 + cc);
      float4 uv = *(const float4*)(Bu + (size_t)(n0 + rr) * 2048 + k0 + cc);
      U16x4 gh{f2bf(gv.x), f2bf(gv.y), f2bf(gv.z), f2bf(gv.w)};
      U16x4 uh{f2bf(uv.x), f2bf(uv.y), f2bf(uv.z), f2bf(uv.w)};
      *(U16x4*)&lsG[eo] = gh;
      *(U16x4*)&lsU[eo] = uh;
    }
    __syncthreads();
    short8 af[4], gf[2], uf[2];
#pragma unroll
    for (int mi = 0; mi < 4; ++mi)
      af[mi] = *(const short8*)&lsA[(wr + mi * 16 + fr) * 32 + fg * 8];
#pragma unroll
    for (int ni = 0; ni < 2; ++ni) {
      const int off = (wc + ni * 16 + fr) * 32 + fg * 8;
      gf[ni] = *(const short8*)&lsG[off];
      uf[ni] = *(const short8*)&lsU[off];
    }
#pragma unroll
    for (int mi = 0; mi < 4; ++mi)
#pragma unroll
      for (int ni = 0; ni < 2; ++ni) {
        ag[mi][ni] = __builtin_amdgcn_mfma_f32_16x16x32_bf16(af[mi], gf[ni], ag[mi][ni], 0, 0, 0);
        au[mi][ni] = __builtin_amdgcn_mfma_f32_16x16x32_bf16(af[mi], uf[ni], au[mi][ni], 0, 0, 0);
      }
    __syncthreads();
  }
#pragma unroll
  for (int mi = 0; mi < 4; ++mi)
#pragma unroll
    for (int ni = 0; ni < 2; ++ni)
#pragma unroll
      for (int qq = 0; qq < 4; ++qq) {
        const int row = row0 + wr + mi * 16 + fg * 4 + qq;
        const int col = n0 + wc + ni * 16 + fr;
        float g = ag[mi][ni][qq], u = au[mi][ni][qq];
        float act = g / (1.0f + expf(-g)) * u;
        outp[(size_t)row * ldc + col] = f2bf(act);
      }
}

// Sparse expert dual GEMM: rows gathered by token list; combine weight folded.
// grid (24 max tiles, 22 n-tiles). act[slot][1408] bf16 out.
__global__ __launch_bounds__(256) void k_dual_sparse(
    const u16* __restrict__ A, const float* __restrict__ eg,
    const float* __restrict__ eu, const int* __restrict__ meta,
    const int* __restrict__ toklist, const float* __restrict__ slotw,
    u16* __restrict__ act) {
  const int t = blockIdx.x;
  if (t >= (meta[8] >> 7)) return;
  __shared__ int toks[128];
  __shared__ u16 lsA[4096], lsG[2048], lsU[2048];
  const int e = tile_to_expert(meta, t);
  const int off_e = meta[e], cnt_e = meta[9 + e];
  const int rtile = t - (off_e >> 7);
  const int tid = threadIdx.x, lane = tid & 63, wv = tid >> 6;
  if (tid < 128) toks[tid] = toklist[off_e + rtile * 128 + tid] & 1023;  // mask: safe gather
  const float* Bg = eg + (size_t)e * 1408 * 2048;
  const float* Bu = eu + (size_t)e * 1408 * 2048;
  const int wr = (wv >> 1) * 64, wc = (wv & 1) * 32;
  const int fr = lane & 15, fg = lane >> 4;
  const int n0 = blockIdx.y * 64;
  f32x4 ag[4][2], au[4][2];
#pragma unroll
  for (int i = 0; i < 4; ++i)
#pragma unroll
    for (int j = 0; j < 2; ++j) { ag[i][j] = 0.f; au[i][j] = 0.f; }
  __syncthreads();

  for (int kt = 0; kt < 64; ++kt) {
    const int k0 = kt * 32;
    // A gather: per-lane global source, linear LDS dest.
#pragma unroll
    for (int it = 0; it < 2; ++it) {
      const int ebase = it * 2048 + wv * 512;
      const int eo = ebase + lane * 8;
      const int rr = eo >> 5, cc = eo & 31;
      gload16(A + (size_t)toks[rr] * 2048 + k0 + cc, lsA + ebase);
    }
#pragma unroll
    for (int j = 0; j < 2; ++j) {
      const int eo = (j * 256 + tid) * 4;
      const int rr = eo >> 5, cc = eo & 31;
      float4 gv = *(const float4*)(Bg + (size_t)(n0 + rr) * 2048 + k0 + cc);
      float4 uv = *(const float4*)(Bu + (size_t)(n0 + rr) * 2048 + k0 + cc);
      U16x4 gh{f2bf(gv.x), f2bf(gv.y), f2bf(gv.z), f2bf(gv.w)};
      U16x4 uh{f2bf(uv.x), f2bf(uv.y), f2bf(uv.z), f2bf(uv.w)};
      *(U16x4*)&lsG[eo] = gh;
      *(U16x4*)&lsU[eo] = uh;
    }
    __syncthreads();
    short8 af[4], gf[2], uf[2];
#pragma unroll
    for (int mi = 0; mi < 4; ++mi)
      af[mi] = *(const short8*)&lsA[(wr + mi * 16 + fr) * 32 + fg * 8];
#pragma unroll
    for (int ni = 0; ni < 2; ++ni) {
      const int off = (wc + ni * 16 + fr) * 32 + fg * 8;
      gf[ni] = *(const short8*)&lsG[off];
      uf[ni] = *(const short8*)&lsU[off];
    }
#pragma unroll
    for (int mi = 0; mi < 4; ++mi)
#pragma unroll
      for (int ni = 0; ni < 2; ++ni) {
        ag[mi][ni] = __builtin_amdgcn_mfma_f32_16x16x32_bf16(af[mi], gf[ni], ag[mi][ni], 0, 0, 0);
        au[mi][ni] = __builtin_amdgcn_mfma_f32_16x16x32_bf16(af[mi], uf[ni], au[mi][ni], 0, 0, 0);
      }
    __syncthreads();
  }
#pragma unroll
  for (int mi = 0; mi < 4; ++mi)
#pragma unroll
    for (int ni = 0; ni < 2; ++ni)
#pragma unroll
      for (int qq = 0; qq < 4; ++qq) {
        const int r = wr + mi * 16 + fg * 4 + qq;
        const int rowInE = rtile * 128 + r;
        if (rowInE < cnt_e) {
          const int col = n0 + wc + ni * 16 + fr;
          float g = ag[mi][ni][qq], u = au[mi][ni][qq];
          float a = g / (1.0f + expf(-g)) * u;
          act[(size_t)(off_e + rowInE) * 1408 + col] = f2bf(a * slotw[off_e + rowInE]);
        }
      }
}

// Sparse expert down GEMM: dwn[slot][2048] = act[slot] @ ed[e]^T.
// grid (24 max tiles, 16 n-tiles of 128). Padding act rows are never written
// by k_dual_sparse; their dwn rows are garbage but never read (slots only
// point to occupied rows).
__global__ __launch_bounds__(256) void k_down_sparse(
    const u16* __restrict__ act, const float* __restrict__ ed,
    const int* __restrict__ meta, float* __restrict__ dwn) {
  const int t = blockIdx.x;
  if (t >= (meta[8] >> 7)) return;
  __shared__ u16 lsA[4096], lsB[4096];
  const int e = tile_to_expert(meta, t);
  const int off_e = meta[e], cnt_e = meta[9 + e];
  const int rtile = t - (off_e >> 7);
  const int tid = threadIdx.x, lane = tid & 63, wv = tid >> 6;
  const int wr = (wv >> 1) * 64, wc = (wv & 1) * 64;
  const int fr = lane & 15, fg = lane >> 4;
  const int col0 = blockIdx.y * 128;
  const u16* Ab = act + (size_t)off_e * 1408;
  const float* Bb = ed + (size_t)e * 2048 * 1408;
  f32x4 acc[4][4];
#pragma unroll
  for (int i = 0; i < 4; ++i)
#pragma unroll
    for (int j = 0; j < 4; ++j) acc[i][j] = 0.f;

  for (int kt = 0; kt < 44; ++kt) {
    const int k0 = kt * 32;
    stageA_bf16(Ab, 1408, rtile * 128, k0, lsA, tid);
    stageB_f32(Bb, 1408, col0, k0, lsB, tid);
    __syncthreads();
    short8 af[4], bf_[4];
#pragma unroll
    for (int mi = 0; mi < 4; ++mi)
      af[mi] = *(const short8*)&lsA[(wr + mi * 16 + fr) * 32 + fg * 8];
#pragma unroll
    for (int ni = 0; ni < 4; ++ni)
      bf_[ni] = *(const short8*)&lsB[(wc + ni * 16 + fr) * 32 + fg * 8];
#pragma unroll
    for (int mi = 0; mi < 4; ++mi)
#pragma unroll
      for (int ni = 0; ni < 4; ++ni)
        acc[mi][ni] = __builtin_amdgcn_mfma_f32_16x16x32_bf16(af[mi], bf_[ni], acc[mi][ni], 0, 0, 0);
    __syncthreads();
  }
  (void)cnt_e;
#pragma unroll
  for (int mi = 0; mi < 4; ++mi)
#pragma unroll
    for (int ni = 0; ni < 4; ++ni)
#pragma unroll
      for (int qq = 0; qq < 4; ++qq) {
        const int r = wr + mi * 16 + fg * 4 + qq;
        const int col = col0 + wc + ni * 16 + fr;
        dwn[(size_t)(off_e + rtile * 128 + r) * 2048 + col] = acc[mi][ni][qq];
      }
}

// Shared down + final combine: out = x + dwn[slot0] + dwn[slot1] + acts@sd^T.
__global__ __launch_bounds__(256) void k_shareddown(
    const u16* __restrict__ acts, const float* __restrict__ sd,
    const float* __restrict__ x, const float* __restrict__ dwn,
    const int* __restrict__ slots, float* __restrict__ outp) {
  __shared__ u16 lsA[4096], lsB[4096];
  const int tid = threadIdx.x, lane = tid & 63, wv = tid >> 6;
  const int wr = (wv >> 1) * 64, wc = (wv & 1) * 64;
  const int fr = lane & 15, fg = lane >> 4;
  const int row0 = blockIdx.x * 128, col0 = blockIdx.y * 128;
  f32x4 acc[4][4];
#pragma unroll
  for (int i = 0; i < 4; ++i)
#pragma unroll
    for (int j = 0; j < 4; ++j) acc[i][j] = 0.f;

  for (int kt = 0; kt < 88; ++kt) {
    const int k0 = kt * 32;
    stageA_bf16(acts, 2816, row0, k0, lsA, tid);
    stageB_f32(sd, 2816, col0, k0, lsB, tid);
    __syncthreads();
    short8 af[4], bf_[4];
#pragma unroll
    for (int mi = 0; mi < 4; ++mi)
      af[mi] = *(const short8*)&lsA[(wr + mi * 16 + fr) * 32 + fg * 8];
#pragma unroll
    for (int ni = 0; ni < 4; ++ni)
      bf_[ni] = *(const short8*)&lsB[(wc + ni * 16 + fr) * 32 + fg * 8];
#pragma unroll
    for (int mi = 0; mi < 4; ++mi)
#pragma unroll
      for (int ni = 0; ni < 4; ++ni)
        acc[mi][ni] = __builtin_amdgcn_mfma_f32_16x16x32_bf16(af[mi], bf_[ni], acc[mi][ni], 0, 0, 0);
    __syncthreads();
  }
#pragma unroll
  for (int mi = 0; mi < 4; ++mi)
#pragma unroll
    for (int ni = 0; ni < 4; ++ni)
#pragma unroll
      for (int qq = 0; qq < 4; ++qq) {
        const int row = row0 + wr + mi * 16 + fg * 4 + qq;
        const int col = col0 + wc + ni * 16 + fr;
        size_t idx = (size_t)row * 2048 + col;
        int s0 = slots[row * 2], s1 = slots[row * 2 + 1];
        outp[idx] = acc[mi][ni][qq] + x[idx] +
                    dwn[(size_t)s0 * 2048 + col] + dwn[(size_t)s1 * 2048 + col];
      }
}

// ---------------- host launch ----------------

extern "C" void kernel_launch(void* const* d_in, const int* in_sizes, int n_in,
                              void* d_out, int out_size, void* d_ws, size_t ws_size,
                              hipStream_t stream) {
  (void)in_sizes; (void)n_in; (void)out_size; (void)ws_size;
  const float* hidden = (const float*)d_in[0];
  const float* ln1 = (const float*)d_in[1];
  const float* ln2 = (const float*)d_in[2];
  const float* wq = (const float*)d_in[3];
  const float* wk = (const float*)d_in[4];
  const float* wvw = (const float*)d_in[5];
  const float* wo = (const float*)d_in[6];
  const float* gw = (const float*)d_in[7];
  const float* eg = (const float*)d_in[8];
  const float* eu = (const float*)d_in[9];
  const float* ed = (const float*)d_in[10];
  const float* sg = (const float*)d_in[11];
  const float* su = (const float*)d_in[12];
  const float* sd = (const float*)d_in[13];
  float* out = (float*)d_out;
  char* ws = (char*)d_ws;

  const size_t KB = 1ull << 10, MB = 1ull << 20;
  float* tab = (float*)(ws + 0);             // [0, 0.5MB)
  int2* tidx = (int2*)(ws + 512 * KB);       // 8KB
  float2* twgt = (float2*)(ws + 520 * KB);   // 8KB
  int* meta = (int*)(ws + 528 * KB);         // 128B
  int* tokl = (int*)(ws + 532 * KB);         // 12KB
  float* slw = (float*)(ws + 544 * KB);      // 12KB
  int* slots = (int*)(ws + 556 * KB);        // 8KB
  float* hn = (float*)(ws + 1 * MB);         // [1, 9)
  float* qf = (float*)(ws + 9 * MB);         // [9, 17)
  float* kf = (float*)(ws + 17 * MB);        // [17, 25)
  float* vf = (float*)(ws + 25 * MB);        // [25, 33)
  u16* Qh = (u16*)(ws + 33 * MB);            // [33, 37)
  u16* Ql = (u16*)(ws + 37 * MB);            // [37, 41)
  u16* Kh = (u16*)(ws + 41 * MB);            // [41, 45)
  u16* Kl = (u16*)(ws + 45 * MB);            // [45, 49)
  u16* Vth = (u16*)(ws + 49 * MB);           // [49, 53)
  u16* Vtl = (u16*)(ws + 53 * MB);           // [53, 57)
  float* att = (float*)(ws + 57 * MB);       // [57, 65)
  float* xf = (float*)(ws + 65 * MB);        // [65, 73)
  float* h2f = (float*)(ws + 73 * MB);       // [73, 81)
  u16* h2b = (u16*)(ws + 81 * MB);           // [81, 85)
  // Post-attention reuse of dead regions:
  u16* act = (u16*)(ws + 1 * MB);            // [1, 9.25)  3072x1408 bf16
  float* dwn = (float*)(ws + 10 * MB);       // [10, 34)   3072x2048 f32
  u16* acts = (u16*)(ws + 34 * MB);          // [34, 39.5) 1024x2816 bf16

  k_ropetab<<<256, 256, 0, stream>>>(tab);
  k_rmsnorm<<<1024, 256, 0, stream>>>(hidden, ln1, hn, nullptr);
  k_gemm_f32split<<<dim3(8, 16, 3), 256, 0, stream>>>(hn, wq, wk, wvw, qf, kf, vf, nullptr);
  k_rope<<<4096, 256, 0, stream>>>(qf, kf, tab);
  k_splitkv<<<2048, 256, 0, stream>>>(qf, kf, vf, Qh, Ql, Kh, Kl, Vth, Vtl);
  k_attn_mfma<<<dim3(32, 16), 128, 0, stream>>>(Qh, Ql, Kh, Kl, Vth, Vtl, att);
  k_gemm_f32split<<<dim3(8, 16, 1), 256, 0, stream>>>(att, wo, wo, wo, xf, xf, xf, hidden);
  k_rmsnorm<<<1024, 256, 0, stream>>>(xf, ln2, h2f, h2b);
  k_router<<<1024, 256, 0, stream>>>(h2f, gw, tidx, twgt);
  k_scan<<<1, 64, 0, stream>>>(tidx, twgt, meta, tokl, slw, slots);
  k_dual_sparse<<<dim3(24, 22), 256, 0, stream>>>(h2b, eg, eu, meta, tokl, slw, act);
  k_dual_shared<<<dim3(8, 44), 256, 0, stream>>>(h2b, sg, su, acts, 2816);
  k_down_sparse<<<dim3(24, 16), 256, 0, stream>>>(act, ed, meta, dwn);
  k_shareddown<<<dim3(8, 16), 256, 0, stream>>>(acts, sd, xf, dwn, slots, out);
}

// Round 5
// 749.666 us; speedup vs baseline: 2.1081x; 1.1922x over previous
//
#include <hip/hip_runtime.h>
#include <hip/hip_bf16.h>

// DeepseekDecoderLayer on MI355X. Round 4: LDS-staged attention + bf16-staged
// split GEMMs for QKV/O.
// - Attention: block = 64 q-rows x head, 4 waves; K/V double-buffered in LDS
//   (global_load_lds, XOR-swizzled source + swizzled ds_read to kill the
//   16-way bank conflict of stride-256B/128B rows); per-wave lane-local
//   online softmax; 3-term split-bf16 MFMA (err ~2^-17) for QK and PV.
// - QKV/O: weights pre-split to bf16 hi/lo once (k_splitf); rmsnorm1 and attn
//   emit hi/lo bf16 directly -> GEMM K-loop is pure gload_lds + 48 MFMA.
// - MoE: unchanged sparse top-2 path (r3/r4, passing).

#define DI __device__ __forceinline__

typedef __attribute__((ext_vector_type(8))) short short8;
typedef __attribute__((ext_vector_type(4))) float f32x4;
using u16 = unsigned short;

struct alignas(8) U16x4 { u16 x, y, z, w; };

DI u16 f2bf(float f) {
  unsigned u = __float_as_uint(f);
  u += 0x7fffu + ((u >> 16) & 1u);
  return (u16)(u >> 16);
}
DI float bf2f(u16 h) { return __uint_as_float(((unsigned)h) << 16); }

DI void gload16(const void* g, void* l) {
  __builtin_amdgcn_global_load_lds((const __attribute__((address_space(1))) void*)g,
                                   (__attribute__((address_space(3))) void*)l, 16, 0, 0);
}

// ---------------- small kernels ----------------

// RoPE cos/sin table in double precision (matches f64 numpy reference).
__global__ __launch_bounds__(256) void k_ropetab(float* __restrict__ tab) {
  int idx = blockIdx.x * 256 + threadIdx.x;  // < 1024*64
  int s = idx >> 6, i = idx & 63;
  double inv = pow(10000.0, -(double)(2 * i) / 128.0);
  double ang = (double)s * inv;
  tab[idx * 2 + 0] = (float)cos(ang);
  tab[idx * 2 + 1] = (float)sin(ang);
}

// RMSNorm row kernel: optional f32 out + optional bf16 hi/lo outs.
__global__ __launch_bounds__(256) void k_rmsnorm(const float* __restrict__ in,
                                                 const float* __restrict__ w,
                                                 float* __restrict__ outf,
                                                 u16* __restrict__ outh,
                                                 u16* __restrict__ outl) {
  const int row = blockIdx.x, t = threadIdx.x;
  const float* x = in + (size_t)row * 2048;
  float4 a = *(const float4*)&x[t * 4];
  float4 b = *(const float4*)&x[1024 + t * 4];
  float ss = a.x * a.x + a.y * a.y + a.z * a.z + a.w * a.w +
             b.x * b.x + b.y * b.y + b.z * b.z + b.w * b.w;
#pragma unroll
  for (int off = 32; off; off >>= 1) ss += __shfl_xor(ss, off);
  __shared__ float red[4];
  if ((t & 63) == 0) red[t >> 6] = ss;
  __syncthreads();
  float total = red[0] + red[1] + red[2] + red[3];
  float r = 1.0f / sqrtf(total * (1.0f / 2048.0f) + 1e-6f);
  float4 wa = *(const float4*)&w[t * 4];
  float4 wb = *(const float4*)&w[1024 + t * 4];
  float va[8] = {a.x * r * wa.x, a.y * r * wa.y, a.z * r * wa.z, a.w * r * wa.w,
                 b.x * r * wb.x, b.y * r * wb.y, b.z * r * wb.z, b.w * r * wb.w};
  if (outf) {
    *(float4*)&outf[(size_t)row * 2048 + t * 4] = make_float4(va[0], va[1], va[2], va[3]);
    *(float4*)&outf[(size_t)row * 2048 + 1024 + t * 4] = make_float4(va[4], va[5], va[6], va[7]);
  }
  if (outh) {
    U16x4 ha{f2bf(va[0]), f2bf(va[1]), f2bf(va[2]), f2bf(va[3])};
    U16x4 hb{f2bf(va[4]), f2bf(va[5]), f2bf(va[6]), f2bf(va[7])};
    *(U16x4*)&outh[(size_t)row * 2048 + t * 4] = ha;
    *(U16x4*)&outh[(size_t)row * 2048 + 1024 + t * 4] = hb;
    if (outl) {
      U16x4 la{f2bf(va[0] - bf2f(ha.x)), f2bf(va[1] - bf2f(ha.y)),
               f2bf(va[2] - bf2f(ha.z)), f2bf(va[3] - bf2f(ha.w))};
      U16x4 lb{f2bf(va[4] - bf2f(hb.x)), f2bf(va[5] - bf2f(hb.y)),
               f2bf(va[6] - bf2f(hb.z)), f2bf(va[7] - bf2f(hb.w))};
      *(U16x4*)&outl[(size_t)row * 2048 + t * 4] = la;
      *(U16x4*)&outl[(size_t)row * 2048 + 1024 + t * 4] = lb;
    }
  }
}

// Split an f32 array into bf16 hi/lo (weights prep).
__global__ __launch_bounds__(256) void k_splitf(const float* __restrict__ src,
                                                u16* __restrict__ dh,
                                                u16* __restrict__ dl) {
  int idx = (blockIdx.x * 256 + threadIdx.x) * 4;
  float4 v = *(const float4*)&src[idx];
  U16x4 h{f2bf(v.x), f2bf(v.y), f2bf(v.z), f2bf(v.w)};
  U16x4 l{f2bf(v.x - bf2f(h.x)), f2bf(v.y - bf2f(h.y)),
          f2bf(v.z - bf2f(h.z)), f2bf(v.w - bf2f(h.w))};
  *(U16x4*)&dh[idx] = h;
  *(U16x4*)&dl[idx] = l;
}

// Apply RoPE in-place to q (with 1/sqrt(128) folded in) and k. f32.
__global__ __launch_bounds__(256) void k_rope(float* __restrict__ q, float* __restrict__ k,
                                              const float* __restrict__ tab) {
  int idx = blockIdx.x * 256 + threadIdx.x;  // < 1024*16*64
  int s = idx >> 10, rem = idx & 1023;
  int h = rem >> 6, i = rem & 63;
  size_t base = (size_t)s * 2048 + h * 128 + i;
  float c = tab[(s * 64 + i) * 2 + 0];
  float sn = tab[(s * 64 + i) * 2 + 1];
  const float qs = 0.08838834764831845f;  // 1/sqrt(128)
  float q1 = q[base], q2 = q[base + 64];
  q[base] = (q1 * c - q2 * sn) * qs;
  q[base + 64] = (q2 * c + q1 * sn) * qs;
  float k1 = k[base], k2 = k[base + 64];
  k[base] = k1 * c - k2 * sn;
  k[base + 64] = k2 * c + k1 * sn;
}

// Split f32 q/k/v into bf16 hi/lo. Q,K keep [s][2048] layout; V transposed to
// [h*128+d][s].
__global__ __launch_bounds__(256) void k_splitkv(
    const float* __restrict__ qf, const float* __restrict__ kf,
    const float* __restrict__ vf,
    u16* __restrict__ Qh, u16* __restrict__ Ql,
    u16* __restrict__ Kh, u16* __restrict__ Kl,
    u16* __restrict__ Vth, u16* __restrict__ Vtl) {
  int idx = (blockIdx.x * 256 + threadIdx.x) * 4;  // over 1024*2048 elements
  int s = idx >> 11, c = idx & 2047;
  float4 q4 = *(const float4*)&qf[idx];
  U16x4 qh{f2bf(q4.x), f2bf(q4.y), f2bf(q4.z), f2bf(q4.w)};
  U16x4 ql{f2bf(q4.x - bf2f(qh.x)), f2bf(q4.y - bf2f(qh.y)),
           f2bf(q4.z - bf2f(qh.z)), f2bf(q4.w - bf2f(qh.w))};
  *(U16x4*)&Qh[idx] = qh; *(U16x4*)&Ql[idx] = ql;
  float4 k4 = *(const float4*)&kf[idx];
  U16x4 kh{f2bf(k4.x), f2bf(k4.y), f2bf(k4.z), f2bf(k4.w)};
  U16x4 kl{f2bf(k4.x - bf2f(kh.x)), f2bf(k4.y - bf2f(kh.y)),
           f2bf(k4.z - bf2f(kh.z)), f2bf(k4.w - bf2f(kh.w))};
  *(U16x4*)&Kh[idx] = kh; *(U16x4*)&Kl[idx] = kl;
  float4 v4 = *(const float4*)&vf[idx];
  float vv[4] = {v4.x, v4.y, v4.z, v4.w};
#pragma unroll
  for (int i = 0; i < 4; ++i) {
    u16 hv = f2bf(vv[i]);
    u16 lv = f2bf(vv[i] - bf2f(hv));
    Vth[(size_t)(c + i) * 1024 + s] = hv;
    Vtl[(size_t)(c + i) * 1024 + s] = lv;
  }
}

// ---------------- attention (LDS-staged, double-buffered) ----------------
// Block = (64 q-rows, head), 4 waves of 16 q-rows each. KVBLK=64.
// K LDS [64][128], V LDS [128][64] (transposed), bf16 hi/lo, XOR-swizzled
// (16B-group index ^= row&7) with inverse swizzle on the global_load_lds
// source so reads are conflict-free (both-sides-or-neither rule).
// Output: bf16 hi/lo split of attention (feeds bf16split O-proj).

DI void stage_kv(const u16* __restrict__ Khg, const u16* __restrict__ Klg,
                 const u16* __restrict__ Vhg, const u16* __restrict__ Vlg,
                 u16* lsKh, u16* lsKl, u16* lsVh, u16* lsVl,
                 int kvb, int hh, int wv, int lane) {
#pragma unroll
  for (int it = 0; it < 4; ++it) {
    const int ebase = it * 2048 + wv * 512;  // wave-uniform LDS base
    const int eo = ebase + lane * 8;
    {  // K tile [64 kv][128 d]
      const int rr = eo >> 7, cg = (eo >> 3) & 15;
      const size_t src = (size_t)(kvb + rr) * 2048 + hh * 128 + ((cg ^ (rr & 7)) << 3);
      gload16(Khg + src, lsKh + ebase);
      gload16(Klg + src, lsKl + ebase);
    }
    {  // V tile [128 d][64 kv]
      const int rr = eo >> 6, cg = (eo >> 3) & 7;
      const size_t src = (size_t)(hh * 128 + rr) * 1024 + kvb + ((cg ^ (rr & 7)) << 3);
      gload16(Vhg + src, lsVh + ebase);
      gload16(Vlg + src, lsVl + ebase);
    }
  }
}

__global__ __launch_bounds__(256) void k_attn_tile(
    const u16* __restrict__ Qh, const u16* __restrict__ Ql,
    const u16* __restrict__ Khg, const u16* __restrict__ Klg,
    const u16* __restrict__ Vhg, const u16* __restrict__ Vlg,
    u16* __restrict__ atth, u16* __restrict__ attl) {
  __shared__ u16 lsKh[2][8192], lsKl[2][8192], lsVh[2][8192], lsVl[2][8192];  // 128KB
  __shared__ u16 Plh[4][16][72], Pll[4][16][72];                              // 18KB
  const int hh = blockIdx.y;
  const int qb = blockIdx.x * 64;
  const int tid = threadIdx.x, lane = tid & 63, wv = tid >> 6;
  const int l15 = lane & 15, grp = lane >> 4;
  u16(*plh)[72] = Plh[wv];
  u16(*pll)[72] = Pll[wv];
  const int q_glob = qb + wv * 16 + l15;
  const int tend = blockIdx.x + 1;

  // Q fragments (global, once).
  short8 qfh[4], qfl[4];
  const size_t qbase = (size_t)q_glob * 2048 + hh * 128;
#pragma unroll
  for (int c = 0; c < 4; ++c) {
    qfh[c] = *(const short8*)&Qh[qbase + c * 32 + grp * 8];
    qfl[c] = *(const short8*)&Ql[qbase + c * 32 + grp * 8];
  }
  f32x4 oacc[8];
#pragma unroll
  for (int dc = 0; dc < 8; ++dc) oacc[dc] = 0.f;
  float m_run = -1e30f, l_run = 0.f;

  int cur = 0;
  stage_kv(Khg, Klg, Vhg, Vlg, lsKh[0], lsKl[0], lsVh[0], lsVl[0], 0, hh, wv, lane);
  __syncthreads();

  for (int kt = 0; kt < tend; ++kt) {
    const int kvb = kt * 64;
    if (kt + 1 < tend)
      stage_kv(Khg, Klg, Vhg, Vlg, lsKh[cur ^ 1], lsKl[cur ^ 1], lsVh[cur ^ 1],
               lsVl[cur ^ 1], kvb + 64, hh, wv, lane);
    const u16* kh = lsKh[cur];
    const u16* kl = lsKl[cur];
    const u16* vh = lsVh[cur];
    const u16* vl = lsVl[cur];

    // QK^T: S^T tile, lane holds 16 scores of q-row q_glob.
    f32x4 s4[4];
#pragma unroll
    for (int sub = 0; sub < 4; ++sub) {
      f32x4 a = {0.f, 0.f, 0.f, 0.f};
      const int kr = sub * 16 + l15;
      const int sw = kr & 7;
#pragma unroll
      for (int c = 0; c < 4; ++c) {
        const int off = kr * 128 + ((((c << 2) | grp) ^ sw) << 3);
        short8 khf = *(const short8*)&kh[off];
        short8 klf = *(const short8*)&kl[off];
        a = __builtin_amdgcn_mfma_f32_16x16x32_bf16(khf, qfh[c], a, 0, 0, 0);
        a = __builtin_amdgcn_mfma_f32_16x16x32_bf16(klf, qfh[c], a, 0, 0, 0);
        a = __builtin_amdgcn_mfma_f32_16x16x32_bf16(khf, qfl[c], a, 0, 0, 0);
      }
      s4[sub] = a;
    }
    if (kt == tend - 1) {
#pragma unroll
      for (int sub = 0; sub < 4; ++sub)
#pragma unroll
        for (int r = 0; r < 4; ++r) {
          int kv = kvb + sub * 16 + grp * 4 + r;
          if (kv > q_glob) s4[sub][r] = -1e30f;
        }
    }
    // Online softmax (lane-local + 2 shfl).
    float tmax = s4[0][0];
#pragma unroll
    for (int sub = 0; sub < 4; ++sub)
#pragma unroll
      for (int r = 0; r < 4; ++r) tmax = fmaxf(tmax, s4[sub][r]);
    tmax = fmaxf(tmax, __shfl_xor(tmax, 16));
    tmax = fmaxf(tmax, __shfl_xor(tmax, 32));
    float mnew = fmaxf(m_run, tmax);
    float scale = expf(m_run - mnew);
    float p[16], lsum = 0.f;
#pragma unroll
    for (int sub = 0; sub < 4; ++sub)
#pragma unroll
      for (int r = 0; r < 4; ++r) {
        float pe = expf(s4[sub][r] - mnew);
        p[sub * 4 + r] = pe;
        lsum += pe;
      }
    lsum += __shfl_xor(lsum, 16);
    lsum += __shfl_xor(lsum, 32);
    l_run = l_run * scale + lsum;
    m_run = mnew;
#pragma unroll
    for (int dc = 0; dc < 8; ++dc) oacc[dc] *= scale;
    // P split -> wave-private LDS.
#pragma unroll
    for (int sub = 0; sub < 4; ++sub)
#pragma unroll
      for (int rp = 0; rp < 2; ++rp) {
        int i0 = sub * 4 + rp * 2;
        u16 h0 = f2bf(p[i0]), h1 = f2bf(p[i0 + 1]);
        u16 lo0 = f2bf(p[i0] - bf2f(h0)), lo1 = f2bf(p[i0 + 1] - bf2f(h1));
        int kvoff = sub * 16 + grp * 4 + rp * 2;
        *(unsigned*)&plh[l15][kvoff] = (unsigned)h0 | ((unsigned)h1 << 16);
        *(unsigned*)&pll[l15][kvoff] = (unsigned)lo0 | ((unsigned)lo1 << 16);
      }
    short8 phf[2], plf[2];
#pragma unroll
    for (int ks = 0; ks < 2; ++ks) {
      phf[ks] = *(const short8*)&plh[l15][ks * 32 + grp * 8];
      plf[ks] = *(const short8*)&pll[l15][ks * 32 + grp * 8];
    }
    // O^T += V^T P^T.
#pragma unroll
    for (int dc = 0; dc < 8; ++dc) {
      const int dr = dc * 16 + l15;
      const int sw = dr & 7;
      f32x4 acc = oacc[dc];
#pragma unroll
      for (int ks = 0; ks < 2; ++ks) {
        const int voff = dr * 64 + ((((ks << 2) | grp) ^ sw) << 3);
        short8 vhf = *(const short8*)&vh[voff];
        short8 vlf = *(const short8*)&vl[voff];
        acc = __builtin_amdgcn_mfma_f32_16x16x32_bf16(vhf, phf[ks], acc, 0, 0, 0);
        acc = __builtin_amdgcn_mfma_f32_16x16x32_bf16(vlf, phf[ks], acc, 0, 0, 0);
        acc = __builtin_amdgcn_mfma_f32_16x16x32_bf16(vhf, plf[ks], acc, 0, 0, 0);
      }
      oacc[dc] = acc;
    }
    __syncthreads();  // drains staging (vmcnt) + LDS; safe to swap buffers
    cur ^= 1;
  }
  float inv = 1.0f / l_run;
#pragma unroll
  for (int dc = 0; dc < 8; ++dc)
#pragma unroll
    for (int rp = 0; rp < 2; ++rp) {
      float v0 = oacc[dc][rp * 2] * inv;
      float v1 = oacc[dc][rp * 2 + 1] * inv;
      u16 h0 = f2bf(v0), h1 = f2bf(v1);
      u16 lo0 = f2bf(v0 - bf2f(h0)), lo1 = f2bf(v1 - bf2f(h1));
      size_t o = (size_t)q_glob * 2048 + hh * 128 + dc * 16 + grp * 4 + rp * 2;
      *(unsigned*)&atth[o] = (unsigned)h0 | ((unsigned)h1 << 16);
      *(unsigned*)&attl[o] = (unsigned)lo0 | ((unsigned)lo1 << 16);
    }
}

// Router: f32 logits (exact top-2 selection); emits top-2 idx + normed weights.
__global__ __launch_bounds__(256) void k_router(const float* __restrict__ h2f,
                                                const float* __restrict__ gw,
                                                int2* __restrict__ tidx,
                                                float2* __restrict__ twgt) {
  const int tok = blockIdx.x;
  const float* hrow = h2f + (size_t)tok * 2048;
  float part[8];
#pragma unroll
  for (int e = 0; e < 8; ++e) part[e] = 0.f;
  for (int j = 0; j < 8; ++j) {
    int p = j * 256 + threadIdx.x;
    float hv = hrow[p];
#pragma unroll
    for (int e = 0; e < 8; ++e) part[e] += hv * gw[e * 2048 + p];
  }
#pragma unroll
  for (int e = 0; e < 8; ++e)
#pragma unroll
    for (int off = 32; off; off >>= 1) part[e] += __shfl_xor(part[e], off);
  __shared__ float red[4][8];
  int wv = threadIdx.x >> 6, lane = threadIdx.x & 63;
  if (lane == 0) {
#pragma unroll
    for (int e = 0; e < 8; ++e) red[wv][e] = part[e];
  }
  __syncthreads();
  if (threadIdx.x == 0) {
    float lg[8];
#pragma unroll
    for (int e = 0; e < 8; ++e) lg[e] = red[0][e] + red[1][e] + red[2][e] + red[3][e];
    float m = lg[0];
#pragma unroll
    for (int e = 1; e < 8; ++e) m = fmaxf(m, lg[e]);
    float ex[8], s = 0.f;
#pragma unroll
    for (int e = 0; e < 8; ++e) { ex[e] = expf(lg[e] - m); s += ex[e]; }
#pragma unroll
    for (int e = 0; e < 8; ++e) ex[e] /= s;
    int i1 = 0;
#pragma unroll
    for (int e = 1; e < 8; ++e) if (ex[e] > ex[i1]) i1 = e;
    int i2 = (i1 == 0) ? 1 : 0;
#pragma unroll
    for (int e = 0; e < 8; ++e) if (e != i1 && ex[e] > ex[i2]) i2 = e;
    float s2 = ex[i1] + ex[i2] + 1e-20f;
    tidx[tok] = make_int2(i1, i2);
    twgt[tok] = make_float2(ex[i1] / s2, ex[i2] / s2);
  }
}

// Deterministic token gather, single wave (race-free). See r3 comments.
__global__ __launch_bounds__(64) void k_scan(const int2* __restrict__ tidx,
                                             const float2* __restrict__ twgt,
                                             int* __restrict__ meta,
                                             int* __restrict__ toklist,
                                             float* __restrict__ slotw,
                                             int* __restrict__ slots) {
  const int lane = threadIdx.x;
  int base = 0;
  for (int e = 0; e < 8; ++e) {
    int cnt = 0;
    for (int c = 0; c < 16; ++c) {
      const int tok = c * 64 + lane;
      int2 my = tidx[tok];
      int f1 = (my.x == e), f2 = (my.y == e);
      int flag = f1 | f2;
      unsigned long long m = __ballot(flag);
      if (flag) {
        float2 w = twgt[tok];
        int rank = (int)__popcll(m & ((1ull << lane) - 1ull));
        int s = base + cnt + rank;
        toklist[s] = tok;
        slotw[s] = f1 ? w.x : w.y;
        slots[tok * 2 + (f1 ? 0 : 1)] = s;
      }
      cnt += (int)__popcll(m);
    }
    if (lane == 0) { meta[e] = base; meta[9 + e] = cnt; }
    const int padded = ((cnt + 127) >> 7) << 7;
    for (int s = cnt + lane; s < padded; s += 64) {
      toklist[base + s] = 0;
      slotw[base + s] = 0.f;
    }
    base += padded;
  }
  if (lane == 0) meta[8] = base;
}

// ---------------- GEMM kernels ----------------
// C[M,N] = A[M,K] @ B[N,K]^T. MFMA 16x16x32 bf16; C/D: col=lane&15,
// row=(lane>>4)*4+reg.

// Staging helpers.
DI void stageA_bf16(const u16* __restrict__ A, size_t lda, int row0, int k0,
                    u16* lsA, int tid) {
  const int lane = tid & 63, wv = tid >> 6;
#pragma unroll
  for (int it = 0; it < 2; ++it) {
    const int ebase = it * 2048 + wv * 512;  // wave-uniform LDS base
    const int eo = ebase + lane * 8;
    const int rr = eo >> 5, cc = eo & 31;
    gload16(A + (size_t)(row0 + rr) * lda + k0 + cc, lsA + ebase);
  }
}
DI void stageB_f32(const float* __restrict__ B, size_t ldb, int row0, int k0,
                   u16* lsB, int tid) {
#pragma unroll
  for (int j = 0; j < 4; ++j) {
    const int eo = (j * 256 + tid) * 4;
    const int rr = eo >> 5, cc = eo & 31;
    float4 bv = *(const float4*)(B + (size_t)(row0 + rr) * ldb + k0 + cc);
    U16x4 hv{f2bf(bv.x), f2bf(bv.y), f2bf(bv.z), f2bf(bv.w)};
    *(U16x4*)&lsB[eo] = hv;
  }
}

// Split GEMM, all-bf16 staging: C = Ah@Bh + Al@Bh + Ah@Bl (+resid).
// z selects among up to 3 (B,C) pairs (QKV fusion / O-proj).
__global__ __launch_bounds__(256) void k_gemm_bf16split(
    const u16* __restrict__ Ah, const u16* __restrict__ Al,
    const u16* __restrict__ Bh0, const u16* __restrict__ Bl0,
    const u16* __restrict__ Bh1, const u16* __restrict__ Bl1,
    const u16* __restrict__ Bh2, const u16* __restrict__ Bl2,
    float* __restrict__ C0, float* __restrict__ C1, float* __restrict__ C2,
    const float* __restrict__ resid) {
  __shared__ u16 lsAh[4096], lsAl[4096], lsBh[4096], lsBl[4096];
  const int z = blockIdx.z;
  const u16* Bh = (z == 0) ? Bh0 : (z == 1) ? Bh1 : Bh2;
  const u16* Bl = (z == 0) ? Bl0 : (z == 1) ? Bl1 : Bl2;
  float* Cm = (z == 0) ? C0 : (z == 1) ? C1 : C2;
  const int tid = threadIdx.x, lane = tid & 63, wv = tid >> 6;
  const int wr = (wv >> 1) * 64, wc = (wv & 1) * 64;
  const int fr = lane & 15, fg = lane >> 4;
  const int row0 = blockIdx.x * 128, col0 = blockIdx.y * 128;
  f32x4 acc[4][4];
#pragma unroll
  for (int i = 0; i < 4; ++i)
#pragma unroll
    for (int j = 0; j < 4; ++j) acc[i][j] = 0.f;

  for (int kt = 0; kt < 64; ++kt) {
    const int k0 = kt * 32;
    stageA_bf16(Ah, 2048, row0, k0, lsAh, tid);
    stageA_bf16(Al, 2048, row0, k0, lsAl, tid);
    stageA_bf16(Bh, 2048, col0, k0, lsBh, tid);
    stageA_bf16(Bl, 2048, col0, k0, lsBl, tid);
    __syncthreads();
    short8 ah[4], al[4], bh[4], bl[4];
#pragma unroll
    for (int mi = 0; mi < 4; ++mi) {
      const int off = (wr + mi * 16 + fr) * 32 + fg * 8;
      ah[mi] = *(const short8*)&lsAh[off];
      al[mi] = *(const short8*)&lsAl[off];
    }
#pragma unroll
    for (int ni = 0; ni < 4; ++ni) {
      const int off = (wc + ni * 16 + fr) * 32 + fg * 8;
      bh[ni] = *(const short8*)&lsBh[off];
      bl[ni] = *(const short8*)&lsBl[off];
    }
#pragma unroll
    for (int mi = 0; mi < 4; ++mi)
#pragma unroll
      for (int ni = 0; ni < 4; ++ni) {
        f32x4 c = acc[mi][ni];
        c = __builtin_amdgcn_mfma_f32_16x16x32_bf16(al[mi], bh[ni], c, 0, 0, 0);
        c = __builtin_amdgcn_mfma_f32_16x16x32_bf16(ah[mi], bl[ni], c, 0, 0, 0);
        c = __builtin_amdgcn_mfma_f32_16x16x32_bf16(ah[mi], bh[ni], c, 0, 0, 0);
        acc[mi][ni] = c;
      }
    __syncthreads();
  }
  const bool hasres = (resid != nullptr);
#pragma unroll
  for (int mi = 0; mi < 4; ++mi)
#pragma unroll
    for (int ni = 0; ni < 4; ++ni)
#pragma unroll
      for (int qq = 0; qq < 4; ++qq) {
        const int row = row0 + wr + mi * 16 + fg * 4 + qq;
        const int col = col0 + wc + ni * 16 + fr;
        float val = acc[mi][ni][qq];
        if (hasres) val += resid[(size_t)row * 2048 + col];
        Cm[(size_t)row * 2048 + col] = val;
      }
}

// Find expert for a padded row-tile index. meta[0..8] = offsets (mult of 128).
DI int tile_to_expert(const int* meta, int t) {
  int e = 0;
  while (e < 7 && t >= (meta[e + 1] >> 7)) ++e;
  return e;
}

// Dense dual GEMM + SiLU for the shared expert: acts = silu(A@Bg^T)*(A@Bu^T).
__global__ __launch_bounds__(256) void k_dual_shared(
    const u16* __restrict__ A, const float* __restrict__ Bg,
    const float* __restrict__ Bu, u16* __restrict__ outp, int ldc) {
  __shared__ u16 lsA[4096], lsG[2048], lsU[2048];
  const int tid = threadIdx.x, lane = tid & 63, wv = tid >> 6;
  const int wr = (wv >> 1) * 64, wc = (wv & 1) * 32;
  const int fr = lane & 15, fg = lane >> 4;
  const int row0 = blockIdx.x * 128, n0 = blockIdx.y * 64;
  f32x4 ag[4][2], au[4][2];
#pragma unroll
  for (int i = 0; i < 4; ++i)
#pragma unroll
    for (int j = 0; j < 2; ++j) { ag[i][j] = 0.f; au[i][j] = 0.f; }

  for (int kt = 0; kt < 64; ++kt) {
    const int k0 = kt * 32;
    stageA_bf16(A, 2048, row0, k0, lsA, tid);
#pragma unroll
    for (int j = 0; j < 2; ++j) {
      const int eo = (j * 256 + tid) * 4;
      const int rr = eo >> 5, cc = eo & 31;
      float4 gv = *(const float4*)(Bg + (size_t)(n0 + rr) * 2048 + k0 + cc);
      float4 uv = *(const float4*)(Bu + (size_t)(n0 + rr) * 2048 + k0 + cc);
      U16x4 gh{f2bf(gv.x), f2bf(gv.y), f2bf(gv.z), f2bf(gv.w)};
      U16x4 uh{f2bf(uv.x), f2bf(uv.y), f2bf(uv.z), f2bf(uv.w)};
      *(U16x4*)&lsG[eo] = gh;
      *(U16x4*)&lsU[eo] = uh;
    }
    __syncthreads();
    short8 af[4], gf[2], uf[2];
#pragma unroll
    for (int mi = 0; mi < 4; ++mi)
      af[mi] = *(const short8*)&lsA[(wr + mi * 16 + fr) * 32 + fg * 8];
#pragma unroll
    for (int ni = 0; ni < 2; ++ni) {
      const int off = (wc + ni * 16 + fr) * 32 + fg * 8;
      gf[ni] = *(const short8*)&lsG[off];
      uf[ni] = *(const short8*)&lsU[off];
    }
#pragma unroll
    for (int mi = 0; mi < 4; ++mi)
#pragma unroll
      for (int ni = 0; ni < 2; ++ni) {
        ag[mi][ni] = __builtin_amdgcn_mfma_f32_16x16x32_bf16(af[mi], gf[ni], ag[mi][ni], 0, 0, 0);
        au[mi][ni] = __builtin_amdgcn_mfma_f32_16x16x32_bf16(af[mi], uf[ni], au[mi][ni], 0, 0, 0);
      }
    __syncthreads();
  }
#pragma unroll
  for (int mi = 0; mi < 4; ++mi)
#pragma unroll
    for (int ni = 0; ni < 2; ++ni)
#pragma unroll
      for (int qq = 0; qq < 4; ++qq) {
        const int row = row0 + wr + mi * 16 + fg * 4 + qq;
        const int col = n0 + wc + ni * 16 + fr;
        float g = ag[mi][ni][qq], u = au[mi][ni][qq];
        float act = g / (1.0f + expf(-g)) * u;
        outp[(size_t)row * ldc + col] = f2bf(act);
      }
}

// Sparse expert dual GEMM: rows gathered by token list; combine weight folded.
__global__ __launch_bounds__(256) void k_dual_sparse(
    const u16* __restrict__ A, const float* __restrict__ eg,
    const float* __restrict__ eu, const int* __restrict__ meta,
    const int* __restrict__ toklist, const float* __restrict__ slotw,
    u16* __restrict__ act) {
  const int t = blockIdx.x;
  if (t >= (meta[8] >> 7)) return;
  __shared__ int toks[128];
  __shared__ u16 lsA[4096], lsG[2048], lsU[2048];
  const int e = tile_to_expert(meta, t);
  const int off_e = meta[e], cnt_e = meta[9 + e];
  const int rtile = t - (off_e >> 7);
  const int tid = threadIdx.x, lane = tid & 63, wv = tid >> 6;
  if (tid < 128) toks[tid] = toklist[off_e + rtile * 128 + tid] & 1023;
  const float* Bg = eg + (size_t)e * 1408 * 2048;
  const float* Bu = eu + (size_t)e * 1408 * 2048;
  const int wr = (wv >> 1) * 64, wc = (wv & 1) * 32;
  const int fr = lane & 15, fg = lane >> 4;
  const int n0 = blockIdx.y * 64;
  f32x4 ag[4][2], au[4][2];
#pragma unroll
  for (int i = 0; i < 4; ++i)
#pragma unroll
    for (int j = 0; j < 2; ++j) { ag[i][j] = 0.f; au[i][j] = 0.f; }
  __syncthreads();

  for (int kt = 0; kt < 64; ++kt) {
    const int k0 = kt * 32;
#pragma unroll
    for (int it = 0; it < 2; ++it) {
      const int ebase = it * 2048 + wv * 512;
      const int eo = ebase + lane * 8;
      const int rr = eo >> 5, cc = eo & 31;
      gload16(A + (size_t)toks[rr] * 2048 + k0 + cc, lsA + ebase);
    }
#pragma unroll
    for (int j = 0; j < 2; ++j) {
      const int eo = (j * 256 + tid) * 4;
      const int rr = eo >> 5, cc = eo & 31;
      float4 gv = *(const float4*)(Bg + (size_t)(n0 + rr) * 2048 + k0 + cc);
      float4 uv = *(const float4*)(Bu + (size_t)(n0 + rr) * 2048 + k0 + cc);
      U16x4 gh{f2bf(gv.x), f2bf(gv.y), f2bf(gv.z), f2bf(gv.w)};
      U16x4 uh{f2bf(uv.x), f2bf(uv.y), f2bf(uv.z), f2bf(uv.w)};
      *(U16x4*)&lsG[eo] = gh;
      *(U16x4*)&lsU[eo] = uh;
    }
    __syncthreads();
    short8 af[4], gf[2], uf[2];
#pragma unroll
    for (int mi = 0; mi < 4; ++mi)
      af[mi] = *(const short8*)&lsA[(wr + mi * 16 + fr) * 32 + fg * 8];
#pragma unroll
    for (int ni = 0; ni < 2; ++ni) {
      const int off = (wc + ni * 16 + fr) * 32 + fg * 8;
      gf[ni] = *(const short8*)&lsG[off];
      uf[ni] = *(const short8*)&lsU[off];
    }
#pragma unroll
    for (int mi = 0; mi < 4; ++mi)
#pragma unroll
      for (int ni = 0; ni < 2; ++ni) {
        ag[mi][ni] = __builtin_amdgcn_mfma_f32_16x16x32_bf16(af[mi], gf[ni], ag[mi][ni], 0, 0, 0);
        au[mi][ni] = __builtin_amdgcn_mfma_f32_16x16x32_bf16(af[mi], uf[ni], au[mi][ni], 0, 0, 0);
      }
    __syncthreads();
  }
#pragma unroll
  for (int mi = 0; mi < 4; ++mi)
#pragma unroll
    for (int ni = 0; ni < 2; ++ni)
#pragma unroll
      for (int qq = 0; qq < 4; ++qq) {
        const int r = wr + mi * 16 + fg * 4 + qq;
        const int rowInE = rtile * 128 + r;
        if (rowInE < cnt_e) {
          const int col = n0 + wc + ni * 16 + fr;
          float g = ag[mi][ni][qq], u = au[mi][ni][qq];
          float a = g / (1.0f + expf(-g)) * u;
          act[(size_t)(off_e + rowInE) * 1408 + col] = f2bf(a * slotw[off_e + rowInE]);
        }
      }
}

// Sparse expert down GEMM: dwn[slot][2048] = act[slot] @ ed[e]^T.
__global__ __launch_bounds__(256) void k_down_sparse(
    const u16* __restrict__ act, const float* __restrict__ ed,
    const int* __restrict__ meta, float* __restrict__ dwn) {
  const int t = blockIdx.x;
  if (t >= (meta[8] >> 7)) return;
  __shared__ u16 lsA[4096], lsB[4096];
  const int e = tile_to_expert(meta, t);
  const int off_e = meta[e];
  const int rtile = t - (off_e >> 7);
  const int tid = threadIdx.x, lane = tid & 63, wv = tid >> 6;
  const int wr = (wv >> 1) * 64, wc = (wv & 1) * 64;
  const int fr = lane & 15, fg = lane >> 4;
  const int col0 = blockIdx.y * 128;
  const u16* Ab = act + (size_t)off_e * 1408;
  const float* Bb = ed + (size_t)e * 2048 * 1408;
  f32x4 acc[4][4];
#pragma unroll
  for (int i = 0; i < 4; ++i)
#pragma unroll
    for (int j = 0; j < 4; ++j) acc[i][j] = 0.f;

  for (int kt = 0; kt < 44; ++kt) {
    const int k0 = kt * 32;
    stageA_bf16(Ab, 1408, rtile * 128, k0, lsA, tid);
    stageB_f32(Bb, 1408, col0, k0, lsB, tid);
    __syncthreads();
    short8 af[4], bf_[4];
#pragma unroll
    for (int mi = 0; mi < 4; ++mi)
      af[mi] = *(const short8*)&lsA[(wr + mi * 16 + fr) * 32 + fg * 8];
#pragma unroll
    for (int ni = 0; ni < 4; ++ni)
      bf_[ni] = *(const short8*)&lsB[(wc + ni * 16 + fr) * 32 + fg * 8];
#pragma unroll
    for (int mi = 0; mi < 4; ++mi)
#pragma unroll
      for (int ni = 0; ni < 4; ++ni)
        acc[mi][ni] = __builtin_amdgcn_mfma_f32_16x16x32_bf16(af[mi], bf_[ni], acc[mi][ni], 0, 0, 0);
    __syncthreads();
  }
#pragma unroll
  for (int mi = 0; mi < 4; ++mi)
#pragma unroll
    for (int ni = 0; ni < 4; ++ni)
#pragma unroll
      for (int qq = 0; qq < 4; ++qq) {
        const int r = wr + mi * 16 + fg * 4 + qq;
        const int col = col0 + wc + ni * 16 + fr;
        dwn[(size_t)(off_e + rtile * 128 + r) * 2048 + col] = acc[mi][ni][qq];
      }
}

// Shared down + final combine: out = x + dwn[slot0] + dwn[slot1] + acts@sd^T.
__global__ __launch_bounds__(256) void k_shareddown(
    const u16* __restrict__ acts, const float* __restrict__ sd,
    const float* __restrict__ x, const float* __restrict__ dwn,
    const int* __restrict__ slots, float* __restrict__ outp) {
  __shared__ u16 lsA[4096], lsB[4096];
  const int tid = threadIdx.x, lane = tid & 63, wv = tid >> 6;
  const int wr = (wv >> 1) * 64, wc = (wv & 1) * 64;
  const int fr = lane & 15, fg = lane >> 4;
  const int row0 = blockIdx.x * 128, col0 = blockIdx.y * 128;
  f32x4 acc[4][4];
#pragma unroll
  for (int i = 0; i < 4; ++i)
#pragma unroll
    for (int j = 0; j < 4; ++j) acc[i][j] = 0.f;

  for (int kt = 0; kt < 88; ++kt) {
    const int k0 = kt * 32;
    stageA_bf16(acts, 2816, row0, k0, lsA, tid);
    stageB_f32(sd, 2816, col0, k0, lsB, tid);
    __syncthreads();
    short8 af[4], bf_[4];
#pragma unroll
    for (int mi = 0; mi < 4; ++mi)
      af[mi] = *(const short8*)&lsA[(wr + mi * 16 + fr) * 32 + fg * 8];
#pragma unroll
    for (int ni = 0; ni < 4; ++ni)
      bf_[ni] = *(const short8*)&lsB[(wc + ni * 16 + fr) * 32 + fg * 8];
#pragma unroll
    for (int mi = 0; mi < 4; ++mi)
#pragma unroll
      for (int ni = 0; ni < 4; ++ni)
        acc[mi][ni] = __builtin_amdgcn_mfma_f32_16x16x32_bf16(af[mi], bf_[ni], acc[mi][ni], 0, 0, 0);
    __syncthreads();
  }
#pragma unroll
  for (int mi = 0; mi < 4; ++mi)
#pragma unroll
    for (int ni = 0; ni < 4; ++ni)
#pragma unroll
      for (int qq = 0; qq < 4; ++qq) {
        const int row = row0 + wr + mi * 16 + fg * 4 + qq;
        const int col = col0 + wc + ni * 16 + fr;
        size_t idx = (size_t)row * 2048 + col;
        int s0 = slots[row * 2], s1 = slots[row * 2 + 1];
        outp[idx] = acc[mi][ni][qq] + x[idx] +
                    dwn[(size_t)s0 * 2048 + col] + dwn[(size_t)s1 * 2048 + col];
      }
}

// ---------------- host launch ----------------

extern "C" void kernel_launch(void* const* d_in, const int* in_sizes, int n_in,
                              void* d_out, int out_size, void* d_ws, size_t ws_size,
                              hipStream_t stream) {
  (void)in_sizes; (void)n_in; (void)out_size; (void)ws_size;
  const float* hidden = (const float*)d_in[0];
  const float* ln1 = (const float*)d_in[1];
  const float* ln2 = (const float*)d_in[2];
  const float* wq = (const float*)d_in[3];
  const float* wk = (const float*)d_in[4];
  const float* wvw = (const float*)d_in[5];
  const float* wo = (const float*)d_in[6];
  const float* gw = (const float*)d_in[7];
  const float* eg = (const float*)d_in[8];
  const float* eu = (const float*)d_in[9];
  const float* ed = (const float*)d_in[10];
  const float* sg = (const float*)d_in[11];
  const float* su = (const float*)d_in[12];
  const float* sd = (const float*)d_in[13];
  float* out = (float*)d_out;
  char* ws = (char*)d_ws;

  const size_t KB = 1ull << 10, MB = 1ull << 20;
  float* tab = (float*)(ws + 0);             // [0, 0.5MB)
  int2* tidx = (int2*)(ws + 512 * KB);
  float2* twgt = (float2*)(ws + 520 * KB);
  int* meta = (int*)(ws + 528 * KB);
  int* tokl = (int*)(ws + 532 * KB);
  float* slw = (float*)(ws + 544 * KB);
  int* slots = (int*)(ws + 556 * KB);
  u16* hnh = (u16*)(ws + 1 * MB);            // [1,5)   dies after QKV
  u16* hnl = (u16*)(ws + 5 * MB);            // [5,9)
  u16* wqh = (u16*)(ws + 9 * MB);            // [9,57): split wq/wk/wv, die after QKV
  u16* wql = (u16*)(ws + 17 * MB);
  u16* wkh = (u16*)(ws + 25 * MB);
  u16* wkl = (u16*)(ws + 33 * MB);
  u16* wvh = (u16*)(ws + 41 * MB);
  u16* wvl = (u16*)(ws + 49 * MB);
  u16* woh = (u16*)(ws + 57 * MB);           // [57,73): dies after O-proj
  u16* wol = (u16*)(ws + 65 * MB);
  float* qf = (float*)(ws + 73 * MB);        // [73,81) dies after splitkv
  float* kf = (float*)(ws + 81 * MB);        // [81,89)
  float* vf = (float*)(ws + 89 * MB);        // [89,97)
  // After QKV GEMM (wq..wvl dead):
  u16* Qh = (u16*)(ws + 9 * MB);             // [9,33): attn operands
  u16* Ql = (u16*)(ws + 13 * MB);
  u16* Kh = (u16*)(ws + 17 * MB);
  u16* Kl = (u16*)(ws + 21 * MB);
  u16* Vth = (u16*)(ws + 25 * MB);
  u16* Vtl = (u16*)(ws + 29 * MB);
  u16* atth = (u16*)(ws + 33 * MB);          // [33,41): dies after O-proj
  u16* attl = (u16*)(ws + 37 * MB);
  float* xf = (float*)(ws + 41 * MB);        // [41,49): residual2 (live to end)
  float* h2f = (float*)(ws + 49 * MB);       // [49,57)
  u16* h2b = (u16*)(ws + 1 * MB);            // [1,5) (hnh dead)
  // MoE (after attn; Qh..Vtl / qf..vf dead):
  u16* act = (u16*)(ws + 73 * MB);           // [73,82)  3072x1408 bf16
  u16* acts = (u16*)(ws + 82 * MB);          // [82,88)  1024x2816 bf16
  float* dwn = (float*)(ws + 9 * MB);        // [9,33)   3072x2048 f32

  k_ropetab<<<256, 256, 0, stream>>>(tab);
  k_rmsnorm<<<1024, 256, 0, stream>>>(hidden, ln1, nullptr, hnh, hnl);
  k_splitf<<<4096, 256, 0, stream>>>(wq, wqh, wql);
  k_splitf<<<4096, 256, 0, stream>>>(wk, wkh, wkl);
  k_splitf<<<4096, 256, 0, stream>>>(wvw, wvh, wvl);
  k_splitf<<<4096, 256, 0, stream>>>(wo, woh, wol);
  k_gemm_bf16split<<<dim3(8, 16, 3), 256, 0, stream>>>(
      hnh, hnl, wqh, wql, wkh, wkl, wvh, wvl, qf, kf, vf, nullptr);
  k_rope<<<4096, 256, 0, stream>>>(qf, kf, tab);
  k_splitkv<<<2048, 256, 0, stream>>>(qf, kf, vf, Qh, Ql, Kh, Kl, Vth, Vtl);
  k_attn_tile<<<dim3(16, 16), 256, 0, stream>>>(Qh, Ql, Kh, Kl, Vth, Vtl, atth, attl);
  k_gemm_bf16split<<<dim3(8, 16, 1), 256, 0, stream>>>(
      atth, attl, woh, wol, woh, wol, woh, wol, xf, xf, xf, hidden);
  k_rmsnorm<<<1024, 256, 0, stream>>>(xf, ln2, h2f, h2b, nullptr);
  k_router<<<1024, 256, 0, stream>>>(h2f, gw, tidx, twgt);
  k_scan<<<1, 64, 0, stream>>>(tidx, twgt, meta, tokl, slw, slots);
  k_dual_sparse<<<dim3(24, 22), 256, 0, stream>>>(h2b, eg, eu, meta, tokl, slw, act);
  k_dual_shared<<<dim3(8, 44), 256, 0, stream>>>(h2b, sg, su, acts, 2816);
  k_down_sparse<<<dim3(24, 16), 256, 0, stream>>>(act, ed, meta, dwn);
  k_shareddown<<<dim3(8, 16), 256, 0, stream>>>(acts, sd, xf, dwn, slots, out);
}

// Round 6
// 608.956 us; speedup vs baseline: 2.5952x; 1.2311x over previous
//
#include <hip/hip_runtime.h>
#include <hip/hip_bf16.h>

// DeepseekDecoderLayer on MI355X. Round 5: fused MoE tail.
// - k_dual_all: sparse top-2 expert dual-GEMM + shared-expert dual-GEMM in ONE
//   880-block launch (shared path = gather with identity token list).
// - k_down_all: sparse down-GEMM (dwn) + shared down-GEMM (shd) fused, 640
//   blocks; the final combine is an elementwise kernel (breaks the old
//   shareddown->dwn dependency that forced serialization).
// - Attention/QKV/O: unchanged from r4 (LDS-staged attn, bf16split GEMMs).

#define DI __device__ __forceinline__

typedef __attribute__((ext_vector_type(8))) short short8;
typedef __attribute__((ext_vector_type(4))) float f32x4;
using u16 = unsigned short;

struct alignas(8) U16x4 { u16 x, y, z, w; };

DI u16 f2bf(float f) {
  unsigned u = __float_as_uint(f);
  u += 0x7fffu + ((u >> 16) & 1u);
  return (u16)(u >> 16);
}
DI float bf2f(u16 h) { return __uint_as_float(((unsigned)h) << 16); }

DI void gload16(const void* g, void* l) {
  __builtin_amdgcn_global_load_lds((const __attribute__((address_space(1))) void*)g,
                                   (__attribute__((address_space(3))) void*)l, 16, 0, 0);
}

// ---------------- small kernels ----------------

// RoPE cos/sin table in double precision (matches f64 numpy reference).
__global__ __launch_bounds__(256) void k_ropetab(float* __restrict__ tab) {
  int idx = blockIdx.x * 256 + threadIdx.x;  // < 1024*64
  int s = idx >> 6, i = idx & 63;
  double inv = pow(10000.0, -(double)(2 * i) / 128.0);
  double ang = (double)s * inv;
  tab[idx * 2 + 0] = (float)cos(ang);
  tab[idx * 2 + 1] = (float)sin(ang);
}

// RMSNorm row kernel: optional f32 out + optional bf16 hi/lo outs.
__global__ __launch_bounds__(256) void k_rmsnorm(const float* __restrict__ in,
                                                 const float* __restrict__ w,
                                                 float* __restrict__ outf,
                                                 u16* __restrict__ outh,
                                                 u16* __restrict__ outl) {
  const int row = blockIdx.x, t = threadIdx.x;
  const float* x = in + (size_t)row * 2048;
  float4 a = *(const float4*)&x[t * 4];
  float4 b = *(const float4*)&x[1024 + t * 4];
  float ss = a.x * a.x + a.y * a.y + a.z * a.z + a.w * a.w +
             b.x * b.x + b.y * b.y + b.z * b.z + b.w * b.w;
#pragma unroll
  for (int off = 32; off; off >>= 1) ss += __shfl_xor(ss, off);
  __shared__ float red[4];
  if ((t & 63) == 0) red[t >> 6] = ss;
  __syncthreads();
  float total = red[0] + red[1] + red[2] + red[3];
  float r = 1.0f / sqrtf(total * (1.0f / 2048.0f) + 1e-6f);
  float4 wa = *(const float4*)&w[t * 4];
  float4 wb = *(const float4*)&w[1024 + t * 4];
  float va[8] = {a.x * r * wa.x, a.y * r * wa.y, a.z * r * wa.z, a.w * r * wa.w,
                 b.x * r * wb.x, b.y * r * wb.y, b.z * r * wb.z, b.w * r * wb.w};
  if (outf) {
    *(float4*)&outf[(size_t)row * 2048 + t * 4] = make_float4(va[0], va[1], va[2], va[3]);
    *(float4*)&outf[(size_t)row * 2048 + 1024 + t * 4] = make_float4(va[4], va[5], va[6], va[7]);
  }
  if (outh) {
    U16x4 ha{f2bf(va[0]), f2bf(va[1]), f2bf(va[2]), f2bf(va[3])};
    U16x4 hb{f2bf(va[4]), f2bf(va[5]), f2bf(va[6]), f2bf(va[7])};
    *(U16x4*)&outh[(size_t)row * 2048 + t * 4] = ha;
    *(U16x4*)&outh[(size_t)row * 2048 + 1024 + t * 4] = hb;
    if (outl) {
      U16x4 la{f2bf(va[0] - bf2f(ha.x)), f2bf(va[1] - bf2f(ha.y)),
               f2bf(va[2] - bf2f(ha.z)), f2bf(va[3] - bf2f(ha.w))};
      U16x4 lb{f2bf(va[4] - bf2f(hb.x)), f2bf(va[5] - bf2f(hb.y)),
               f2bf(va[6] - bf2f(hb.z)), f2bf(va[7] - bf2f(hb.w))};
      *(U16x4*)&outl[(size_t)row * 2048 + t * 4] = la;
      *(U16x4*)&outl[(size_t)row * 2048 + 1024 + t * 4] = lb;
    }
  }
}

// Split an f32 array into bf16 hi/lo (weights prep).
__global__ __launch_bounds__(256) void k_splitf(const float* __restrict__ src,
                                                u16* __restrict__ dh,
                                                u16* __restrict__ dl) {
  int idx = (blockIdx.x * 256 + threadIdx.x) * 4;
  float4 v = *(const float4*)&src[idx];
  U16x4 h{f2bf(v.x), f2bf(v.y), f2bf(v.z), f2bf(v.w)};
  U16x4 l{f2bf(v.x - bf2f(h.x)), f2bf(v.y - bf2f(h.y)),
          f2bf(v.z - bf2f(h.z)), f2bf(v.w - bf2f(h.w))};
  *(U16x4*)&dh[idx] = h;
  *(U16x4*)&dl[idx] = l;
}

// Apply RoPE in-place to q (with 1/sqrt(128) folded in) and k. f32.
__global__ __launch_bounds__(256) void k_rope(float* __restrict__ q, float* __restrict__ k,
                                              const float* __restrict__ tab) {
  int idx = blockIdx.x * 256 + threadIdx.x;  // < 1024*16*64
  int s = idx >> 10, rem = idx & 1023;
  int h = rem >> 6, i = rem & 63;
  size_t base = (size_t)s * 2048 + h * 128 + i;
  float c = tab[(s * 64 + i) * 2 + 0];
  float sn = tab[(s * 64 + i) * 2 + 1];
  const float qs = 0.08838834764831845f;  // 1/sqrt(128)
  float q1 = q[base], q2 = q[base + 64];
  q[base] = (q1 * c - q2 * sn) * qs;
  q[base + 64] = (q2 * c + q1 * sn) * qs;
  float k1 = k[base], k2 = k[base + 64];
  k[base] = k1 * c - k2 * sn;
  k[base + 64] = k2 * c + k1 * sn;
}

// Split f32 q/k/v into bf16 hi/lo. Q,K keep [s][2048] layout; V transposed to
// [h*128+d][s].
__global__ __launch_bounds__(256) void k_splitkv(
    const float* __restrict__ qf, const float* __restrict__ kf,
    const float* __restrict__ vf,
    u16* __restrict__ Qh, u16* __restrict__ Ql,
    u16* __restrict__ Kh, u16* __restrict__ Kl,
    u16* __restrict__ Vth, u16* __restrict__ Vtl) {
  int idx = (blockIdx.x * 256 + threadIdx.x) * 4;  // over 1024*2048 elements
  int s = idx >> 11, c = idx & 2047;
  float4 q4 = *(const float4*)&qf[idx];
  U16x4 qh{f2bf(q4.x), f2bf(q4.y), f2bf(q4.z), f2bf(q4.w)};
  U16x4 ql{f2bf(q4.x - bf2f(qh.x)), f2bf(q4.y - bf2f(qh.y)),
           f2bf(q4.z - bf2f(qh.z)), f2bf(q4.w - bf2f(qh.w))};
  *(U16x4*)&Qh[idx] = qh; *(U16x4*)&Ql[idx] = ql;
  float4 k4 = *(const float4*)&kf[idx];
  U16x4 kh{f2bf(k4.x), f2bf(k4.y), f2bf(k4.z), f2bf(k4.w)};
  U16x4 kl{f2bf(k4.x - bf2f(kh.x)), f2bf(k4.y - bf2f(kh.y)),
           f2bf(k4.z - bf2f(kh.z)), f2bf(k4.w - bf2f(kh.w))};
  *(U16x4*)&Kh[idx] = kh; *(U16x4*)&Kl[idx] = kl;
  float4 v4 = *(const float4*)&vf[idx];
  float vv[4] = {v4.x, v4.y, v4.z, v4.w};
#pragma unroll
  for (int i = 0; i < 4; ++i) {
    u16 hv = f2bf(vv[i]);
    u16 lv = f2bf(vv[i] - bf2f(hv));
    Vth[(size_t)(c + i) * 1024 + s] = hv;
    Vtl[(size_t)(c + i) * 1024 + s] = lv;
  }
}

// ---------------- attention (LDS-staged, double-buffered) ----------------
DI void stage_kv(const u16* __restrict__ Khg, const u16* __restrict__ Klg,
                 const u16* __restrict__ Vhg, const u16* __restrict__ Vlg,
                 u16* lsKh, u16* lsKl, u16* lsVh, u16* lsVl,
                 int kvb, int hh, int wv, int lane) {
#pragma unroll
  for (int it = 0; it < 4; ++it) {
    const int ebase = it * 2048 + wv * 512;  // wave-uniform LDS base
    const int eo = ebase + lane * 8;
    {  // K tile [64 kv][128 d]
      const int rr = eo >> 7, cg = (eo >> 3) & 15;
      const size_t src = (size_t)(kvb + rr) * 2048 + hh * 128 + ((cg ^ (rr & 7)) << 3);
      gload16(Khg + src, lsKh + ebase);
      gload16(Klg + src, lsKl + ebase);
    }
    {  // V tile [128 d][64 kv]
      const int rr = eo >> 6, cg = (eo >> 3) & 7;
      const size_t src = (size_t)(hh * 128 + rr) * 1024 + kvb + ((cg ^ (rr & 7)) << 3);
      gload16(Vhg + src, lsVh + ebase);
      gload16(Vlg + src, lsVl + ebase);
    }
  }
}

__global__ __launch_bounds__(256) void k_attn_tile(
    const u16* __restrict__ Qh, const u16* __restrict__ Ql,
    const u16* __restrict__ Khg, const u16* __restrict__ Klg,
    const u16* __restrict__ Vhg, const u16* __restrict__ Vlg,
    u16* __restrict__ atth, u16* __restrict__ attl) {
  __shared__ u16 lsKh[2][8192], lsKl[2][8192], lsVh[2][8192], lsVl[2][8192];  // 128KB
  __shared__ u16 Plh[4][16][72], Pll[4][16][72];                              // 18KB
  const int hh = blockIdx.y;
  const int qb = blockIdx.x * 64;
  const int tid = threadIdx.x, lane = tid & 63, wv = tid >> 6;
  const int l15 = lane & 15, grp = lane >> 4;
  u16(*plh)[72] = Plh[wv];
  u16(*pll)[72] = Pll[wv];
  const int q_glob = qb + wv * 16 + l15;
  const int tend = blockIdx.x + 1;

  short8 qfh[4], qfl[4];
  const size_t qbase = (size_t)q_glob * 2048 + hh * 128;
#pragma unroll
  for (int c = 0; c < 4; ++c) {
    qfh[c] = *(const short8*)&Qh[qbase + c * 32 + grp * 8];
    qfl[c] = *(const short8*)&Ql[qbase + c * 32 + grp * 8];
  }
  f32x4 oacc[8];
#pragma unroll
  for (int dc = 0; dc < 8; ++dc) oacc[dc] = 0.f;
  float m_run = -1e30f, l_run = 0.f;

  int cur = 0;
  stage_kv(Khg, Klg, Vhg, Vlg, lsKh[0], lsKl[0], lsVh[0], lsVl[0], 0, hh, wv, lane);
  __syncthreads();

  for (int kt = 0; kt < tend; ++kt) {
    const int kvb = kt * 64;
    if (kt + 1 < tend)
      stage_kv(Khg, Klg, Vhg, Vlg, lsKh[cur ^ 1], lsKl[cur ^ 1], lsVh[cur ^ 1],
               lsVl[cur ^ 1], kvb + 64, hh, wv, lane);
    const u16* kh = lsKh[cur];
    const u16* kl = lsKl[cur];
    const u16* vh = lsVh[cur];
    const u16* vl = lsVl[cur];

    f32x4 s4[4];
#pragma unroll
    for (int sub = 0; sub < 4; ++sub) {
      f32x4 a = {0.f, 0.f, 0.f, 0.f};
      const int kr = sub * 16 + l15;
      const int sw = kr & 7;
#pragma unroll
      for (int c = 0; c < 4; ++c) {
        const int off = kr * 128 + ((((c << 2) | grp) ^ sw) << 3);
        short8 khf = *(const short8*)&kh[off];
        short8 klf = *(const short8*)&kl[off];
        a = __builtin_amdgcn_mfma_f32_16x16x32_bf16(khf, qfh[c], a, 0, 0, 0);
        a = __builtin_amdgcn_mfma_f32_16x16x32_bf16(klf, qfh[c], a, 0, 0, 0);
        a = __builtin_amdgcn_mfma_f32_16x16x32_bf16(khf, qfl[c], a, 0, 0, 0);
      }
      s4[sub] = a;
    }
    if (kt == tend - 1) {
#pragma unroll
      for (int sub = 0; sub < 4; ++sub)
#pragma unroll
        for (int r = 0; r < 4; ++r) {
          int kv = kvb + sub * 16 + grp * 4 + r;
          if (kv > q_glob) s4[sub][r] = -1e30f;
        }
    }
    float tmax = s4[0][0];
#pragma unroll
    for (int sub = 0; sub < 4; ++sub)
#pragma unroll
      for (int r = 0; r < 4; ++r) tmax = fmaxf(tmax, s4[sub][r]);
    tmax = fmaxf(tmax, __shfl_xor(tmax, 16));
    tmax = fmaxf(tmax, __shfl_xor(tmax, 32));
    float mnew = fmaxf(m_run, tmax);
    float scale = expf(m_run - mnew);
    float p[16], lsum = 0.f;
#pragma unroll
    for (int sub = 0; sub < 4; ++sub)
#pragma unroll
      for (int r = 0; r < 4; ++r) {
        float pe = expf(s4[sub][r] - mnew);
        p[sub * 4 + r] = pe;
        lsum += pe;
      }
    lsum += __shfl_xor(lsum, 16);
    lsum += __shfl_xor(lsum, 32);
    l_run = l_run * scale + lsum;
    m_run = mnew;
#pragma unroll
    for (int dc = 0; dc < 8; ++dc) oacc[dc] *= scale;
#pragma unroll
    for (int sub = 0; sub < 4; ++sub)
#pragma unroll
      for (int rp = 0; rp < 2; ++rp) {
        int i0 = sub * 4 + rp * 2;
        u16 h0 = f2bf(p[i0]), h1 = f2bf(p[i0 + 1]);
        u16 lo0 = f2bf(p[i0] - bf2f(h0)), lo1 = f2bf(p[i0 + 1] - bf2f(h1));
        int kvoff = sub * 16 + grp * 4 + rp * 2;
        *(unsigned*)&plh[l15][kvoff] = (unsigned)h0 | ((unsigned)h1 << 16);
        *(unsigned*)&pll[l15][kvoff] = (unsigned)lo0 | ((unsigned)lo1 << 16);
      }
    short8 phf[2], plf[2];
#pragma unroll
    for (int ks = 0; ks < 2; ++ks) {
      phf[ks] = *(const short8*)&plh[l15][ks * 32 + grp * 8];
      plf[ks] = *(const short8*)&pll[l15][ks * 32 + grp * 8];
    }
#pragma unroll
    for (int dc = 0; dc < 8; ++dc) {
      const int dr = dc * 16 + l15;
      const int sw = dr & 7;
      f32x4 acc = oacc[dc];
#pragma unroll
      for (int ks = 0; ks < 2; ++ks) {
        const int voff = dr * 64 + ((((ks << 2) | grp) ^ sw) << 3);
        short8 vhf = *(const short8*)&vh[voff];
        short8 vlf = *(const short8*)&vl[voff];
        acc = __builtin_amdgcn_mfma_f32_16x16x32_bf16(vhf, phf[ks], acc, 0, 0, 0);
        acc = __builtin_amdgcn_mfma_f32_16x16x32_bf16(vlf, phf[ks], acc, 0, 0, 0);
        acc = __builtin_amdgcn_mfma_f32_16x16x32_bf16(vhf, plf[ks], acc, 0, 0, 0);
      }
      oacc[dc] = acc;
    }
    __syncthreads();
    cur ^= 1;
  }
  float inv = 1.0f / l_run;
#pragma unroll
  for (int dc = 0; dc < 8; ++dc)
#pragma unroll
    for (int rp = 0; rp < 2; ++rp) {
      float v0 = oacc[dc][rp * 2] * inv;
      float v1 = oacc[dc][rp * 2 + 1] * inv;
      u16 h0 = f2bf(v0), h1 = f2bf(v1);
      u16 lo0 = f2bf(v0 - bf2f(h0)), lo1 = f2bf(v1 - bf2f(h1));
      size_t o = (size_t)q_glob * 2048 + hh * 128 + dc * 16 + grp * 4 + rp * 2;
      *(unsigned*)&atth[o] = (unsigned)h0 | ((unsigned)h1 << 16);
      *(unsigned*)&attl[o] = (unsigned)lo0 | ((unsigned)lo1 << 16);
    }
}

// Router: f32 logits (exact top-2 selection); emits top-2 idx + normed weights.
__global__ __launch_bounds__(256) void k_router(const float* __restrict__ h2f,
                                                const float* __restrict__ gw,
                                                int2* __restrict__ tidx,
                                                float2* __restrict__ twgt) {
  const int tok = blockIdx.x;
  const float* hrow = h2f + (size_t)tok * 2048;
  float part[8];
#pragma unroll
  for (int e = 0; e < 8; ++e) part[e] = 0.f;
  for (int j = 0; j < 8; ++j) {
    int p = j * 256 + threadIdx.x;
    float hv = hrow[p];
#pragma unroll
    for (int e = 0; e < 8; ++e) part[e] += hv * gw[e * 2048 + p];
  }
#pragma unroll
  for (int e = 0; e < 8; ++e)
#pragma unroll
    for (int off = 32; off; off >>= 1) part[e] += __shfl_xor(part[e], off);
  __shared__ float red[4][8];
  int wv = threadIdx.x >> 6, lane = threadIdx.x & 63;
  if (lane == 0) {
#pragma unroll
    for (int e = 0; e < 8; ++e) red[wv][e] = part[e];
  }
  __syncthreads();
  if (threadIdx.x == 0) {
    float lg[8];
#pragma unroll
    for (int e = 0; e < 8; ++e) lg[e] = red[0][e] + red[1][e] + red[2][e] + red[3][e];
    float m = lg[0];
#pragma unroll
    for (int e = 1; e < 8; ++e) m = fmaxf(m, lg[e]);
    float ex[8], s = 0.f;
#pragma unroll
    for (int e = 0; e < 8; ++e) { ex[e] = expf(lg[e] - m); s += ex[e]; }
#pragma unroll
    for (int e = 0; e < 8; ++e) ex[e] /= s;
    int i1 = 0;
#pragma unroll
    for (int e = 1; e < 8; ++e) if (ex[e] > ex[i1]) i1 = e;
    int i2 = (i1 == 0) ? 1 : 0;
#pragma unroll
    for (int e = 0; e < 8; ++e) if (e != i1 && ex[e] > ex[i2]) i2 = e;
    float s2 = ex[i1] + ex[i2] + 1e-20f;
    tidx[tok] = make_int2(i1, i2);
    twgt[tok] = make_float2(ex[i1] / s2, ex[i2] / s2);
  }
}

// Deterministic token gather, single wave (race-free). See r3 comments.
__global__ __launch_bounds__(64) void k_scan(const int2* __restrict__ tidx,
                                             const float2* __restrict__ twgt,
                                             int* __restrict__ meta,
                                             int* __restrict__ toklist,
                                             float* __restrict__ slotw,
                                             int* __restrict__ slots) {
  const int lane = threadIdx.x;
  int base = 0;
  for (int e = 0; e < 8; ++e) {
    int cnt = 0;
    for (int c = 0; c < 16; ++c) {
      const int tok = c * 64 + lane;
      int2 my = tidx[tok];
      int f1 = (my.x == e), f2 = (my.y == e);
      int flag = f1 | f2;
      unsigned long long m = __ballot(flag);
      if (flag) {
        float2 w = twgt[tok];
        int rank = (int)__popcll(m & ((1ull << lane) - 1ull));
        int s = base + cnt + rank;
        toklist[s] = tok;
        slotw[s] = f1 ? w.x : w.y;
        slots[tok * 2 + (f1 ? 0 : 1)] = s;
      }
      cnt += (int)__popcll(m);
    }
    if (lane == 0) { meta[e] = base; meta[9 + e] = cnt; }
    const int padded = ((cnt + 127) >> 7) << 7;
    for (int s = cnt + lane; s < padded; s += 64) {
      toklist[base + s] = 0;
      slotw[base + s] = 0.f;
    }
    base += padded;
  }
  if (lane == 0) meta[8] = base;
}

// ---------------- GEMM kernels ----------------
// C[M,N] = A[M,K] @ B[N,K]^T. MFMA 16x16x32 bf16; C/D: col=lane&15,
// row=(lane>>4)*4+reg.

DI void stageA_bf16(const u16* __restrict__ A, size_t lda, int row0, int k0,
                    u16* lsA, int tid) {
  const int lane = tid & 63, wv = tid >> 6;
#pragma unroll
  for (int it = 0; it < 2; ++it) {
    const int ebase = it * 2048 + wv * 512;  // wave-uniform LDS base
    const int eo = ebase + lane * 8;
    const int rr = eo >> 5, cc = eo & 31;
    gload16(A + (size_t)(row0 + rr) * lda + k0 + cc, lsA + ebase);
  }
}
DI void stageB_f32(const float* __restrict__ B, size_t ldb, int row0, int k0,
                   u16* lsB, int tid) {
#pragma unroll
  for (int j = 0; j < 4; ++j) {
    const int eo = (j * 256 + tid) * 4;
    const int rr = eo >> 5, cc = eo & 31;
    float4 bv = *(const float4*)(B + (size_t)(row0 + rr) * ldb + k0 + cc);
    U16x4 hv{f2bf(bv.x), f2bf(bv.y), f2bf(bv.z), f2bf(bv.w)};
    *(U16x4*)&lsB[eo] = hv;
  }
}
// 64-row variant ([64][32] tile).
DI void stageB64_f32(const float* __restrict__ B, size_t ldb, int row0, int k0,
                     u16* lsB, int tid) {
#pragma unroll
  for (int j = 0; j < 2; ++j) {
    const int eo = (j * 256 + tid) * 4;
    const int rr = eo >> 5, cc = eo & 31;
    float4 bv = *(const float4*)(B + (size_t)(row0 + rr) * ldb + k0 + cc);
    U16x4 hv{f2bf(bv.x), f2bf(bv.y), f2bf(bv.z), f2bf(bv.w)};
    *(U16x4*)&lsB[eo] = hv;
  }
}

// Split GEMM, all-bf16 staging: C = Ah@Bh + Al@Bh + Ah@Bl (+resid).
__global__ __launch_bounds__(256) void k_gemm_bf16split(
    const u16* __restrict__ Ah, const u16* __restrict__ Al,
    const u16* __restrict__ Bh0, const u16* __restrict__ Bl0,
    const u16* __restrict__ Bh1, const u16* __restrict__ Bl1,
    const u16* __restrict__ Bh2, const u16* __restrict__ Bl2,
    float* __restrict__ C0, float* __restrict__ C1, float* __restrict__ C2,
    const float* __restrict__ resid) {
  __shared__ u16 lsAh[4096], lsAl[4096], lsBh[4096], lsBl[4096];
  const int z = blockIdx.z;
  const u16* Bh = (z == 0) ? Bh0 : (z == 1) ? Bh1 : Bh2;
  const u16* Bl = (z == 0) ? Bl0 : (z == 1) ? Bl1 : Bl2;
  float* Cm = (z == 0) ? C0 : (z == 1) ? C1 : C2;
  const int tid = threadIdx.x, lane = tid & 63, wv = tid >> 6;
  const int wr = (wv >> 1) * 64, wc = (wv & 1) * 64;
  const int fr = lane & 15, fg = lane >> 4;
  const int row0 = blockIdx.x * 128, col0 = blockIdx.y * 128;
  f32x4 acc[4][4];
#pragma unroll
  for (int i = 0; i < 4; ++i)
#pragma unroll
    for (int j = 0; j < 4; ++j) acc[i][j] = 0.f;

  for (int kt = 0; kt < 64; ++kt) {
    const int k0 = kt * 32;
    stageA_bf16(Ah, 2048, row0, k0, lsAh, tid);
    stageA_bf16(Al, 2048, row0, k0, lsAl, tid);
    stageA_bf16(Bh, 2048, col0, k0, lsBh, tid);
    stageA_bf16(Bl, 2048, col0, k0, lsBl, tid);
    __syncthreads();
    short8 ah[4], al[4], bh[4], bl[4];
#pragma unroll
    for (int mi = 0; mi < 4; ++mi) {
      const int off = (wr + mi * 16 + fr) * 32 + fg * 8;
      ah[mi] = *(const short8*)&lsAh[off];
      al[mi] = *(const short8*)&lsAl[off];
    }
#pragma unroll
    for (int ni = 0; ni < 4; ++ni) {
      const int off = (wc + ni * 16 + fr) * 32 + fg * 8;
      bh[ni] = *(const short8*)&lsBh[off];
      bl[ni] = *(const short8*)&lsBl[off];
    }
#pragma unroll
    for (int mi = 0; mi < 4; ++mi)
#pragma unroll
      for (int ni = 0; ni < 4; ++ni) {
        f32x4 c = acc[mi][ni];
        c = __builtin_amdgcn_mfma_f32_16x16x32_bf16(al[mi], bh[ni], c, 0, 0, 0);
        c = __builtin_amdgcn_mfma_f32_16x16x32_bf16(ah[mi], bl[ni], c, 0, 0, 0);
        c = __builtin_amdgcn_mfma_f32_16x16x32_bf16(ah[mi], bh[ni], c, 0, 0, 0);
        acc[mi][ni] = c;
      }
    __syncthreads();
  }
  const bool hasres = (resid != nullptr);
#pragma unroll
  for (int mi = 0; mi < 4; ++mi)
#pragma unroll
    for (int ni = 0; ni < 4; ++ni)
#pragma unroll
      for (int qq = 0; qq < 4; ++qq) {
        const int row = row0 + wr + mi * 16 + fg * 4 + qq;
        const int col = col0 + wc + ni * 16 + fr;
        float val = acc[mi][ni][qq];
        if (hasres) val += resid[(size_t)row * 2048 + col];
        Cm[(size_t)row * 2048 + col] = val;
      }
}

// Find expert for a padded row-tile index. meta[0..8] = offsets (mult of 128).
DI int tile_to_expert(const int* meta, int t) {
  int e = 0;
  while (e < 7 && t >= (meta[e + 1] >> 7)) ++e;
  return e;
}

// Fused dual GEMM + SiLU: sparse expert tiles (bid<528) + shared expert
// (bid>=528). Shared path reuses the gather machinery with identity toks.
// Per block: 128 rows x 64 cols, K=2048.
__global__ __launch_bounds__(256) void k_dual_all(
    const u16* __restrict__ h2b, const float* __restrict__ eg,
    const float* __restrict__ eu, const float* __restrict__ sg,
    const float* __restrict__ su, const int* __restrict__ meta,
    const int* __restrict__ toklist, const float* __restrict__ slotw,
    u16* __restrict__ act, u16* __restrict__ acts) {
  const int bid = blockIdx.x;
  const bool isShared = bid >= 528;
  __shared__ int toks[128];
  __shared__ u16 lsA[4096], lsG[2048], lsU[2048];
  const int tid = threadIdx.x, lane = tid & 63, wv = tid >> 6;
  const int wr = (wv >> 1) * 64, wc = (wv & 1) * 32;
  const int fr = lane & 15, fg = lane >> 4;

  int n0, e = 0, off_e = 0, cnt_e = 0, rtile = 0;
  const float *Bg, *Bu;
  if (isShared) {
    const int b2 = bid - 528;
    rtile = b2 / 44;
    n0 = (b2 % 44) * 64;
    Bg = sg;
    Bu = su;
    if (tid < 128) toks[tid] = rtile * 128 + tid;
  } else {
    const int t = bid / 22;
    if (t >= (meta[8] >> 7)) return;
    n0 = (bid % 22) * 64;
    e = tile_to_expert(meta, t);
    off_e = meta[e];
    cnt_e = meta[9 + e];
    rtile = t - (off_e >> 7);
    Bg = eg + (size_t)e * 1408 * 2048;
    Bu = eu + (size_t)e * 1408 * 2048;
    if (tid < 128) toks[tid] = toklist[off_e + rtile * 128 + tid] & 1023;
  }
  f32x4 ag[4][2], au[4][2];
#pragma unroll
  for (int i = 0; i < 4; ++i)
#pragma unroll
    for (int j = 0; j < 2; ++j) { ag[i][j] = 0.f; au[i][j] = 0.f; }
  __syncthreads();

  for (int kt = 0; kt < 64; ++kt) {
    const int k0 = kt * 32;
    // A gather: per-lane global source, linear LDS dest.
#pragma unroll
    for (int it = 0; it < 2; ++it) {
      const int ebase = it * 2048 + wv * 512;
      const int eo = ebase + lane * 8;
      const int rr = eo >> 5, cc = eo & 31;
      gload16(h2b + (size_t)toks[rr] * 2048 + k0 + cc, lsA + ebase);
    }
#pragma unroll
    for (int j = 0; j < 2; ++j) {
      const int eo = (j * 256 + tid) * 4;
      const int rr = eo >> 5, cc = eo & 31;
      float4 gv = *(const float4*)(Bg + (size_t)(n0 + rr) * 2048 + k0 + cc);
      float4 uv = *(const float4*)(Bu + (size_t)(n0 + rr) * 2048 + k0 + cc);
      U16x4 gh{f2bf(gv.x), f2bf(gv.y), f2bf(gv.z), f2bf(gv.w)};
      U16x4 uh{f2bf(uv.x), f2bf(uv.y), f2bf(uv.z), f2bf(uv.w)};
      *(U16x4*)&lsG[eo] = gh;
      *(U16x4*)&lsU[eo] = uh;
    }
    __syncthreads();
    short8 af[4], gf[2], uf[2];
#pragma unroll
    for (int mi = 0; mi < 4; ++mi)
      af[mi] = *(const short8*)&lsA[(wr + mi * 16 + fr) * 32 + fg * 8];
#pragma unroll
    for (int ni = 0; ni < 2; ++ni) {
      const int off = (wc + ni * 16 + fr) * 32 + fg * 8;
      gf[ni] = *(const short8*)&lsG[off];
      uf[ni] = *(const short8*)&lsU[off];
    }
#pragma unroll
    for (int mi = 0; mi < 4; ++mi)
#pragma unroll
      for (int ni = 0; ni < 2; ++ni) {
        ag[mi][ni] = __builtin_amdgcn_mfma_f32_16x16x32_bf16(af[mi], gf[ni], ag[mi][ni], 0, 0, 0);
        au[mi][ni] = __builtin_amdgcn_mfma_f32_16x16x32_bf16(af[mi], uf[ni], au[mi][ni], 0, 0, 0);
      }
    __syncthreads();
  }
#pragma unroll
  for (int mi = 0; mi < 4; ++mi)
#pragma unroll
    for (int ni = 0; ni < 2; ++ni)
#pragma unroll
      for (int qq = 0; qq < 4; ++qq) {
        const int r = wr + mi * 16 + fg * 4 + qq;
        const int col = n0 + wc + ni * 16 + fr;
        float g = ag[mi][ni][qq], u = au[mi][ni][qq];
        float a = g / (1.0f + expf(-g)) * u;
        if (isShared) {
          acts[(size_t)(rtile * 128 + r) * 2816 + col] = f2bf(a);
        } else {
          const int rowInE = rtile * 128 + r;
          if (rowInE < cnt_e)
            act[(size_t)(off_e + rowInE) * 1408 + col] = f2bf(a * slotw[off_e + rowInE]);
        }
      }
}

// Fused down GEMMs: sparse (bid<384, 128x128, K=1408 -> dwn) + shared
// (bid>=384, 128x64, K=2816 -> shd). Independent outputs; combined later.
__global__ __launch_bounds__(256) void k_down_all(
    const u16* __restrict__ act, const float* __restrict__ ed,
    const u16* __restrict__ acts, const float* __restrict__ sd,
    const int* __restrict__ meta, float* __restrict__ dwn,
    float* __restrict__ shd) {
  __shared__ u16 lsA[4096], lsB[4096];
  const int bid = blockIdx.x;
  const int tid = threadIdx.x, lane = tid & 63, wv = tid >> 6;
  const int fr = lane & 15, fg = lane >> 4;
  if (bid < 384) {
    const int t = bid >> 4;
    if (t >= (meta[8] >> 7)) return;
    const int col0 = (bid & 15) * 128;
    const int e = tile_to_expert(meta, t);
    const int off_e = meta[e];
    const int rtile = t - (off_e >> 7);
    const int wr = (wv >> 1) * 64, wc = (wv & 1) * 64;
    const u16* Ab = act + (size_t)off_e * 1408;
    const float* Bb = ed + (size_t)e * 2048 * 1408;
    f32x4 acc[4][4];
#pragma unroll
    for (int i = 0; i < 4; ++i)
#pragma unroll
      for (int j = 0; j < 4; ++j) acc[i][j] = 0.f;
    for (int kt = 0; kt < 44; ++kt) {
      const int k0 = kt * 32;
      stageA_bf16(Ab, 1408, rtile * 128, k0, lsA, tid);
      stageB_f32(Bb, 1408, col0, k0, lsB, tid);
      __syncthreads();
      short8 af[4], bf_[4];
#pragma unroll
      for (int mi = 0; mi < 4; ++mi)
        af[mi] = *(const short8*)&lsA[(wr + mi * 16 + fr) * 32 + fg * 8];
#pragma unroll
      for (int ni = 0; ni < 4; ++ni)
        bf_[ni] = *(const short8*)&lsB[(wc + ni * 16 + fr) * 32 + fg * 8];
#pragma unroll
      for (int mi = 0; mi < 4; ++mi)
#pragma unroll
        for (int ni = 0; ni < 4; ++ni)
          acc[mi][ni] = __builtin_amdgcn_mfma_f32_16x16x32_bf16(af[mi], bf_[ni], acc[mi][ni], 0, 0, 0);
      __syncthreads();
    }
#pragma unroll
    for (int mi = 0; mi < 4; ++mi)
#pragma unroll
      for (int ni = 0; ni < 4; ++ni)
#pragma unroll
        for (int qq = 0; qq < 4; ++qq) {
          const int r = wr + mi * 16 + fg * 4 + qq;
          const int col = col0 + wc + ni * 16 + fr;
          dwn[(size_t)(off_e + rtile * 128 + r) * 2048 + col] = acc[mi][ni][qq];
        }
  } else {
    const int b2 = bid - 384;
    const int row0 = (b2 >> 5) * 128;
    const int col0 = (b2 & 31) * 64;
    const int wr = (wv >> 1) * 64, wc = (wv & 1) * 32;
    f32x4 acc[4][2];
#pragma unroll
    for (int i = 0; i < 4; ++i)
#pragma unroll
      for (int j = 0; j < 2; ++j) acc[i][j] = 0.f;
    for (int kt = 0; kt < 88; ++kt) {
      const int k0 = kt * 32;
      stageA_bf16(acts, 2816, row0, k0, lsA, tid);
      stageB64_f32(sd, 2816, col0, k0, lsB, tid);
      __syncthreads();
      short8 af[4], bf_[2];
#pragma unroll
      for (int mi = 0; mi < 4; ++mi)
        af[mi] = *(const short8*)&lsA[(wr + mi * 16 + fr) * 32 + fg * 8];
#pragma unroll
      for (int ni = 0; ni < 2; ++ni)
        bf_[ni] = *(const short8*)&lsB[(wc + ni * 16 + fr) * 32 + fg * 8];
#pragma unroll
      for (int mi = 0; mi < 4; ++mi)
#pragma unroll
        for (int ni = 0; ni < 2; ++ni)
          acc[mi][ni] = __builtin_amdgcn_mfma_f32_16x16x32_bf16(af[mi], bf_[ni], acc[mi][ni], 0, 0, 0);
      __syncthreads();
    }
#pragma unroll
    for (int mi = 0; mi < 4; ++mi)
#pragma unroll
      for (int ni = 0; ni < 2; ++ni)
#pragma unroll
        for (int qq = 0; qq < 4; ++qq) {
          const int row = row0 + wr + mi * 16 + fg * 4 + qq;
          const int col = col0 + wc + ni * 16 + fr;
          shd[(size_t)row * 2048 + col] = acc[mi][ni][qq];
        }
  }
}

// Final combine: out = x + shd + dwn[slot0] + dwn[slot1].
__global__ __launch_bounds__(256) void k_combine(
    const float* __restrict__ shd, const float* __restrict__ x,
    const float* __restrict__ dwn, const int* __restrict__ slots,
    float* __restrict__ outp) {
  const int i4 = (blockIdx.x * 256 + threadIdx.x) * 4;
  const int row = i4 >> 11, col = i4 & 2047;
  const int s0 = slots[row * 2], s1 = slots[row * 2 + 1];
  float4 a = *(const float4*)&shd[i4];
  float4 b = *(const float4*)&x[i4];
  float4 c = *(const float4*)&dwn[(size_t)s0 * 2048 + col];
  float4 d = *(const float4*)&dwn[(size_t)s1 * 2048 + col];
  float4 o;
  o.x = a.x + b.x + c.x + d.x;
  o.y = a.y + b.y + c.y + d.y;
  o.z = a.z + b.z + c.z + d.z;
  o.w = a.w + b.w + c.w + d.w;
  *(float4*)&outp[i4] = o;
}

// ---------------- host launch ----------------

extern "C" void kernel_launch(void* const* d_in, const int* in_sizes, int n_in,
                              void* d_out, int out_size, void* d_ws, size_t ws_size,
                              hipStream_t stream) {
  (void)in_sizes; (void)n_in; (void)out_size; (void)ws_size;
  const float* hidden = (const float*)d_in[0];
  const float* ln1 = (const float*)d_in[1];
  const float* ln2 = (const float*)d_in[2];
  const float* wq = (const float*)d_in[3];
  const float* wk = (const float*)d_in[4];
  const float* wvw = (const float*)d_in[5];
  const float* wo = (const float*)d_in[6];
  const float* gw = (const float*)d_in[7];
  const float* eg = (const float*)d_in[8];
  const float* eu = (const float*)d_in[9];
  const float* ed = (const float*)d_in[10];
  const float* sg = (const float*)d_in[11];
  const float* su = (const float*)d_in[12];
  const float* sd = (const float*)d_in[13];
  float* out = (float*)d_out;
  char* ws = (char*)d_ws;

  const size_t KB = 1ull << 10, MB = 1ull << 20;
  float* tab = (float*)(ws + 0);             // [0, 0.5MB)
  int2* tidx = (int2*)(ws + 512 * KB);
  float2* twgt = (float2*)(ws + 520 * KB);
  int* meta = (int*)(ws + 528 * KB);
  int* tokl = (int*)(ws + 532 * KB);
  float* slw = (float*)(ws + 544 * KB);
  int* slots = (int*)(ws + 556 * KB);
  u16* hnh = (u16*)(ws + 1 * MB);            // [1,5)   dies after QKV
  u16* hnl = (u16*)(ws + 5 * MB);            // [5,9)
  u16* wqh = (u16*)(ws + 9 * MB);            // [9,57): split wq/wk/wv, die after QKV
  u16* wql = (u16*)(ws + 17 * MB);
  u16* wkh = (u16*)(ws + 25 * MB);
  u16* wkl = (u16*)(ws + 33 * MB);
  u16* wvh = (u16*)(ws + 41 * MB);
  u16* wvl = (u16*)(ws + 49 * MB);
  u16* woh = (u16*)(ws + 57 * MB);           // [57,73): dies after O-proj
  u16* wol = (u16*)(ws + 65 * MB);
  float* qf = (float*)(ws + 73 * MB);        // [73,81) dies after splitkv
  float* kf = (float*)(ws + 81 * MB);        // [81,89)
  float* vf = (float*)(ws + 89 * MB);        // [89,97)
  // After QKV GEMM (wq..wvl dead):
  u16* Qh = (u16*)(ws + 9 * MB);             // [9,33): attn operands
  u16* Ql = (u16*)(ws + 13 * MB);
  u16* Kh = (u16*)(ws + 17 * MB);
  u16* Kl = (u16*)(ws + 21 * MB);
  u16* Vth = (u16*)(ws + 25 * MB);
  u16* Vtl = (u16*)(ws + 29 * MB);
  u16* atth = (u16*)(ws + 33 * MB);          // [33,41): dies after O-proj
  u16* attl = (u16*)(ws + 37 * MB);
  float* xf = (float*)(ws + 41 * MB);        // [41,49): residual2 (live to end)
  float* h2f = (float*)(ws + 49 * MB);       // [49,57)
  u16* h2b = (u16*)(ws + 1 * MB);            // [1,5) (hnh dead)
  // MoE (after attn; Qh..Vtl / qf..vf / atth dead):
  u16* act = (u16*)(ws + 73 * MB);           // [73,82)  3072x1408 bf16
  u16* acts = (u16*)(ws + 82 * MB);          // [82,88)  1024x2816 bf16
  float* dwn = (float*)(ws + 9 * MB);        // [9,33)   3072x2048 f32
  float* shd = (float*)(ws + 33 * MB);       // [33,41)  1024x2048 f32

  k_ropetab<<<256, 256, 0, stream>>>(tab);
  k_rmsnorm<<<1024, 256, 0, stream>>>(hidden, ln1, nullptr, hnh, hnl);
  k_splitf<<<4096, 256, 0, stream>>>(wq, wqh, wql);
  k_splitf<<<4096, 256, 0, stream>>>(wk, wkh, wkl);
  k_splitf<<<4096, 256, 0, stream>>>(wvw, wvh, wvl);
  k_splitf<<<4096, 256, 0, stream>>>(wo, woh, wol);
  k_gemm_bf16split<<<dim3(8, 16, 3), 256, 0, stream>>>(
      hnh, hnl, wqh, wql, wkh, wkl, wvh, wvl, qf, kf, vf, nullptr);
  k_rope<<<4096, 256, 0, stream>>>(qf, kf, tab);
  k_splitkv<<<2048, 256, 0, stream>>>(qf, kf, vf, Qh, Ql, Kh, Kl, Vth, Vtl);
  k_attn_tile<<<dim3(16, 16), 256, 0, stream>>>(Qh, Ql, Kh, Kl, Vth, Vtl, atth, attl);
  k_gemm_bf16split<<<dim3(8, 16, 1), 256, 0, stream>>>(
      atth, attl, woh, wol, woh, wol, woh, wol, xf, xf, xf, hidden);
  k_rmsnorm<<<1024, 256, 0, stream>>>(xf, ln2, h2f, h2b, nullptr);
  k_router<<<1024, 256, 0, stream>>>(h2f, gw, tidx, twgt);
  k_scan<<<1, 64, 0, stream>>>(tidx, twgt, meta, tokl, slw, slots);
  k_dual_all<<<880, 256, 0, stream>>>(h2b, eg, eu, sg, su, meta, tokl, slw, act, acts);
  k_down_all<<<640, 256, 0, stream>>>(act, ed, acts, sd, meta, dwn, shd);
  k_combine<<<2048, 256, 0, stream>>>(shd, xf, dwn, slots, out);
}

// Round 7
// 590.091 us; speedup vs baseline: 2.6782x; 1.0320x over previous
//
#include <hip/hip_runtime.h>
#include <hip/hip_bf16.h>

// DeepseekDecoderLayer on MI355X. Round 6: 2-phase double-buffered MoE GEMMs.
// - k_dual_all / k_down_all: K-loop restructured to the 2-phase template
//   (issue next-tile STAGE -> ds_read+MFMA current -> convert+write prefetched
//   B -> ONE barrier). HBM latency hides under MFMA; B f32->bf16 conversion
//   overlaps the matrix pipe. LDS double-buffered (32KB, still 4 blocks/CU).
// - Attention/QKV/O/router/scan/combine: unchanged from r5.

#define DI __device__ __forceinline__

typedef __attribute__((ext_vector_type(8))) short short8;
typedef __attribute__((ext_vector_type(4))) float f32x4;
using u16 = unsigned short;

struct alignas(8) U16x4 { u16 x, y, z, w; };

DI u16 f2bf(float f) {
  unsigned u = __float_as_uint(f);
  u += 0x7fffu + ((u >> 16) & 1u);
  return (u16)(u >> 16);
}
DI float bf2f(u16 h) { return __uint_as_float(((unsigned)h) << 16); }

DI void gload16(const void* g, void* l) {
  __builtin_amdgcn_global_load_lds((const __attribute__((address_space(1))) void*)g,
                                   (__attribute__((address_space(3))) void*)l, 16, 0, 0);
}

// ---------------- small kernels ----------------

// RoPE cos/sin table in double precision (matches f64 numpy reference).
__global__ __launch_bounds__(256) void k_ropetab(float* __restrict__ tab) {
  int idx = blockIdx.x * 256 + threadIdx.x;  // < 1024*64
  int s = idx >> 6, i = idx & 63;
  double inv = pow(10000.0, -(double)(2 * i) / 128.0);
  double ang = (double)s * inv;
  tab[idx * 2 + 0] = (float)cos(ang);
  tab[idx * 2 + 1] = (float)sin(ang);
}

// RMSNorm row kernel: optional f32 out + optional bf16 hi/lo outs.
__global__ __launch_bounds__(256) void k_rmsnorm(const float* __restrict__ in,
                                                 const float* __restrict__ w,
                                                 float* __restrict__ outf,
                                                 u16* __restrict__ outh,
                                                 u16* __restrict__ outl) {
  const int row = blockIdx.x, t = threadIdx.x;
  const float* x = in + (size_t)row * 2048;
  float4 a = *(const float4*)&x[t * 4];
  float4 b = *(const float4*)&x[1024 + t * 4];
  float ss = a.x * a.x + a.y * a.y + a.z * a.z + a.w * a.w +
             b.x * b.x + b.y * b.y + b.z * b.z + b.w * b.w;
#pragma unroll
  for (int off = 32; off; off >>= 1) ss += __shfl_xor(ss, off);
  __shared__ float red[4];
  if ((t & 63) == 0) red[t >> 6] = ss;
  __syncthreads();
  float total = red[0] + red[1] + red[2] + red[3];
  float r = 1.0f / sqrtf(total * (1.0f / 2048.0f) + 1e-6f);
  float4 wa = *(const float4*)&w[t * 4];
  float4 wb = *(const float4*)&w[1024 + t * 4];
  float va[8] = {a.x * r * wa.x, a.y * r * wa.y, a.z * r * wa.z, a.w * r * wa.w,
                 b.x * r * wb.x, b.y * r * wb.y, b.z * r * wb.z, b.w * r * wb.w};
  if (outf) {
    *(float4*)&outf[(size_t)row * 2048 + t * 4] = make_float4(va[0], va[1], va[2], va[3]);
    *(float4*)&outf[(size_t)row * 2048 + 1024 + t * 4] = make_float4(va[4], va[5], va[6], va[7]);
  }
  if (outh) {
    U16x4 ha{f2bf(va[0]), f2bf(va[1]), f2bf(va[2]), f2bf(va[3])};
    U16x4 hb{f2bf(va[4]), f2bf(va[5]), f2bf(va[6]), f2bf(va[7])};
    *(U16x4*)&outh[(size_t)row * 2048 + t * 4] = ha;
    *(U16x4*)&outh[(size_t)row * 2048 + 1024 + t * 4] = hb;
    if (outl) {
      U16x4 la{f2bf(va[0] - bf2f(ha.x)), f2bf(va[1] - bf2f(ha.y)),
               f2bf(va[2] - bf2f(ha.z)), f2bf(va[3] - bf2f(ha.w))};
      U16x4 lb{f2bf(va[4] - bf2f(hb.x)), f2bf(va[5] - bf2f(hb.y)),
               f2bf(va[6] - bf2f(hb.z)), f2bf(va[7] - bf2f(hb.w))};
      *(U16x4*)&outl[(size_t)row * 2048 + t * 4] = la;
      *(U16x4*)&outl[(size_t)row * 2048 + 1024 + t * 4] = lb;
    }
  }
}

// Split an f32 array into bf16 hi/lo (weights prep).
__global__ __launch_bounds__(256) void k_splitf(const float* __restrict__ src,
                                                u16* __restrict__ dh,
                                                u16* __restrict__ dl) {
  int idx = (blockIdx.x * 256 + threadIdx.x) * 4;
  float4 v = *(const float4*)&src[idx];
  U16x4 h{f2bf(v.x), f2bf(v.y), f2bf(v.z), f2bf(v.w)};
  U16x4 l{f2bf(v.x - bf2f(h.x)), f2bf(v.y - bf2f(h.y)),
          f2bf(v.z - bf2f(h.z)), f2bf(v.w - bf2f(h.w))};
  *(U16x4*)&dh[idx] = h;
  *(U16x4*)&dl[idx] = l;
}

// Apply RoPE in-place to q (with 1/sqrt(128) folded in) and k. f32.
__global__ __launch_bounds__(256) void k_rope(float* __restrict__ q, float* __restrict__ k,
                                              const float* __restrict__ tab) {
  int idx = blockIdx.x * 256 + threadIdx.x;  // < 1024*16*64
  int s = idx >> 10, rem = idx & 1023;
  int h = rem >> 6, i = rem & 63;
  size_t base = (size_t)s * 2048 + h * 128 + i;
  float c = tab[(s * 64 + i) * 2 + 0];
  float sn = tab[(s * 64 + i) * 2 + 1];
  const float qs = 0.08838834764831845f;  // 1/sqrt(128)
  float q1 = q[base], q2 = q[base + 64];
  q[base] = (q1 * c - q2 * sn) * qs;
  q[base + 64] = (q2 * c + q1 * sn) * qs;
  float k1 = k[base], k2 = k[base + 64];
  k[base] = k1 * c - k2 * sn;
  k[base + 64] = k2 * c + k1 * sn;
}

// Split f32 q/k/v into bf16 hi/lo. Q,K keep [s][2048] layout; V transposed to
// [h*128+d][s].
__global__ __launch_bounds__(256) void k_splitkv(
    const float* __restrict__ qf, const float* __restrict__ kf,
    const float* __restrict__ vf,
    u16* __restrict__ Qh, u16* __restrict__ Ql,
    u16* __restrict__ Kh, u16* __restrict__ Kl,
    u16* __restrict__ Vth, u16* __restrict__ Vtl) {
  int idx = (blockIdx.x * 256 + threadIdx.x) * 4;  // over 1024*2048 elements
  int s = idx >> 11, c = idx & 2047;
  float4 q4 = *(const float4*)&qf[idx];
  U16x4 qh{f2bf(q4.x), f2bf(q4.y), f2bf(q4.z), f2bf(q4.w)};
  U16x4 ql{f2bf(q4.x - bf2f(qh.x)), f2bf(q4.y - bf2f(qh.y)),
           f2bf(q4.z - bf2f(qh.z)), f2bf(q4.w - bf2f(qh.w))};
  *(U16x4*)&Qh[idx] = qh; *(U16x4*)&Ql[idx] = ql;
  float4 k4 = *(const float4*)&kf[idx];
  U16x4 kh{f2bf(k4.x), f2bf(k4.y), f2bf(k4.z), f2bf(k4.w)};
  U16x4 kl{f2bf(k4.x - bf2f(kh.x)), f2bf(k4.y - bf2f(kh.y)),
           f2bf(k4.z - bf2f(kh.z)), f2bf(k4.w - bf2f(kh.w))};
  *(U16x4*)&Kh[idx] = kh; *(U16x4*)&Kl[idx] = kl;
  float4 v4 = *(const float4*)&vf[idx];
  float vv[4] = {v4.x, v4.y, v4.z, v4.w};
#pragma unroll
  for (int i = 0; i < 4; ++i) {
    u16 hv = f2bf(vv[i]);
    u16 lv = f2bf(vv[i] - bf2f(hv));
    Vth[(size_t)(c + i) * 1024 + s] = hv;
    Vtl[(size_t)(c + i) * 1024 + s] = lv;
  }
}

// ---------------- attention (LDS-staged, double-buffered) ----------------
DI void stage_kv(const u16* __restrict__ Khg, const u16* __restrict__ Klg,
                 const u16* __restrict__ Vhg, const u16* __restrict__ Vlg,
                 u16* lsKh, u16* lsKl, u16* lsVh, u16* lsVl,
                 int kvb, int hh, int wv, int lane) {
#pragma unroll
  for (int it = 0; it < 4; ++it) {
    const int ebase = it * 2048 + wv * 512;  // wave-uniform LDS base
    const int eo = ebase + lane * 8;
    {  // K tile [64 kv][128 d]
      const int rr = eo >> 7, cg = (eo >> 3) & 15;
      const size_t src = (size_t)(kvb + rr) * 2048 + hh * 128 + ((cg ^ (rr & 7)) << 3);
      gload16(Khg + src, lsKh + ebase);
      gload16(Klg + src, lsKl + ebase);
    }
    {  // V tile [128 d][64 kv]
      const int rr = eo >> 6, cg = (eo >> 3) & 7;
      const size_t src = (size_t)(hh * 128 + rr) * 1024 + kvb + ((cg ^ (rr & 7)) << 3);
      gload16(Vhg + src, lsVh + ebase);
      gload16(Vlg + src, lsVl + ebase);
    }
  }
}

__global__ __launch_bounds__(256) void k_attn_tile(
    const u16* __restrict__ Qh, const u16* __restrict__ Ql,
    const u16* __restrict__ Khg, const u16* __restrict__ Klg,
    const u16* __restrict__ Vhg, const u16* __restrict__ Vlg,
    u16* __restrict__ atth, u16* __restrict__ attl) {
  __shared__ u16 lsKh[2][8192], lsKl[2][8192], lsVh[2][8192], lsVl[2][8192];  // 128KB
  __shared__ u16 Plh[4][16][72], Pll[4][16][72];                              // 18KB
  const int hh = blockIdx.y;
  const int qb = blockIdx.x * 64;
  const int tid = threadIdx.x, lane = tid & 63, wv = tid >> 6;
  const int l15 = lane & 15, grp = lane >> 4;
  u16(*plh)[72] = Plh[wv];
  u16(*pll)[72] = Pll[wv];
  const int q_glob = qb + wv * 16 + l15;
  const int tend = blockIdx.x + 1;

  short8 qfh[4], qfl[4];
  const size_t qbase = (size_t)q_glob * 2048 + hh * 128;
#pragma unroll
  for (int c = 0; c < 4; ++c) {
    qfh[c] = *(const short8*)&Qh[qbase + c * 32 + grp * 8];
    qfl[c] = *(const short8*)&Ql[qbase + c * 32 + grp * 8];
  }
  f32x4 oacc[8];
#pragma unroll
  for (int dc = 0; dc < 8; ++dc) oacc[dc] = 0.f;
  float m_run = -1e30f, l_run = 0.f;

  int cur = 0;
  stage_kv(Khg, Klg, Vhg, Vlg, lsKh[0], lsKl[0], lsVh[0], lsVl[0], 0, hh, wv, lane);
  __syncthreads();

  for (int kt = 0; kt < tend; ++kt) {
    const int kvb = kt * 64;
    if (kt + 1 < tend)
      stage_kv(Khg, Klg, Vhg, Vlg, lsKh[cur ^ 1], lsKl[cur ^ 1], lsVh[cur ^ 1],
               lsVl[cur ^ 1], kvb + 64, hh, wv, lane);
    const u16* kh = lsKh[cur];
    const u16* kl = lsKl[cur];
    const u16* vh = lsVh[cur];
    const u16* vl = lsVl[cur];

    f32x4 s4[4];
#pragma unroll
    for (int sub = 0; sub < 4; ++sub) {
      f32x4 a = {0.f, 0.f, 0.f, 0.f};
      const int kr = sub * 16 + l15;
      const int sw = kr & 7;
#pragma unroll
      for (int c = 0; c < 4; ++c) {
        const int off = kr * 128 + ((((c << 2) | grp) ^ sw) << 3);
        short8 khf = *(const short8*)&kh[off];
        short8 klf = *(const short8*)&kl[off];
        a = __builtin_amdgcn_mfma_f32_16x16x32_bf16(khf, qfh[c], a, 0, 0, 0);
        a = __builtin_amdgcn_mfma_f32_16x16x32_bf16(klf, qfh[c], a, 0, 0, 0);
        a = __builtin_amdgcn_mfma_f32_16x16x32_bf16(khf, qfl[c], a, 0, 0, 0);
      }
      s4[sub] = a;
    }
    if (kt == tend - 1) {
#pragma unroll
      for (int sub = 0; sub < 4; ++sub)
#pragma unroll
        for (int r = 0; r < 4; ++r) {
          int kv = kvb + sub * 16 + grp * 4 + r;
          if (kv > q_glob) s4[sub][r] = -1e30f;
        }
    }
    float tmax = s4[0][0];
#pragma unroll
    for (int sub = 0; sub < 4; ++sub)
#pragma unroll
      for (int r = 0; r < 4; ++r) tmax = fmaxf(tmax, s4[sub][r]);
    tmax = fmaxf(tmax, __shfl_xor(tmax, 16));
    tmax = fmaxf(tmax, __shfl_xor(tmax, 32));
    float mnew = fmaxf(m_run, tmax);
    float scale = expf(m_run - mnew);
    float p[16], lsum = 0.f;
#pragma unroll
    for (int sub = 0; sub < 4; ++sub)
#pragma unroll
      for (int r = 0; r < 4; ++r) {
        float pe = expf(s4[sub][r] - mnew);
        p[sub * 4 + r] = pe;
        lsum += pe;
      }
    lsum += __shfl_xor(lsum, 16);
    lsum += __shfl_xor(lsum, 32);
    l_run = l_run * scale + lsum;
    m_run = mnew;
#pragma unroll
    for (int dc = 0; dc < 8; ++dc) oacc[dc] *= scale;
#pragma unroll
    for (int sub = 0; sub < 4; ++sub)
#pragma unroll
      for (int rp = 0; rp < 2; ++rp) {
        int i0 = sub * 4 + rp * 2;
        u16 h0 = f2bf(p[i0]), h1 = f2bf(p[i0 + 1]);
        u16 lo0 = f2bf(p[i0] - bf2f(h0)), lo1 = f2bf(p[i0 + 1] - bf2f(h1));
        int kvoff = sub * 16 + grp * 4 + rp * 2;
        *(unsigned*)&plh[l15][kvoff] = (unsigned)h0 | ((unsigned)h1 << 16);
        *(unsigned*)&pll[l15][kvoff] = (unsigned)lo0 | ((unsigned)lo1 << 16);
      }
    short8 phf[2], plf[2];
#pragma unroll
    for (int ks = 0; ks < 2; ++ks) {
      phf[ks] = *(const short8*)&plh[l15][ks * 32 + grp * 8];
      plf[ks] = *(const short8*)&pll[l15][ks * 32 + grp * 8];
    }
#pragma unroll
    for (int dc = 0; dc < 8; ++dc) {
      const int dr = dc * 16 + l15;
      const int sw = dr & 7;
      f32x4 acc = oacc[dc];
#pragma unroll
      for (int ks = 0; ks < 2; ++ks) {
        const int voff = dr * 64 + ((((ks << 2) | grp) ^ sw) << 3);
        short8 vhf = *(const short8*)&vh[voff];
        short8 vlf = *(const short8*)&vl[voff];
        acc = __builtin_amdgcn_mfma_f32_16x16x32_bf16(vhf, phf[ks], acc, 0, 0, 0);
        acc = __builtin_amdgcn_mfma_f32_16x16x32_bf16(vlf, phf[ks], acc, 0, 0, 0);
        acc = __builtin_amdgcn_mfma_f32_16x16x32_bf16(vhf, plf[ks], acc, 0, 0, 0);
      }
      oacc[dc] = acc;
    }
    __syncthreads();
    cur ^= 1;
  }
  float inv = 1.0f / l_run;
#pragma unroll
  for (int dc = 0; dc < 8; ++dc)
#pragma unroll
    for (int rp = 0; rp < 2; ++rp) {
      float v0 = oacc[dc][rp * 2] * inv;
      float v1 = oacc[dc][rp * 2 + 1] * inv;
      u16 h0 = f2bf(v0), h1 = f2bf(v1);
      u16 lo0 = f2bf(v0 - bf2f(h0)), lo1 = f2bf(v1 - bf2f(h1));
      size_t o = (size_t)q_glob * 2048 + hh * 128 + dc * 16 + grp * 4 + rp * 2;
      *(unsigned*)&atth[o] = (unsigned)h0 | ((unsigned)h1 << 16);
      *(unsigned*)&attl[o] = (unsigned)lo0 | ((unsigned)lo1 << 16);
    }
}

// Router: f32 logits (exact top-2 selection); emits top-2 idx + normed weights.
__global__ __launch_bounds__(256) void k_router(const float* __restrict__ h2f,
                                                const float* __restrict__ gw,
                                                int2* __restrict__ tidx,
                                                float2* __restrict__ twgt) {
  const int tok = blockIdx.x;
  const float* hrow = h2f + (size_t)tok * 2048;
  float part[8];
#pragma unroll
  for (int e = 0; e < 8; ++e) part[e] = 0.f;
  for (int j = 0; j < 8; ++j) {
    int p = j * 256 + threadIdx.x;
    float hv = hrow[p];
#pragma unroll
    for (int e = 0; e < 8; ++e) part[e] += hv * gw[e * 2048 + p];
  }
#pragma unroll
  for (int e = 0; e < 8; ++e)
#pragma unroll
    for (int off = 32; off; off >>= 1) part[e] += __shfl_xor(part[e], off);
  __shared__ float red[4][8];
  int wv = threadIdx.x >> 6, lane = threadIdx.x & 63;
  if (lane == 0) {
#pragma unroll
    for (int e = 0; e < 8; ++e) red[wv][e] = part[e];
  }
  __syncthreads();
  if (threadIdx.x == 0) {
    float lg[8];
#pragma unroll
    for (int e = 0; e < 8; ++e) lg[e] = red[0][e] + red[1][e] + red[2][e] + red[3][e];
    float m = lg[0];
#pragma unroll
    for (int e = 1; e < 8; ++e) m = fmaxf(m, lg[e]);
    float ex[8], s = 0.f;
#pragma unroll
    for (int e = 0; e < 8; ++e) { ex[e] = expf(lg[e] - m); s += ex[e]; }
#pragma unroll
    for (int e = 0; e < 8; ++e) ex[e] /= s;
    int i1 = 0;
#pragma unroll
    for (int e = 1; e < 8; ++e) if (ex[e] > ex[i1]) i1 = e;
    int i2 = (i1 == 0) ? 1 : 0;
#pragma unroll
    for (int e = 0; e < 8; ++e) if (e != i1 && ex[e] > ex[i2]) i2 = e;
    float s2 = ex[i1] + ex[i2] + 1e-20f;
    tidx[tok] = make_int2(i1, i2);
    twgt[tok] = make_float2(ex[i1] / s2, ex[i2] / s2);
  }
}

// Deterministic token gather, single wave (race-free). See r3 comments.
__global__ __launch_bounds__(64) void k_scan(const int2* __restrict__ tidx,
                                             const float2* __restrict__ twgt,
                                             int* __restrict__ meta,
                                             int* __restrict__ toklist,
                                             float* __restrict__ slotw,
                                             int* __restrict__ slots) {
  const int lane = threadIdx.x;
  int base = 0;
  for (int e = 0; e < 8; ++e) {
    int cnt = 0;
    for (int c = 0; c < 16; ++c) {
      const int tok = c * 64 + lane;
      int2 my = tidx[tok];
      int f1 = (my.x == e), f2 = (my.y == e);
      int flag = f1 | f2;
      unsigned long long m = __ballot(flag);
      if (flag) {
        float2 w = twgt[tok];
        int rank = (int)__popcll(m & ((1ull << lane) - 1ull));
        int s = base + cnt + rank;
        toklist[s] = tok;
        slotw[s] = f1 ? w.x : w.y;
        slots[tok * 2 + (f1 ? 0 : 1)] = s;
      }
      cnt += (int)__popcll(m);
    }
    if (lane == 0) { meta[e] = base; meta[9 + e] = cnt; }
    const int padded = ((cnt + 127) >> 7) << 7;
    for (int s = cnt + lane; s < padded; s += 64) {
      toklist[base + s] = 0;
      slotw[base + s] = 0.f;
    }
    base += padded;
  }
  if (lane == 0) meta[8] = base;
}

// ---------------- GEMM kernels ----------------
// C[M,N] = A[M,K] @ B[N,K]^T. MFMA 16x16x32 bf16; C/D: col=lane&15,
// row=(lane>>4)*4+reg.

DI void stageA_bf16(const u16* __restrict__ A, size_t lda, int row0, int k0,
                    u16* lsA, int tid) {
  const int lane = tid & 63, wv = tid >> 6;
#pragma unroll
  for (int it = 0; it < 2; ++it) {
    const int ebase = it * 2048 + wv * 512;  // wave-uniform LDS base
    const int eo = ebase + lane * 8;
    const int rr = eo >> 5, cc = eo & 31;
    gload16(A + (size_t)(row0 + rr) * lda + k0 + cc, lsA + ebase);
  }
}
// B f32 prefetch helpers: load to regs (issue-early) / convert+write (late).
template <int NJ>
DI void loadB_regs(const float* __restrict__ B, size_t ldb, int row0, int k0,
                   int tid, float4* r) {
#pragma unroll
  for (int j = 0; j < NJ; ++j) {
    const int eo = (j * 256 + tid) * 4;
    const int rr = eo >> 5, cc = eo & 31;
    r[j] = *(const float4*)(B + (size_t)(row0 + rr) * ldb + k0 + cc);
  }
}
template <int NJ>
DI void writeB_lds(u16* lsB, int tid, const float4* r) {
#pragma unroll
  for (int j = 0; j < NJ; ++j) {
    const int eo = (j * 256 + tid) * 4;
    U16x4 hv{f2bf(r[j].x), f2bf(r[j].y), f2bf(r[j].z), f2bf(r[j].w)};
    *(U16x4*)&lsB[eo] = hv;
  }
}

// Split GEMM, all-bf16 staging: C = Ah@Bh + Al@Bh + Ah@Bl (+resid).
__global__ __launch_bounds__(256) void k_gemm_bf16split(
    const u16* __restrict__ Ah, const u16* __restrict__ Al,
    const u16* __restrict__ Bh0, const u16* __restrict__ Bl0,
    const u16* __restrict__ Bh1, const u16* __restrict__ Bl1,
    const u16* __restrict__ Bh2, const u16* __restrict__ Bl2,
    float* __restrict__ C0, float* __restrict__ C1, float* __restrict__ C2,
    const float* __restrict__ resid) {
  __shared__ u16 lsAh[4096], lsAl[4096], lsBh[4096], lsBl[4096];
  const int z = blockIdx.z;
  const u16* Bh = (z == 0) ? Bh0 : (z == 1) ? Bh1 : Bh2;
  const u16* Bl = (z == 0) ? Bl0 : (z == 1) ? Bl1 : Bl2;
  float* Cm = (z == 0) ? C0 : (z == 1) ? C1 : C2;
  const int tid = threadIdx.x, lane = tid & 63, wv = tid >> 6;
  const int wr = (wv >> 1) * 64, wc = (wv & 1) * 64;
  const int fr = lane & 15, fg = lane >> 4;
  const int row0 = blockIdx.x * 128, col0 = blockIdx.y * 128;
  f32x4 acc[4][4];
#pragma unroll
  for (int i = 0; i < 4; ++i)
#pragma unroll
    for (int j = 0; j < 4; ++j) acc[i][j] = 0.f;

  for (int kt = 0; kt < 64; ++kt) {
    const int k0 = kt * 32;
    stageA_bf16(Ah, 2048, row0, k0, lsAh, tid);
    stageA_bf16(Al, 2048, row0, k0, lsAl, tid);
    stageA_bf16(Bh, 2048, col0, k0, lsBh, tid);
    stageA_bf16(Bl, 2048, col0, k0, lsBl, tid);
    __syncthreads();
    short8 ah[4], al[4], bh[4], bl[4];
#pragma unroll
    for (int mi = 0; mi < 4; ++mi) {
      const int off = (wr + mi * 16 + fr) * 32 + fg * 8;
      ah[mi] = *(const short8*)&lsAh[off];
      al[mi] = *(const short8*)&lsAl[off];
    }
#pragma unroll
    for (int ni = 0; ni < 4; ++ni) {
      const int off = (wc + ni * 16 + fr) * 32 + fg * 8;
      bh[ni] = *(const short8*)&lsBh[off];
      bl[ni] = *(const short8*)&lsBl[off];
    }
#pragma unroll
    for (int mi = 0; mi < 4; ++mi)
#pragma unroll
      for (int ni = 0; ni < 4; ++ni) {
        f32x4 c = acc[mi][ni];
        c = __builtin_amdgcn_mfma_f32_16x16x32_bf16(al[mi], bh[ni], c, 0, 0, 0);
        c = __builtin_amdgcn_mfma_f32_16x16x32_bf16(ah[mi], bl[ni], c, 0, 0, 0);
        c = __builtin_amdgcn_mfma_f32_16x16x32_bf16(ah[mi], bh[ni], c, 0, 0, 0);
        acc[mi][ni] = c;
      }
    __syncthreads();
  }
  const bool hasres = (resid != nullptr);
#pragma unroll
  for (int mi = 0; mi < 4; ++mi)
#pragma unroll
    for (int ni = 0; ni < 4; ++ni)
#pragma unroll
      for (int qq = 0; qq < 4; ++qq) {
        const int row = row0 + wr + mi * 16 + fg * 4 + qq;
        const int col = col0 + wc + ni * 16 + fr;
        float val = acc[mi][ni][qq];
        if (hasres) val += resid[(size_t)row * 2048 + col];
        Cm[(size_t)row * 2048 + col] = val;
      }
}

// Find expert for a padded row-tile index. meta[0..8] = offsets (mult of 128).
DI int tile_to_expert(const int* meta, int t) {
  int e = 0;
  while (e < 7 && t >= (meta[e + 1] >> 7)) ++e;
  return e;
}

// Fused dual GEMM + SiLU, 2-PHASE double-buffered: sparse expert tiles
// (bid<528) + shared expert (bid>=528). Per K-step: issue next A-stage
// (gload_lds) + next B f32 reg-loads -> ds_read+MFMA current -> convert+write
// next B -> ONE barrier.
__global__ __launch_bounds__(256) void k_dual_all(
    const u16* __restrict__ h2b, const float* __restrict__ eg,
    const float* __restrict__ eu, const float* __restrict__ sg,
    const float* __restrict__ su, const int* __restrict__ meta,
    const int* __restrict__ toklist, const float* __restrict__ slotw,
    u16* __restrict__ act, u16* __restrict__ acts) {
  const int bid = blockIdx.x;
  const bool isShared = bid >= 528;
  __shared__ int toks[128];
  __shared__ u16 lsA[2][4096], lsG[2][2048], lsU[2][2048];  // 32KB dbuf
  const int tid = threadIdx.x, lane = tid & 63, wv = tid >> 6;
  const int wr = (wv >> 1) * 64, wc = (wv & 1) * 32;
  const int fr = lane & 15, fg = lane >> 4;

  int n0, e = 0, off_e = 0, cnt_e = 0, rtile = 0;
  const float *Bg, *Bu;
  if (isShared) {
    const int b2 = bid - 528;
    rtile = b2 / 44;
    n0 = (b2 % 44) * 64;
    Bg = sg;
    Bu = su;
    if (tid < 128) toks[tid] = rtile * 128 + tid;
  } else {
    const int t = bid / 22;
    if (t >= (meta[8] >> 7)) return;
    n0 = (bid % 22) * 64;
    e = tile_to_expert(meta, t);
    off_e = meta[e];
    cnt_e = meta[9 + e];
    rtile = t - (off_e >> 7);
    Bg = eg + (size_t)e * 1408 * 2048;
    Bu = eu + (size_t)e * 1408 * 2048;
    if (tid < 128) toks[tid] = toklist[off_e + rtile * 128 + tid] & 1023;
  }
  f32x4 ag[4][2], au[4][2];
#pragma unroll
  for (int i = 0; i < 4; ++i)
#pragma unroll
    for (int j = 0; j < 2; ++j) { ag[i][j] = 0.f; au[i][j] = 0.f; }
  __syncthreads();  // toks visible

  // A-gather staging (per-lane global source, linear LDS dest).
  auto stageAg = [&](u16* dst, int k0) {
#pragma unroll
    for (int it = 0; it < 2; ++it) {
      const int ebase = it * 2048 + wv * 512;
      const int eo = ebase + lane * 8;
      const int rr = eo >> 5, cc = eo & 31;
      gload16(h2b + (size_t)toks[rr] * 2048 + k0 + cc, dst + ebase);
    }
  };

  // Prologue: stage tile 0.
  float4 gpre[2], upre[2];
  stageAg(lsA[0], 0);
  loadB_regs<2>(Bg, 2048, n0, 0, tid, gpre);
  loadB_regs<2>(Bu, 2048, n0, 0, tid, upre);
  writeB_lds<2>(lsG[0], tid, gpre);
  writeB_lds<2>(lsU[0], tid, upre);
  __syncthreads();

  int cur = 0;
  for (int kt = 0; kt < 64; ++kt) {
    const int k1 = (kt + 1) * 32;
    const bool pf = (kt + 1 < 64);
    if (pf) {  // issue next-tile loads first (hide HBM under MFMA)
      stageAg(lsA[cur ^ 1], k1);
      loadB_regs<2>(Bg, 2048, n0, k1, tid, gpre);
      loadB_regs<2>(Bu, 2048, n0, k1, tid, upre);
    }
    short8 af[4], gf[2], uf[2];
#pragma unroll
    for (int mi = 0; mi < 4; ++mi)
      af[mi] = *(const short8*)&lsA[cur][(wr + mi * 16 + fr) * 32 + fg * 8];
#pragma unroll
    for (int ni = 0; ni < 2; ++ni) {
      const int off = (wc + ni * 16 + fr) * 32 + fg * 8;
      gf[ni] = *(const short8*)&lsG[cur][off];
      uf[ni] = *(const short8*)&lsU[cur][off];
    }
#pragma unroll
    for (int mi = 0; mi < 4; ++mi)
#pragma unroll
      for (int ni = 0; ni < 2; ++ni) {
        ag[mi][ni] = __builtin_amdgcn_mfma_f32_16x16x32_bf16(af[mi], gf[ni], ag[mi][ni], 0, 0, 0);
        au[mi][ni] = __builtin_amdgcn_mfma_f32_16x16x32_bf16(af[mi], uf[ni], au[mi][ni], 0, 0, 0);
      }
    if (pf) {  // convert + write prefetched B into the other buffer
      writeB_lds<2>(lsG[cur ^ 1], tid, gpre);
      writeB_lds<2>(lsU[cur ^ 1], tid, upre);
    }
    __syncthreads();
    cur ^= 1;
  }
#pragma unroll
  for (int mi = 0; mi < 4; ++mi)
#pragma unroll
    for (int ni = 0; ni < 2; ++ni)
#pragma unroll
      for (int qq = 0; qq < 4; ++qq) {
        const int r = wr + mi * 16 + fg * 4 + qq;
        const int col = n0 + wc + ni * 16 + fr;
        float g = ag[mi][ni][qq], u = au[mi][ni][qq];
        float a = g / (1.0f + expf(-g)) * u;
        if (isShared) {
          acts[(size_t)(rtile * 128 + r) * 2816 + col] = f2bf(a);
        } else {
          const int rowInE = rtile * 128 + r;
          if (rowInE < cnt_e)
            act[(size_t)(off_e + rowInE) * 1408 + col] = f2bf(a * slotw[off_e + rowInE]);
        }
      }
}

// Fused down GEMMs, 2-PHASE double-buffered: sparse (bid<384, 128x128,
// K=1408 -> dwn) + shared (bid>=384, 128x64, K=2816 -> shd).
__global__ __launch_bounds__(256) void k_down_all(
    const u16* __restrict__ act, const float* __restrict__ ed,
    const u16* __restrict__ acts, const float* __restrict__ sd,
    const int* __restrict__ meta, float* __restrict__ dwn,
    float* __restrict__ shd) {
  __shared__ u16 lsA[2][4096], lsB[2][4096];  // 32KB dbuf
  const int bid = blockIdx.x;
  const int tid = threadIdx.x, lane = tid & 63, wv = tid >> 6;
  const int fr = lane & 15, fg = lane >> 4;
  if (bid < 384) {
    const int t = bid >> 4;
    if (t >= (meta[8] >> 7)) return;
    const int col0 = (bid & 15) * 128;
    const int e = tile_to_expert(meta, t);
    const int off_e = meta[e];
    const int rtile = t - (off_e >> 7);
    const int wr = (wv >> 1) * 64, wc = (wv & 1) * 64;
    const u16* Ab = act + (size_t)off_e * 1408;
    const float* Bb = ed + (size_t)e * 2048 * 1408;
    f32x4 acc[4][4];
#pragma unroll
    for (int i = 0; i < 4; ++i)
#pragma unroll
      for (int j = 0; j < 4; ++j) acc[i][j] = 0.f;
    float4 bpre[4];
    stageA_bf16(Ab, 1408, rtile * 128, 0, lsA[0], tid);
    loadB_regs<4>(Bb, 1408, col0, 0, tid, bpre);
    writeB_lds<4>(lsB[0], tid, bpre);
    __syncthreads();
    int cur = 0;
    for (int kt = 0; kt < 44; ++kt) {
      const int k1 = (kt + 1) * 32;
      const bool pf = (kt + 1 < 44);
      if (pf) {
        stageA_bf16(Ab, 1408, rtile * 128, k1, lsA[cur ^ 1], tid);
        loadB_regs<4>(Bb, 1408, col0, k1, tid, bpre);
      }
      short8 af[4], bf_[4];
#pragma unroll
      for (int mi = 0; mi < 4; ++mi)
        af[mi] = *(const short8*)&lsA[cur][(wr + mi * 16 + fr) * 32 + fg * 8];
#pragma unroll
      for (int ni = 0; ni < 4; ++ni)
        bf_[ni] = *(const short8*)&lsB[cur][(wc + ni * 16 + fr) * 32 + fg * 8];
#pragma unroll
      for (int mi = 0; mi < 4; ++mi)
#pragma unroll
        for (int ni = 0; ni < 4; ++ni)
          acc[mi][ni] = __builtin_amdgcn_mfma_f32_16x16x32_bf16(af[mi], bf_[ni], acc[mi][ni], 0, 0, 0);
      if (pf) writeB_lds<4>(lsB[cur ^ 1], tid, bpre);
      __syncthreads();
      cur ^= 1;
    }
#pragma unroll
    for (int mi = 0; mi < 4; ++mi)
#pragma unroll
      for (int ni = 0; ni < 4; ++ni)
#pragma unroll
        for (int qq = 0; qq < 4; ++qq) {
          const int r = wr + mi * 16 + fg * 4 + qq;
          const int col = col0 + wc + ni * 16 + fr;
          dwn[(size_t)(off_e + rtile * 128 + r) * 2048 + col] = acc[mi][ni][qq];
        }
  } else {
    const int b2 = bid - 384;
    const int row0 = (b2 >> 5) * 128;
    const int col0 = (b2 & 31) * 64;
    const int wr = (wv >> 1) * 64, wc = (wv & 1) * 32;
    f32x4 acc[4][2];
#pragma unroll
    for (int i = 0; i < 4; ++i)
#pragma unroll
      for (int j = 0; j < 2; ++j) acc[i][j] = 0.f;
    float4 bpre[2];
    stageA_bf16(acts, 2816, row0, 0, lsA[0], tid);
    loadB_regs<2>(sd, 2816, col0, 0, tid, bpre);
    writeB_lds<2>(lsB[0], tid, bpre);
    __syncthreads();
    int cur = 0;
    for (int kt = 0; kt < 88; ++kt) {
      const int k1 = (kt + 1) * 32;
      const bool pf = (kt + 1 < 88);
      if (pf) {
        stageA_bf16(acts, 2816, row0, k1, lsA[cur ^ 1], tid);
        loadB_regs<2>(sd, 2816, col0, k1, tid, bpre);
      }
      short8 af[4], bf_[2];
#pragma unroll
      for (int mi = 0; mi < 4; ++mi)
        af[mi] = *(const short8*)&lsA[cur][(wr + mi * 16 + fr) * 32 + fg * 8];
#pragma unroll
      for (int ni = 0; ni < 2; ++ni)
        bf_[ni] = *(const short8*)&lsB[cur][(wc + ni * 16 + fr) * 32 + fg * 8];
#pragma unroll
      for (int mi = 0; mi < 4; ++mi)
#pragma unroll
        for (int ni = 0; ni < 2; ++ni)
          acc[mi][ni] = __builtin_amdgcn_mfma_f32_16x16x32_bf16(af[mi], bf_[ni], acc[mi][ni], 0, 0, 0);
      if (pf) writeB_lds<2>(lsB[cur ^ 1], tid, bpre);
      __syncthreads();
      cur ^= 1;
    }
#pragma unroll
    for (int mi = 0; mi < 4; ++mi)
#pragma unroll
      for (int ni = 0; ni < 2; ++ni)
#pragma unroll
        for (int qq = 0; qq < 4; ++qq) {
          const int row = row0 + wr + mi * 16 + fg * 4 + qq;
          const int col = col0 + wc + ni * 16 + fr;
          shd[(size_t)row * 2048 + col] = acc[mi][ni][qq];
        }
  }
}

// Final combine: out = x + shd + dwn[slot0] + dwn[slot1].
__global__ __launch_bounds__(256) void k_combine(
    const float* __restrict__ shd, const float* __restrict__ x,
    const float* __restrict__ dwn, const int* __restrict__ slots,
    float* __restrict__ outp) {
  const int i4 = (blockIdx.x * 256 + threadIdx.x) * 4;
  const int row = i4 >> 11, col = i4 & 2047;
  const int s0 = slots[row * 2], s1 = slots[row * 2 + 1];
  float4 a = *(const float4*)&shd[i4];
  float4 b = *(const float4*)&x[i4];
  float4 c = *(const float4*)&dwn[(size_t)s0 * 2048 + col];
  float4 d = *(const float4*)&dwn[(size_t)s1 * 2048 + col];
  float4 o;
  o.x = a.x + b.x + c.x + d.x;
  o.y = a.y + b.y + c.y + d.y;
  o.z = a.z + b.z + c.z + d.z;
  o.w = a.w + b.w + c.w + d.w;
  *(float4*)&outp[i4] = o;
}

// ---------------- host launch ----------------

extern "C" void kernel_launch(void* const* d_in, const int* in_sizes, int n_in,
                              void* d_out, int out_size, void* d_ws, size_t ws_size,
                              hipStream_t stream) {
  (void)in_sizes; (void)n_in; (void)out_size; (void)ws_size;
  const float* hidden = (const float*)d_in[0];
  const float* ln1 = (const float*)d_in[1];
  const float* ln2 = (const float*)d_in[2];
  const float* wq = (const float*)d_in[3];
  const float* wk = (const float*)d_in[4];
  const float* wvw = (const float*)d_in[5];
  const float* wo = (const float*)d_in[6];
  const float* gw = (const float*)d_in[7];
  const float* eg = (const float*)d_in[8];
  const float* eu = (const float*)d_in[9];
  const float* ed = (const float*)d_in[10];
  const float* sg = (const float*)d_in[11];
  const float* su = (const float*)d_in[12];
  const float* sd = (const float*)d_in[13];
  float* out = (float*)d_out;
  char* ws = (char*)d_ws;

  const size_t KB = 1ull << 10, MB = 1ull << 20;
  float* tab = (float*)(ws + 0);             // [0, 0.5MB)
  int2* tidx = (int2*)(ws + 512 * KB);
  float2* twgt = (float2*)(ws + 520 * KB);
  int* meta = (int*)(ws + 528 * KB);
  int* tokl = (int*)(ws + 532 * KB);
  float* slw = (float*)(ws + 544 * KB);
  int* slots = (int*)(ws + 556 * KB);
  u16* hnh = (u16*)(ws + 1 * MB);            // [1,5)   dies after QKV
  u16* hnl = (u16*)(ws + 5 * MB);            // [5,9)
  u16* wqh = (u16*)(ws + 9 * MB);            // [9,57): split wq/wk/wv, die after QKV
  u16* wql = (u16*)(ws + 17 * MB);
  u16* wkh = (u16*)(ws + 25 * MB);
  u16* wkl = (u16*)(ws + 33 * MB);
  u16* wvh = (u16*)(ws + 41 * MB);
  u16* wvl = (u16*)(ws + 49 * MB);
  u16* woh = (u16*)(ws + 57 * MB);           // [57,73): dies after O-proj
  u16* wol = (u16*)(ws + 65 * MB);
  float* qf = (float*)(ws + 73 * MB);        // [73,81) dies after splitkv
  float* kf = (float*)(ws + 81 * MB);        // [81,89)
  float* vf = (float*)(ws + 89 * MB);        // [89,97)
  // After QKV GEMM (wq..wvl dead):
  u16* Qh = (u16*)(ws + 9 * MB);             // [9,33): attn operands
  u16* Ql = (u16*)(ws + 13 * MB);
  u16* Kh = (u16*)(ws + 17 * MB);
  u16* Kl = (u16*)(ws + 21 * MB);
  u16* Vth = (u16*)(ws + 25 * MB);
  u16* Vtl = (u16*)(ws + 29 * MB);
  u16* atth = (u16*)(ws + 33 * MB);          // [33,41): dies after O-proj
  u16* attl = (u16*)(ws + 37 * MB);
  float* xf = (float*)(ws + 41 * MB);        // [41,49): residual2 (live to end)
  float* h2f = (float*)(ws + 49 * MB);       // [49,57)
  u16* h2b = (u16*)(ws + 1 * MB);            // [1,5) (hnh dead)
  // MoE (after attn; Qh..Vtl / qf..vf / atth dead):
  u16* act = (u16*)(ws + 73 * MB);           // [73,82)  3072x1408 bf16
  u16* acts = (u16*)(ws + 82 * MB);          // [82,88)  1024x2816 bf16
  float* dwn = (float*)(ws + 9 * MB);        // [9,33)   3072x2048 f32
  float* shd = (float*)(ws + 33 * MB);       // [33,41)  1024x2048 f32

  k_ropetab<<<256, 256, 0, stream>>>(tab);
  k_rmsnorm<<<1024, 256, 0, stream>>>(hidden, ln1, nullptr, hnh, hnl);
  k_splitf<<<4096, 256, 0, stream>>>(wq, wqh, wql);
  k_splitf<<<4096, 256, 0, stream>>>(wk, wkh, wkl);
  k_splitf<<<4096, 256, 0, stream>>>(wvw, wvh, wvl);
  k_splitf<<<4096, 256, 0, stream>>>(wo, woh, wol);
  k_gemm_bf16split<<<dim3(8, 16, 3), 256, 0, stream>>>(
      hnh, hnl, wqh, wql, wkh, wkl, wvh, wvl, qf, kf, vf, nullptr);
  k_rope<<<4096, 256, 0, stream>>>(qf, kf, tab);
  k_splitkv<<<2048, 256, 0, stream>>>(qf, kf, vf, Qh, Ql, Kh, Kl, Vth, Vtl);
  k_attn_tile<<<dim3(16, 16), 256, 0, stream>>>(Qh, Ql, Kh, Kl, Vth, Vtl, atth, attl);
  k_gemm_bf16split<<<dim3(8, 16, 1), 256, 0, stream>>>(
      atth, attl, woh, wol, woh, wol, woh, wol, xf, xf, xf, hidden);
  k_rmsnorm<<<1024, 256, 0, stream>>>(xf, ln2, h2f, h2b, nullptr);
  k_router<<<1024, 256, 0, stream>>>(h2f, gw, tidx, twgt);
  k_scan<<<1, 64, 0, stream>>>(tidx, twgt, meta, tokl, slw, slots);
  k_dual_all<<<880, 256, 0, stream>>>(h2b, eg, eu, sg, su, meta, tokl, slw, act, acts);
  k_down_all<<<640, 256, 0, stream>>>(act, ed, acts, sd, meta, dwn, shd);
  k_combine<<<2048, 256, 0, stream>>>(shd, xf, dwn, slots, out);
}